// Round 10
// baseline (2077.855 us; speedup 1.0000x reference)
//
#include <hip/hip_runtime.h>
#include <hip/hip_bf16.h>

// NS solver: 256x256 periodic, B=8, NC=3 (u,v,density), T outer x 10 inner steps.
// y0 = fp32, dt = fp32, out = fp32 (established R1-R5). Internal state fp32.
//
// R19 = R18 resubmitted (R18 bench was an infra failure: "container failed
// twice", no kernel verdict; code re-audited -- no OOB, no barrier
// divergence, intra-wave exchanges only).
//
// R18: radix-16-in-register B kernel. R17 (fused 2-stage rounds) verified
// -6.6% -> LDS round-trip count is the serial chain. Go further in B:
// stages 1-4 live in contiguous 16-blocks, stages 5-8 in stride-16 residue
// classes -> one lane holds 16 float2 in regs and does 4 stages per LDS
// round. B core = 3 rounds: [fwd1-4], [fwd5-8 + scale + inv8-5] (same sets!),
// [inv4-1] vs 9 in R17. Cross-round exchange stays inside each 16-lane
// group (sub-wave) -> wave_sync only. Same butterflies/order/twiddles ->
// numerics match R17. A kernel unchanged (VGPR headroom too tight at 1024
// thr for x[16]); fallbacks unchanged.

#define NN 256
#define NM 255
#define FIELD (NN*NN)
#define BATCH 8
#define TOTAL (BATCH*FIELD)
#define ROWF2 264   // padded LDS row stride in float2 (256 + 8)

constexpr float RDX  = 40.743665431525205f;   // N/(2*pi) = 1/DX
constexpr float VISC = 1e-3f;

__device__ __forceinline__ int rev8(int x) { return (int)(__brev((unsigned)x) >> 24); }
__device__ __forceinline__ int pdx(int x)  { return x + (x >> 5); }

// Intra-wave LDS exchange fence (R13-verified on gfx950): compiler fence +
// sched barrier. A wave's DS ops complete in program order -> no s_barrier
// needed when producer and consumer lanes share a wave.
__device__ __forceinline__ void wave_sync() {
  asm volatile("" ::: "memory");
  __builtin_amdgcn_wave_barrier();
}

__device__ __forceinline__ float decode_dt(const unsigned* dtw) {
  unsigned w = dtw[0];
  float cf = __uint_as_float(w);
  float cb = __uint_as_float((w & 0xFFFFu) << 16);
  bool v32 = (cf > 1e-8f) && (cf < 1.0f);          // NaN-safe
  bool vbf = (cb > 1e-8f) && (cb < 1.0f);
  return v32 ? cf : (vbf ? cb : 1e-3f);
}

// ---------------------------------------------------------------- advection
__device__ __forceinline__ float face_flux(float uf, float cm, float c0,
                                           float cp, float cpp, float hdtdx) {
  float dc = cp - c0;
  float f_low  = (uf >= 0.0f) ? uf*c0 : uf*cp;
  float f_high = uf*0.5f*(c0+cp) - hdtdx*uf*uf*dc;
  float dc_up  = (uf >= 0.0f) ? (c0 - cm) : (cpp - cp);
  float dc_safe = (fabsf(dc) > 1e-12f) ? dc : 1e-12f;
  // van Leer: (a*b>0) ? 2a/(a+b) : 0
  float phi = (dc_up * dc_safe > 0.0f) ? (2.0f*dc_up/(dc_up + dc_safe)) : 0.0f;
  return f_low + phi*(f_high - f_low);
}

// global-memory stencil variant (fallback paths)
template<int NEED_VD>
__device__ __forceinline__ void advect_point(
    const float* __restrict__ Ub, const float* __restrict__ Vb,
    const float* __restrict__ Db,
    int i, int j, float hdtdx, float dt,
    float& u1, float& v1, float& d1)
{
  int im2 = ((i-2)&NM)*NN, im1 = ((i-1)&NM)*NN, i0r = i*NN,
      ip1 = ((i+1)&NM)*NN, ip2 = ((i+2)&NM)*NN;
  int jm2 = (j-2)&NM, jm1 = (j-1)&NM, jp1 = (j+1)&NM, jp2 = (j+2)&NM;

  float u_c  = Ub[i0r+j];
  float u_im2= Ub[im2+j], u_im1 = Ub[im1+j], u_ip1 = Ub[ip1+j], u_ip2 = Ub[ip2+j];
  float u_jm2= Ub[i0r+jm2], u_jm1 = Ub[i0r+jm1], u_jp1 = Ub[i0r+jp1], u_jp2 = Ub[i0r+jp2];
  float v_c  = Vb[i0r+j];
  float v_jm1= Vb[i0r+jm1], v_jp1 = Vb[i0r+jp1];

  float ufI0 = 0.5f*(u_c + u_ip1);
  float ufIm = 0.5f*(u_im1 + u_c);
  float vfJ0 = 0.5f*(v_c + v_jp1);
  float vfJm = 0.5f*(v_jm1 + v_c);

  float tu = -(( face_flux(ufI0, u_im1, u_c, u_ip1, u_ip2, hdtdx)
               - face_flux(ufIm, u_im2, u_im1, u_c, u_ip1, hdtdx))
             + ( face_flux(vfJ0, u_jm1, u_c, u_jp1, u_jp2, hdtdx)
               - face_flux(vfJm, u_jm2, u_jm1, u_c, u_jp1, hdtdx))) * RDX;
  float lapu = (u_im1 + u_ip1 + u_jm1 + u_jp1 - 4.0f*u_c) * (RDX*RDX);
  u1 = u_c + dt*(tu + VISC*lapu);

  if (NEED_VD) {
    float v_im2= Vb[im2+j], v_im1 = Vb[im1+j], v_ip1 = Vb[ip1+j], v_ip2 = Vb[ip2+j];
    float v_jm2= Vb[i0r+jm2], v_jp2 = Vb[i0r+jp2];
    float d_c  = Db[i0r+j];
    float d_im2= Db[im2+j], d_im1 = Db[im1+j], d_ip1 = Db[ip1+j], d_ip2 = Db[ip2+j];
    float d_jm2= Db[i0r+jm2], d_jm1 = Db[i0r+jm1], d_jp1 = Db[i0r+jp1], d_jp2 = Db[i0r+jp2];

    float tv = -(( face_flux(ufI0, v_im1, v_c, v_ip1, v_ip2, hdtdx)
                 - face_flux(ufIm, v_im2, v_im1, v_c, v_ip1, hdtdx))
               + ( face_flux(vfJ0, v_jm1, v_c, v_jp1, v_jp2, hdtdx)
                 - face_flux(vfJm, v_jm2, v_jm1, v_c, v_jp1, hdtdx))) * RDX;
    float lapv = (v_im1 + v_ip1 + v_jm1 + v_jp1 - 4.0f*v_c) * (RDX*RDX);
    v1 = v_c + dt*(tv + VISC*lapv);

    float td = -(( face_flux(ufI0, d_im1, d_c, d_ip1, d_ip2, hdtdx)
                 - face_flux(ufIm, d_im2, d_im1, d_c, d_ip1, hdtdx))
               + ( face_flux(vfJ0, d_jm1, d_c, d_jp1, d_jp2, hdtdx)
                 - face_flux(vfJm, d_jm2, d_jm1, d_c, d_jp1, hdtdx))) * RDX;
    d1 = d_c + dt*td;
  }
}

// LDS-slab stencil variant (fused A kernel). ku = u-slab row of the point,
// kv = v/d-slab row of the point. Slabs are contiguous (no row wrap); j wraps.
template<int NEED_VD>
__device__ __forceinline__ void advect_point_lds(
    const float* __restrict__ U, const float* __restrict__ V,
    const float* __restrict__ D,
    int ku, int kv, int j, float hdtdx, float dt,
    float& u1, float& v1, float& d1)
{
  int jm2 = (j-2)&NM, jm1 = (j-1)&NM, jp1 = (j+1)&NM, jp2 = (j+2)&NM;

  const float* Ur = U + ku*NN;
  float u_c  = Ur[j];
  float u_im2= U[(ku-2)*NN+j], u_im1 = U[(ku-1)*NN+j],
        u_ip1= U[(ku+1)*NN+j], u_ip2 = U[(ku+2)*NN+j];
  float u_jm2= Ur[jm2], u_jm1 = Ur[jm1], u_jp1 = Ur[jp1], u_jp2 = Ur[jp2];
  const float* Vr = V + kv*NN;
  float v_c  = Vr[j];
  float v_jm1= Vr[jm1], v_jp1 = Vr[jp1];

  float ufI0 = 0.5f*(u_c + u_ip1);
  float ufIm = 0.5f*(u_im1 + u_c);
  float vfJ0 = 0.5f*(v_c + v_jp1);
  float vfJm = 0.5f*(v_jm1 + v_c);

  float tu = -(( face_flux(ufI0, u_im1, u_c, u_ip1, u_ip2, hdtdx)
               - face_flux(ufIm, u_im2, u_im1, u_c, u_ip1, hdtdx))
             + ( face_flux(vfJ0, u_jm1, u_c, u_jp1, u_jp2, hdtdx)
               - face_flux(vfJm, u_jm2, u_jm1, u_c, u_jp1, hdtdx))) * RDX;
  float lapu = (u_im1 + u_ip1 + u_jm1 + u_jp1 - 4.0f*u_c) * (RDX*RDX);
  u1 = u_c + dt*(tu + VISC*lapu);

  if (NEED_VD) {
    float v_im2= V[(kv-2)*NN+j], v_im1 = V[(kv-1)*NN+j],
          v_ip1= V[(kv+1)*NN+j], v_ip2 = V[(kv+2)*NN+j];
    float v_jm2= Vr[jm2], v_jp2 = Vr[jp2];
    const float* Dr = D + kv*NN;
    float d_c  = Dr[j];
    float d_im2= D[(kv-2)*NN+j], d_im1 = D[(kv-1)*NN+j],
          d_ip1= D[(kv+1)*NN+j], d_ip2 = D[(kv+2)*NN+j];
    float d_jm2= Dr[jm2], d_jm1 = Dr[jm1], d_jp1 = Dr[jp1], d_jp2 = Dr[jp2];

    float tv = -(( face_flux(ufI0, v_im1, v_c, v_ip1, v_ip2, hdtdx)
                 - face_flux(ufIm, v_im2, v_im1, v_c, v_ip1, hdtdx))
               + ( face_flux(vfJ0, v_jm1, v_c, v_jp1, v_jp2, hdtdx)
                 - face_flux(vfJm, v_jm2, v_jm1, v_c, v_jp1, hdtdx))) * RDX;
    float lapv = (v_im1 + v_ip1 + v_jm1 + v_jp1 - 4.0f*v_c) * (RDX*RDX);
    v1 = v_c + dt*(tv + VISC*lapv);

    float td = -(( face_flux(ufI0, d_im1, d_c, d_ip1, d_ip2, hdtdx)
                 - face_flux(ufIm, d_im2, d_im1, d_c, d_ip1, hdtdx))
               + ( face_flux(vfJ0, d_jm1, d_c, d_jp1, d_jp2, hdtdx)
                 - face_flux(vfJm, d_jm2, d_jm1, d_c, d_jp1, hdtdx))) * RDX;
    d1 = d_c + dt*td;
  }
}

// ---------------------------------------------------------------- FFT cores
// Table-driven, padded-LDS. tw[m] = exp(-2*pi*i*m/256), m<128. Stage-s
// twiddle = tw[q<<(8-s)] (fwd), conjugate for inverse. A = padded row base;
// element x lives at A[pdx(x)].
// WAVE-SYNCHRONOUS (R13): exchanges within a wave need only wave_sync().
//
// R17 FUSED ROUNDS (A kernel): stages (s,s+1) fused, 4 LDS rounds/FFT.
// R18 RADIX-16 ROUNDS (B kernel): stages 1-4 confined to 16-blocks, stages
// 5-8 to stride-16 residue classes. One lane holds 16 float2 in regs ->
// 4 stages/round, and [fwd5-8 + scale + inv8-5] share the same sets ->
// single middle round. 3 LDS rounds for the whole fwd+scale+inv core.
// Same butterflies/order/twiddles as radix-2 network.

// --- radix-16 in-register stage groups (lane-local x[16]) ---
__device__ __forceinline__ void r16_fwd_low(float2* x, const float2* tw) {
  #pragma unroll
  for (int s = 1; s <= 4; ++s) {
    int h = 1 << (s-1);
    #pragma unroll
    for (int b = 0; b < 8; ++b) {
      int q = b & (h-1);
      int t = ((b >> (s-1)) << s) + q;
      float2 w = tw[q << (8-s)];
      float2 a = x[t], c = x[t+h];
      float wbx = w.x*c.x - w.y*c.y, wby = w.x*c.y + w.y*c.x;
      x[t]   = make_float2(a.x+wbx, a.y+wby);
      x[t+h] = make_float2(a.x-wbx, a.y-wby);
    }
  }
}
__device__ __forceinline__ void r16_fwd_high(float2* x, int r, const float2* tw) {
  #pragma unroll
  for (int s = 5; s <= 8; ++s) {
    int hp = 1 << (s-5);
    #pragma unroll
    for (int b = 0; b < 8; ++b) {
      int qp = b & (hp-1);
      int t = ((b >> (s-5)) << (s-4)) + qp;
      float2 w = tw[(r + (qp<<4)) << (8-s)];
      float2 a = x[t], c = x[t+hp];
      float wbx = w.x*c.x - w.y*c.y, wby = w.x*c.y + w.y*c.x;
      x[t]    = make_float2(a.x+wbx, a.y+wby);
      x[t+hp] = make_float2(a.x-wbx, a.y-wby);
    }
  }
}
__device__ __forceinline__ void r16_inv_high(float2* x, int r, const float2* tw) {
  #pragma unroll
  for (int s = 8; s >= 5; --s) {
    int hp = 1 << (s-5);
    #pragma unroll
    for (int b = 0; b < 8; ++b) {
      int qp = b & (hp-1);
      int t = ((b >> (s-5)) << (s-4)) + qp;
      float2 w = tw[(r + (qp<<4)) << (8-s)];
      float2 a = x[t], c = x[t+hp];
      float dx = a.x-c.x, dy = a.y-c.y;
      x[t]    = make_float2(a.x+c.x, a.y+c.y);
      x[t+hp] = make_float2(w.x*dx + w.y*dy, w.x*dy - w.y*dx);
    }
  }
}
__device__ __forceinline__ void r16_inv_low(float2* x, const float2* tw) {
  #pragma unroll
  for (int s = 4; s >= 1; --s) {
    int h = 1 << (s-1);
    #pragma unroll
    for (int b = 0; b < 8; ++b) {
      int q = b & (h-1);
      int t = ((b >> (s-1)) << s) + q;
      float2 w = tw[q << (8-s)];
      float2 a = x[t], c = x[t+h];
      float dx = a.x-c.x, dy = a.y-c.y;
      x[t]   = make_float2(a.x+c.x, a.y+c.y);
      x[t+h] = make_float2(w.x*dx + w.y*dy, w.x*dy - w.y*dx);
    }
  }
}

// --- R17 fused 2-stage rounds (A kernel) ---
// fwd DIT, fused stage pairs (1,2),(3,4),(5,6),(7,8). lane in [0,64).
__device__ __forceinline__ void fft256_fwd_f2(float2* __restrict__ A, int lane,
                                              const float2* __restrict__ tw,
                                              bool active)
{
  #pragma unroll
  for (int s = 1; s <= 8; s += 2) {
    if (active) {
      int half = 1 << (s-1);
      int q2 = lane & (half - 1);
      int i0 = ((lane >> (s-1)) << (s+1)) + q2;
      float2 a0 = A[pdx(i0)];
      float2 a1 = A[pdx(i0 + half)];
      float2 a2 = A[pdx(i0 + 2*half)];
      float2 a3 = A[pdx(i0 + 3*half)];
      // stage s: pairs (a0,a1),(a2,a3), twiddle tw[q2<<(8-s)]
      float2 w1 = tw[q2 << (8 - s)];
      float wbx = w1.x*a1.x - w1.y*a1.y, wby = w1.x*a1.y + w1.y*a1.x;
      float2 b0 = make_float2(a0.x + wbx, a0.y + wby);
      float2 b1 = make_float2(a0.x - wbx, a0.y - wby);
      wbx = w1.x*a3.x - w1.y*a3.y; wby = w1.x*a3.y + w1.y*a3.x;
      float2 b2 = make_float2(a2.x + wbx, a2.y + wby);
      float2 b3 = make_float2(a2.x - wbx, a2.y - wby);
      // stage s+1: pairs (b0,b2) tw[q2<<(7-s)], (b1,b3) tw[(q2+half)<<(7-s)]
      float2 w2 = tw[q2 << (7 - s)];
      float2 w3 = tw[(q2 + half) << (7 - s)];
      wbx = w2.x*b2.x - w2.y*b2.y; wby = w2.x*b2.y + w2.y*b2.x;
      A[pdx(i0)]            = make_float2(b0.x + wbx, b0.y + wby);
      A[pdx(i0 + 2*half)]   = make_float2(b0.x - wbx, b0.y - wby);
      wbx = w3.x*b3.x - w3.y*b3.y; wby = w3.x*b3.y + w3.y*b3.x;
      A[pdx(i0 + half)]     = make_float2(b1.x + wbx, b1.y + wby);
      A[pdx(i0 + 3*half)]   = make_float2(b1.x - wbx, b1.y - wby);
    }
    wave_sync();
  }
}

// inv DIF, fused stage pairs (8,7),(6,5),(4,3),(2,1). lane in [0,64).
__device__ __forceinline__ void fft256_inv_f2(float2* __restrict__ A, int lane,
                                              const float2* __restrict__ tw,
                                              bool active)
{
  #pragma unroll
  for (int s = 8; s >= 2; s -= 2) {
    if (active) {
      int h = 1 << (s-2);              // half of stage s-1
      int q2 = lane & (h - 1);
      int i0 = ((lane >> (s-2)) << s) + q2;
      float2 a0 = A[pdx(i0)];
      float2 a1 = A[pdx(i0 + h)];
      float2 a2 = A[pdx(i0 + 2*h)];
      float2 a3 = A[pdx(i0 + 3*h)];
      // stage s (half=2h): pairs (a0,a2) q=q2, (a1,a3) q=q2+h
      float2 w1 = tw[q2 << (8 - s)];
      float2 w2 = tw[(q2 + h) << (8 - s)];
      float dx = a0.x - a2.x, dy = a0.y - a2.y;
      float2 b0 = make_float2(a0.x + a2.x, a0.y + a2.y);
      float2 b2 = make_float2(w1.x*dx + w1.y*dy, w1.x*dy - w1.y*dx);
      dx = a1.x - a3.x; dy = a1.y - a3.y;
      float2 b1 = make_float2(a1.x + a3.x, a1.y + a3.y);
      float2 b3 = make_float2(w2.x*dx + w2.y*dy, w2.x*dy - w2.y*dx);
      // stage s-1 (half=h): pairs (b0,b1) and (b2,b3), both q=q2
      float2 w3 = tw[q2 << (9 - s)];
      dx = b0.x - b1.x; dy = b0.y - b1.y;
      A[pdx(i0)]       = make_float2(b0.x + b1.x, b0.y + b1.y);
      A[pdx(i0 + h)]   = make_float2(w3.x*dx + w3.y*dy, w3.x*dy - w3.y*dx);
      dx = b2.x - b3.x; dy = b2.y - b3.y;
      A[pdx(i0 + 2*h)] = make_float2(b2.x + b3.x, b2.y + b3.y);
      A[pdx(i0 + 3*h)] = make_float2(w3.x*dx + w3.y*dy, w3.x*dy - w3.y*dx);
    }
    wave_sync();
  }
}

// Legacy single-stage variants (fallback paths + final correction kernel).
template<int W>
__device__ __forceinline__ void fft256_dit_fwd(float2* __restrict__ A, int lane,
                                               const float2* __restrict__ tw,
                                               bool active)
{
  #pragma unroll
  for (int s = 1; s <= 8; ++s) {
    int half = 1 << (s-1);
    if (active) {
      #pragma unroll
      for (int r = 0; r < 128/W; ++r) {
        int bfly = lane + r*W;
        int q = bfly & (half - 1);
        int g = (bfly >> (s-1)) << s;
        float2 w = tw[q << (8 - s)];
        float2 a = A[pdx(g + q)];
        float2 b = A[pdx(g + q + half)];
        float wbx = w.x*b.x - w.y*b.y;
        float wby = w.x*b.y + w.y*b.x;
        A[pdx(g + q)]        = make_float2(a.x + wbx, a.y + wby);
        A[pdx(g + q + half)] = make_float2(a.x - wbx, a.y - wby);
      }
    }
    wave_sync();
  }
}

template<int W>
__device__ __forceinline__ void fft256_dif_inv(float2* __restrict__ A, int lane,
                                               const float2* __restrict__ tw,
                                               bool active)
{
  #pragma unroll
  for (int s = 8; s >= 1; --s) {
    int half = 1 << (s-1);
    if (active) {
      #pragma unroll
      for (int r = 0; r < 128/W; ++r) {
        int bfly = lane + r*W;
        int q = bfly & (half - 1);
        int g = (bfly >> (s-1)) << s;
        float2 w = tw[q << (8 - s)];      // conj applied below (inverse)
        float2 a = A[pdx(g + q)];
        float2 b = A[pdx(g + q + half)];
        float dx = a.x - b.x, dy = a.y - b.y;
        A[pdx(g + q)]        = make_float2(a.x + b.x, a.y + b.y);
        A[pdx(g + q + half)] = make_float2(w.x*dx + w.y*dy, w.x*dy - w.y*dx);
      }
    }
    wave_sync();
  }
}

// ================================================================ A (fused, 8-row, 1024 thr)
// 256 blocks x 1024 threads. Per block: batch b = bid>>5, rows row0..row0+7.
//  0. issue U/V/D global->reg staging loads (consumed in phase 2)
//  1. inv row FFT of 14 halo rows of S_prev (16 teams x 64, 14 active, fused)
//  2. q gather; corrected u (13 rows), v (12), d (12) slabs in LDS (from regs)
//  3. optional trajectory write-out of corrected state t-1 (owned 8 rows)
//  4. advect from LDS: quarter q -> u-only row 2q-1, full rows 2q, 2q+1
//  5. div -> bit-rev scatter -> fwd row FFT (16 teams, 8 active, fused) -> S_new
// Slab rows: q row k <-> global row0-3+k (k in [0,13])
//            u row k <-> global row0-3+k (k in [0,12])
//            v,d row k <-> global row0-2+k (k in [0,11])
// LDS aliasing (R12): Vs -> qs (dead after phase 2); Dss -> AbS rows 8..13
// (dead after phase 1; phase 5 uses rows 0..7). Total ~69 KB.
__global__ __launch_bounds__(1024) void proj_advect_fft8(
    const float2* __restrict__ Sprev, const float* __restrict__ inb,
    float* __restrict__ outb, float2* __restrict__ Snew,
    float* __restrict__ out, const unsigned* __restrict__ dtw,
    int T, int tm1, int first)
{
  __shared__ float2 tw[128];
  __shared__ float2 AbS[14*ROWF2];
  __shared__ float  qs [14*NN];
  __shared__ float  Ucs[13*NN];
  __shared__ float  Vcs[12*NN];
  float* Dss = (float*)(AbS + 8*ROWF2);  // 12*NN floats; phase-5 uses rows 0..7
  float* Vs  = qs;                       // 8*NN floats; qs dead after phase 2

  const int tid  = threadIdx.x;
  const int j    = tid & 255;
  const int qtr  = tid >> 8;           // 0..3
  const int b    = blockIdx.x >> 5;
  const int row0 = (blockIdx.x & 31) << 3;

  if (tid < 128) {
    float sw, cw;
    __sincosf(-0.02454369260617026f * (float)tid, &sw, &cw);  // -2pi/256
    tw[tid] = make_float2(cw, sw);
  }

  const float dt = decode_dt(dtw);
  const float hdtdx = 0.5f*dt*RDX;

  const float* Ub = inb + b*FIELD;
  const float* Vb = inb + TOTAL + b*FIELD;
  const float* Db = inb + 2*TOTAL + b*FIELD;
  float* Uo  = outb + b*FIELD;
  float* Vo  = outb + TOTAL + b*FIELD;
  float* Do_ = outb + 2*TOTAL + b*FIELD;

  // ---- phase 0: early global->reg staging (T14). Latency hides under phase 1.
  float u_reg[4], v_reg[3], d_reg[3];
  #pragma unroll
  for (int m = 0; m < 4; ++m) {        // U: 13 rows = 3328 elems
    int e = tid + (m << 10);
    if (e < 13*NN) {
      int k = e >> 8, jj = e & 255;
      u_reg[m] = Ub[((row0 - 3 + k) & NM)*NN + jj];
    }
  }
  #pragma unroll
  for (int m = 0; m < 3; ++m) {        // V, D: 12 rows = 3072 = 3*1024
    int e = tid + (m << 10);
    int k = e >> 8, jj = e & 255;
    int gr = ((row0 - 2 + k) & NM)*NN;
    v_reg[m] = Vb[gr + jj];
    d_reg[m] = Db[gr + jj];
  }

  // ---- phase 1: inv row FFT of 14 rows of S_prev -> qs (skip on step 0)
  if (!first) {
    const float2* Sb = Sprev + b*FIELD;
    #pragma unroll
    for (int m = 0; m < 4; ++m) {      // 14*256 = 3584 elems
      int e = tid + (m << 10);
      if (e < 14*NN) {
        int k = e >> 8, jj = e & 255;
        AbS[k*ROWF2 + pdx(jj)] = Sb[((row0 - 3 + k) & NM)*NN + jj];
      }
    }
    __syncthreads();                   // cross-wave: scatter -> per-wave FFT

    int g = tid >> 6, lane = tid & 63; // 16 teams of 64; 14 active
    bool act = (g < 14);
    fft256_inv_f2(AbS + (act ? g : 13)*ROWF2, lane, tw, act);
    __syncthreads();                   // cross-wave: FFT rows -> qs gather

    #pragma unroll
    for (int m = 0; m < 4; ++m) {      // un-reverse gather -> qs natural
      int e = tid + (m << 10);
      if (e < 14*NN) {
        int k = e >> 8, jj = e & 255;
        qs[k*NN + jj] = AbS[k*ROWF2 + pdx(rev8(jj))].x;
      }
    }
    __syncthreads();
  } else {
    __syncthreads();                   // match table init visibility
  }

  // ---- phase 2: corrected u,v + d slabs in LDS (from staged registers)
  // (Dss writes land in AbS rows 8..13 -- dead scratch after phase 1.)
  #pragma unroll
  for (int m = 0; m < 4; ++m) {        // U: 13 rows
    int e = tid + (m << 10);
    if (e < 13*NN) {
      int k = e >> 8, jj = e & 255;
      Ucs[e] = first ? u_reg[m]
                     : (u_reg[m] - (qs[(k+1)*NN + jj] - qs[k*NN + jj])*RDX);
    }
  }
  #pragma unroll
  for (int m = 0; m < 3; ++m) {        // V, D: 12 rows
    int e = tid + (m << 10);
    int k = e >> 8, jj = e & 255;
    Vcs[e] = first ? v_reg[m]
                   : (v_reg[m] - (qs[(k+1)*NN + ((jj+1)&NM)] - qs[(k+1)*NN + jj])*RDX);
    Dss[e] = d_reg[m];
  }
  __syncthreads();                     // qs dead from here; Vs may reuse it

  // ---- phase 3: fused trajectory write-out of corrected state t-1
  if (tm1 >= 0) {
    #pragma unroll
    for (int m = 0; m < 2; ++m) {
      int e = tid + (m << 10);         // 8 owned rows x 256 = 2048
      int k = e >> 8, jj = e & 255;
      int pos = (row0 + k)*NN + jj;
      size_t o = ((size_t)(b*T + tm1)*FIELD + pos)*3u;
      out[o]   = Ucs[(k+3)*NN + jj];
      out[o+1] = Vcs[(k+2)*NN + jj];
      out[o+2] = Dss[(k+2)*NN + jj];
    }
  }

  // ---- phase 4: advect from LDS. Quarter qtr: u-only row 2q-1 (backward
  // halo for div), full rows 2q, 2q+1.
  const int kbeg = (qtr << 1) - 1;     // -1, 1, 3, 5
  float u1r[3];
  #pragma unroll
  for (int kk = 0; kk < 3; ++kk) {
    int k = kbeg + kk;                 // global row = row0 + k
    int ku = k + 3, kv = k + 2;
    float u1, v1, d1;
    if (kk == 0) {
      advect_point_lds<0>(Ucs, Vcs, Dss, ku, kv, j, hdtdx, dt, u1, v1, d1);
    } else {
      advect_point_lds<1>(Ucs, Vcs, Dss, ku, kv, j, hdtdx, dt, u1, v1, d1);
      int gi = (row0 + k)*NN + j;
      Uo[gi] = u1; Vo[gi] = v1; Do_[gi] = d1;
      Vs[k*NN + j] = v1;               // k in [0,7], owned
    }
    u1r[kk] = u1;
  }
  __syncthreads();                     // Vs visible across waves

  // ---- phase 5: div (backward) -> bit-rev scatter (AbS rows 0..7) -> fwd FFT
  {
    int jm1 = (j - 1) & NM, rj = rev8(j);
    #pragma unroll
    for (int m = 0; m < 2; ++m) {
      int k = (qtr << 1) + m;          // owned rows
      float dv = (u1r[m+1] - u1r[m] + Vs[k*NN + j] - Vs[k*NN + jm1]) * RDX;
      AbS[k*ROWF2 + pdx(rj)] = make_float2(dv, 0.0f);
    }
  }
  __syncthreads();                     // cross-wave: scatter -> per-wave FFT

  {
    const int g = tid >> 6, lane = tid & 63;   // 16 teams of 64; 8 active
    bool act = (g < 8);
    fft256_fwd_f2(AbS + (act ? g : 7)*ROWF2, lane, tw, act);
  }
  __syncthreads();                     // cross-wave: FFT rows -> store

  float2* So = Snew + b*FIELD;
  #pragma unroll
  for (int m = 0; m < 2; ++m) {
    int e = tid + (m << 10);           // 8 rows x 256 = 2048
    int row = e >> 8, jj = e & 255;
    So[(row0 + row)*NN + jj] = AbS[row*ROWF2 + pdx(jj)];
  }
}

// ================================================================ B (radix-16, 3 LDS rounds)
// 256 blocks x 512 threads. fwd col FFT * invLam/N^2 * inv col FFT, in
// place. 8 columns, each handled by a 16-lane group (tid<128): 16 float2
// in registers, 4 stages per LDS round. Core = 3 rounds:
//   round 1: fwd stages 1-4 on 16-blocks
//   round 2: fwd 5-8 + scale + inv 8-5 on stride-16 classes (same sets)
//   round 3: inv stages 4-1 on 16-blocks
// Cross-round exchange within each 16-lane group (sub-wave) -> wave_sync.
__global__ __launch_bounds__(512) void fft_cols(float2* __restrict__ S)
{
  __shared__ float2 Ab[8*ROWF2];
  __shared__ float2 tw[128];
  __shared__ float  lam[NN];
  int tid = threadIdx.x;
  int b = blockIdx.x >> 5;
  int col0 = (blockIdx.x & 31) << 3;

  if (tid < 128) {
    float sw, cw;
    __sincosf(-0.02454369260617026f * (float)tid, &sw, &cw);
    tw[tid] = make_float2(cw, sw);
  }
  if (tid < 256) {
    float s1 = __sinf(0.01227184630308512983f * (float)tid);   // pi/256 * k
    lam[tid] = -4.0f * s1 * s1 * (RDX*RDX);
  }

  float2* Sb = S + b*FIELD;
  #pragma unroll
  for (int k = 0; k < 4; ++k) {        // load transposed, bit-reversed
    int idx = tid + (k << 9);
    int i = idx >> 3, c = idx & 7;
    Ab[c*ROWF2 + pdx(rev8(i))] = Sb[i*NN + col0 + c];
  }
  __syncthreads();                     // cross-wave: scatter -> FFT groups

  {
    const int g = tid >> 4;            // column index 0..7 (tid<128)
    const int r = tid & 15;            // lane role within group
    const bool act = (tid < 128);
    float2* Ar = Ab + g*ROWF2;

    if (act) {                         // round 1: fwd stages 1-4, block r
      float2 x[16];
      #pragma unroll
      for (int t = 0; t < 16; ++t) x[t] = Ar[pdx((r<<4) + t)];
      r16_fwd_low(x, tw);
      #pragma unroll
      for (int t = 0; t < 16; ++t) Ar[pdx((r<<4) + t)] = x[t];
    }
    wave_sync();

    if (act) {                         // round 2: fwd 5-8 + scale + inv 8-5
      float2 x[16];
      #pragma unroll
      for (int k = 0; k < 16; ++k) x[k] = Ar[pdx(r + (k<<4))];
      r16_fwd_high(x, r, tw);
      float l2 = lam[col0 + g];
      #pragma unroll
      for (int k = 0; k < 16; ++k) {
        int k1 = r + (k<<4);
        float den = lam[k1] + l2;
        float sc = ((k1 | (col0 + g)) == 0) ? 0.0f : (1.0f/den);
        sc *= (1.0f/65536.0f);         // fold in ifft2's 1/N^2
        x[k].x *= sc; x[k].y *= sc;
      }
      r16_inv_high(x, r, tw);
      #pragma unroll
      for (int k = 0; k < 16; ++k) Ar[pdx(r + (k<<4))] = x[k];
    }
    wave_sync();

    if (act) {                         // round 3: inv stages 4-1, block r
      float2 x[16];
      #pragma unroll
      for (int t = 0; t < 16; ++t) x[t] = Ar[pdx((r<<4) + t)];
      r16_inv_low(x, tw);
      #pragma unroll
      for (int t = 0; t < 16; ++t) Ar[pdx((r<<4) + t)] = x[t];
    }
  }
  __syncthreads();                     // cross-wave: FFT rows -> store

  #pragma unroll
  for (int k = 0; k < 4; ++k) {        // store transposed, un-reversed
    int idx = tid + (k << 9);
    int i = idx >> 3, c = idx & 7;
    Sb[i*NN + col0 + c] = Ab[c*ROWF2 + pdx(rev8(i))];
  }
}

// ================================================================ K1 (R9 fallback)
__global__ __launch_bounds__(512) void advect_div_fft(
    const float* __restrict__ inb, float* __restrict__ outb,
    float2* __restrict__ S, float* __restrict__ out,
    const unsigned* __restrict__ dtw, int T, int tm1)
{
  __shared__ float  Vs[8][NN];
  __shared__ float2 AbS[8*ROWF2];
  __shared__ float2 tw[128];
  const int tid = threadIdx.x;
  const int j   = tid & 255;
  const int h   = tid >> 8;           // 0 or 1
  const int b    = blockIdx.x >> 5;
  const int row0 = (blockIdx.x & 31) << 3;

  if (tid < 128) {
    float sw, cw;
    __sincosf(-0.02454369260617026f * (float)tid, &sw, &cw);  // -2pi/256
    tw[tid] = make_float2(cw, sw);
  }

  const float* Ub = inb + b*FIELD;
  const float* Vb = inb + TOTAL + b*FIELD;
  const float* Db = inb + 2*TOTAL + b*FIELD;
  float* Uo  = outb + b*FIELD;
  float* Vo  = outb + TOTAL + b*FIELD;
  float* Do_ = outb + 2*TOTAL + b*FIELD;

  const float dt = decode_dt(dtw);
  const float hdtdx = 0.5f*dt*RDX;

  if (tm1 >= 0) {                      // fused write_out of previous state
    #pragma unroll
    for (int k = 0; k < 4; ++k) {
      int pos = (row0 + h*4 + k)*NN + j;
      size_t o = ((size_t)(b*T + tm1)*FIELD + pos)*3u;
      out[o]   = Ub[pos];
      out[o+1] = Vb[pos];
      out[o+2] = Db[pos];
    }
  }

  const int kbeg = h ? 3 : -1;
  float u1r[5];
  #pragma unroll
  for (int kk = 0; kk < 5; ++kk) {
    int k = kbeg + kk;
    int r = (row0 + k) & NM;
    float u1, v1, d1;
    if (kk == 0) {
      advect_point<0>(Ub, Vb, Db, r, j, hdtdx, dt, u1, v1, d1);
    } else {
      advect_point<1>(Ub, Vb, Db, r, j, hdtdx, dt, u1, v1, d1);
      int gi = r*NN + j;
      Uo[gi] = u1; Vo[gi] = v1; Do_[gi] = d1;
      Vs[k][j] = v1;
    }
    u1r[kk] = u1;
  }
  __syncthreads();

  {  // div (backward diff) -> bit-reversed scatter (padded)
    int jm1 = (j - 1) & NM, rj = rev8(j);
    #pragma unroll
    for (int m = 0; m < 4; ++m) {
      int k = h*4 + m;
      float dv = (u1r[m+1] - u1r[m] + Vs[k][j] - Vs[k][jm1]) * RDX;
      AbS[k*ROWF2 + pdx(rj)] = make_float2(dv, 0.0f);
    }
  }
  __syncthreads();

  // fwd row FFT: 8 teams x 64 lanes
  const int g = tid >> 6, lane = tid & 63;
  fft256_dit_fwd<64>(AbS + g*ROWF2, lane, tw, true);
  __syncthreads();

  float2* Sb = S + b*FIELD;
  #pragma unroll
  for (int k = 0; k < 4; ++k) {
    int row = h*4 + k;
    Sb[(row0 + row)*NN + j] = AbS[row*ROWF2 + pdx(j)];
  }
}

// ================================================================ K2 (R9 fallback)
__global__ __launch_bounds__(512) void fft_cols_r9(float2* __restrict__ S)
{
  __shared__ float2 Ab[8*ROWF2];
  __shared__ float2 tw[128];
  __shared__ float  lam[NN];
  int tid = threadIdx.x;
  int b = blockIdx.x >> 5;
  int col0 = (blockIdx.x & 31) << 3;

  if (tid < 128) {
    float sw, cw;
    __sincosf(-0.02454369260617026f * (float)tid, &sw, &cw);
    tw[tid] = make_float2(cw, sw);
  }
  if (tid < 256) {
    float s1 = __sinf(0.01227184630308512983f * (float)tid);   // pi/256 * k
    lam[tid] = -4.0f * s1 * s1 * (RDX*RDX);
  }

  float2* Sb = S + b*FIELD;
  #pragma unroll
  for (int k = 0; k < 4; ++k) {        // load transposed, bit-reversed
    int idx = tid + (k << 9);
    int i = idx >> 3, c = idx & 7;
    Ab[c*ROWF2 + pdx(rev8(i))] = Sb[i*NN + col0 + c];
  }
  __syncthreads();                     // cross-wave: scatter -> per-wave FFT

  int g = tid >> 6, lane = tid & 63;   // wave g owns column-row g
  fft256_dit_fwd<64>(Ab + g*ROWF2, lane, tw, true);

  float l2 = lam[col0 + g];
  #pragma unroll
  for (int r = 0; r < 4; ++r) {
    int k1 = lane + (r << 6);
    float den = lam[k1] + l2;
    float sc = ((k1 | (col0 + g)) == 0) ? 0.0f : (1.0f/den);
    sc *= (1.0f/65536.0f);             // fold in ifft2's 1/N^2
    float2 v = Ab[g*ROWF2 + pdx(k1)];
    Ab[g*ROWF2 + pdx(k1)] = make_float2(v.x*sc, v.y*sc);
  }
  wave_sync();

  fft256_dif_inv<64>(Ab + g*ROWF2, lane, tw, true);
  __syncthreads();                     // cross-wave: FFT rows -> store

  #pragma unroll
  for (int k = 0; k < 4; ++k) {        // store transposed, un-reversed
    int idx = tid + (k << 9);
    int i = idx >> 3, c = idx & 7;
    Sb[i*NN + col0 + c] = Ab[c*ROWF2 + pdx(rev8(i))];
  }
}

// ================================================================ K3 (final correction)
__global__ __launch_bounds__(512) void fft_inv_correct(
    const float2* __restrict__ S, float* __restrict__ outb)
{
  __shared__ float2 Ab[9*ROWF2];
  __shared__ float  qs[9*NN];
  __shared__ float2 tw[128];
  int tid = threadIdx.x;
  int b = blockIdx.x >> 5;
  int row0 = (blockIdx.x & 31) << 3;

  if (tid < 128) {
    float sw, cw;
    __sincosf(-0.02454369260617026f * (float)tid, &sw, &cw);
    tw[tid] = make_float2(cw, sw);
  }

  const float2* Sb = S + b*FIELD;
  #pragma unroll
  for (int m = 0; m < 5; ++m) {        // load 9 rows, natural order (DIF in)
    int e = tid + m*512;
    if (e < 9*NN) {
      int k = e >> 8, j = e & 255;
      Ab[k*ROWF2 + pdx(j)] = Sb[((row0 + k) & NM)*NN + j];
    }
  }
  __syncthreads();

  int g = tid >> 5, lane = tid & 31;   // 16 teams of 32; 9 active
  bool active = (g < 9);
  fft256_dif_inv<32>(Ab + (active ? g : 8)*ROWF2, lane, tw, active);
  __syncthreads();

  #pragma unroll
  for (int m = 0; m < 5; ++m) {        // un-reverse gather -> qs natural
    int e = tid + m*512;
    if (e < 9*NN) {
      int k = e >> 8, j = e & 255;
      qs[k*NN + j] = Ab[k*ROWF2 + pdx(rev8(j))].x;
    }
  }
  __syncthreads();

  float* Ug = outb + b*FIELD;
  float* Vg = outb + TOTAL + b*FIELD;
  #pragma unroll
  for (int m = 0; m < 4; ++m) {
    int e = tid + m*512;               // 0..2047
    int k = e >> 8, j = e & 255;
    int gi = (row0 + k)*NN + j;
    float q0 = qs[k*NN + j];
    float q1 = qs[(k+1)*NN + j];
    float qj = qs[k*NN + ((j+1) & NM)];
    Ug[gi] -= (q1 - q0)*RDX;
    Vg[gi] -= (qj - q0)*RDX;
  }
}

// ================================================================ misc
__global__ __launch_bounds__(256) void write_out_k(
    const float* __restrict__ U, const float* __restrict__ V, const float* __restrict__ D,
    float* __restrict__ out, int t, int T)
{
  int idx = blockIdx.x*256 + threadIdx.x;
  int b = idx >> 16;
  int pos = idx & (FIELD-1);
  size_t o = ((size_t)(b*T + t)*FIELD + pos)*3u;
  out[o]   = U[idx];
  out[o+1] = V[idx];
  out[o+2] = D[idx];
}

__global__ __launch_bounds__(256) void init_state(
    const float* __restrict__ y0,
    float* __restrict__ U, float* __restrict__ V, float* __restrict__ D)
{
  int idx = blockIdx.x*256 + threadIdx.x;
  U[idx] = y0[idx*3];
  V[idx] = y0[idx*3+1];
  D[idx] = y0[idx*3+2];
}

// ================================================================ fallback
// R5-proven sincos/unpadded kernels (used only if ws too small).
__device__ __forceinline__ void fft_fwd_sc(float2* A, int lane) {
  #pragma unroll
  for (int s = 1; s <= 8; ++s) {
    int half = 1 << (s-1);
    float angscale = -6.28318530717958647692f / (float)(2*half);
    #pragma unroll
    for (int r = 0; r < 4; ++r) {
      int bfly = lane + (r << 5);
      int q = bfly & (half - 1);
      int g = (bfly >> (s-1)) << s;
      float sw, cw; __sincosf(angscale * (float)q, &sw, &cw);
      float2 a = A[g+q], b = A[g+q+half];
      float wbx = cw*b.x - sw*b.y, wby = cw*b.y + sw*b.x;
      A[g+q] = make_float2(a.x+wbx, a.y+wby);
      A[g+q+half] = make_float2(a.x-wbx, a.y-wby);
    }
    __syncthreads();
  }
}
__device__ __forceinline__ void fft_inv_sc(float2* A, int lane) {
  #pragma unroll
  for (int s = 8; s >= 1; --s) {
    int half = 1 << (s-1);
    float angscale = 6.28318530717958647692f / (float)(2*half);
    #pragma unroll
    for (int r = 0; r < 4; ++r) {
      int bfly = lane + (r << 5);
      int q = bfly & (half - 1);
      int g = (bfly >> (s-1)) << s;
      float sw, cw; __sincosf(angscale * (float)q, &sw, &cw);
      float2 a = A[g+q], b = A[g+q+half];
      float dx = a.x-b.x, dy = a.y-b.y;
      A[g+q] = make_float2(a.x+b.x, a.y+b.y);
      A[g+q+half] = make_float2(cw*dx - sw*dy, cw*dy + sw*dx);
    }
    __syncthreads();
  }
}

__global__ __launch_bounds__(256) void advect_kernel_fb(
    const float* __restrict__ U, const float* __restrict__ V, const float* __restrict__ D,
    float* __restrict__ Uo, float* __restrict__ Vo, float* __restrict__ Do_,
    const unsigned* __restrict__ dtw)
{
  int idx = blockIdx.x*256 + threadIdx.x;
  int j = idx & NM, i = (idx >> 8) & NM, base = (idx >> 16) * FIELD;
  float dt = decode_dt(dtw);
  float u1, v1, d1;
  advect_point<1>(U + base, V + base, D + base, i, j, 0.5f*dt*RDX, dt, u1, v1, d1);
  Uo[idx] = u1; Vo[idx] = v1; Do_[idx] = d1;
}

__global__ __launch_bounds__(256) void fft_rows_div_fb(
    const float* __restrict__ U2, const float* __restrict__ V2, float2* __restrict__ S)
{
  __shared__ float2 Ab[8*NN];
  int tid = threadIdx.x, b = blockIdx.x >> 5, row0 = (blockIdx.x & 31) << 3;
  const float* Ub = U2 + b*FIELD;
  const float* Vb = V2 + b*FIELD;
  int jm1 = (tid - 1) & NM, rj = rev8(tid);
  #pragma unroll
  for (int k = 0; k < 8; ++k) {
    int row = row0 + k, rm1 = (row - 1) & NM;
    float dv = (Ub[row*NN + tid] - Ub[rm1*NN + tid]
              + Vb[row*NN + tid] - Vb[row*NN + jm1]) * RDX;
    Ab[(k<<8) + rj] = make_float2(dv, 0.0f);
  }
  __syncthreads();
  int g = tid >> 5, lane = tid & 31;
  fft_fwd_sc(Ab + (g<<8), lane);
  float2* Sb = S + b*FIELD;
  #pragma unroll
  for (int k = 0; k < 8; ++k)
    Sb[(row0 + k)*NN + tid] = Ab[(k<<8) + tid];
}

__global__ __launch_bounds__(256) void fft_cols_fb(float2* __restrict__ S)
{
  __shared__ float2 Ab[8*NN];
  int tid = threadIdx.x, b = blockIdx.x >> 5, col0 = (blockIdx.x & 31) << 3;
  float2* Sb = S + b*FIELD;
  #pragma unroll
  for (int k = 0; k < 8; ++k) {
    int idx = tid + (k << 8);
    int i = idx >> 3, c = idx & 7;
    Ab[(c<<8) + rev8(i)] = Sb[i*NN + col0 + c];
  }
  __syncthreads();
  int g = tid >> 5, lane = tid & 31;
  fft_fwd_sc(Ab + (g<<8), lane);
  int k2 = col0 + g;
  float s2 = __sinf(0.01227184630308512983f * (float)k2);
  float l2 = -4.0f * s2 * s2 * (RDX*RDX);
  #pragma unroll
  for (int r = 0; r < 8; ++r) {
    int k1 = lane + (r << 5);
    float s1 = __sinf(0.01227184630308512983f * (float)k1);
    float l1 = -4.0f * s1 * s1 * (RDX*RDX);
    float den = l1 + l2;
    float sc = ((k1 | k2) == 0) ? 0.0f : (1.0f/den);
    sc *= (1.0f/65536.0f);
    float2 v = Ab[(g<<8) + k1];
    Ab[(g<<8) + k1] = make_float2(v.x*sc, v.y*sc);
  }
  __syncthreads();
  fft_inv_sc(Ab + (g<<8), lane);
  #pragma unroll
  for (int k = 0; k < 8; ++k) {
    int idx = tid + (k << 8);
    int i = idx >> 3, c = idx & 7;
    Sb[i*NN + col0 + c] = Ab[(c<<8) + rev8(i)];
  }
}

__global__ __launch_bounds__(256) void fft_rows_inv_fb(
    const float2* __restrict__ S, float* __restrict__ Q)
{
  __shared__ float2 Ab[8*NN];
  int tid = threadIdx.x, b = blockIdx.x >> 5, row0 = (blockIdx.x & 31) << 3;
  const float2* Sb = S + b*FIELD;
  #pragma unroll
  for (int k = 0; k < 8; ++k)
    Ab[(k<<8) + tid] = Sb[(row0 + k)*NN + tid];
  __syncthreads();
  int g = tid >> 5, lane = tid & 31;
  fft_inv_sc(Ab + (g<<8), lane);
  float* Qb = Q + b*FIELD;
  int rj = rev8(tid);
  #pragma unroll
  for (int k = 0; k < 8; ++k)
    Qb[(row0 + k)*NN + tid] = Ab[(k<<8) + rj].x;
}

__global__ __launch_bounds__(256) void correct_uv_fb(
    float* __restrict__ U2, float* __restrict__ V2, const float* __restrict__ Q)
{
  int idx = blockIdx.x*256 + threadIdx.x;
  int j = idx & NM, i = (idx >> 8) & NM, base = (idx >> 16) * FIELD;
  const float* Qb = Q + base;
  float q0 = Qb[i*NN + j];
  float qi = Qb[((i+1)&NM)*NN + j];
  float qj = Qb[i*NN + ((j+1)&NM)];
  U2[idx] -= (qi - q0)*RDX;
  V2[idx] -= (qj - q0)*RDX;
}

// ---------------------------------------------------------------- launch
extern "C" void kernel_launch(void* const* d_in, const int* in_sizes, int n_in,
                              void* d_out, int out_size, void* d_ws, size_t ws_size,
                              hipStream_t stream) {
  (void)in_sizes; (void)n_in;
  const float*    y0  = (const float*)d_in[0];
  const unsigned* dtw = (const unsigned*)d_in[1];
  float* out = (float*)d_out;

  int T = out_size / (3*FIELD*BATCH);
  if (T < 1) T = 1;

  float* wsf = (float*)d_ws;

  // ---- preferred: fused 2-kernel/step path (needs 10*TOTAL floats) ----
  if (ws_size >= (size_t)10*TOTAL*sizeof(float)) {
    float* stA = wsf;                  // 3*TOTAL
    float* stB = wsf + 3*TOTAL;        // 3*TOTAL
    float2* Sa = (float2*)(wsf + 6*TOTAL);   // TOTAL float2
    float2* Sc = (float2*)(wsf + 8*TOTAL);   // TOTAL float2

    init_state<<<TOTAL/256, 256, 0, stream>>>(y0, stA, stA+TOTAL, stA+2*TOTAL);
    float* inb  = stA;
    float* outb = stB;
    float2* Sr = Sa;                   // spectral q from previous step
    float2* Sw = Sc;                   // new div spectral
    int step = 0;
    for (int t = 0; t < T; ++t) {
      for (int s = 0; s < 10; ++s) {
        int tm1 = (s == 0) ? (t - 1) : -1;
        proj_advect_fft8<<<256, 1024, 0, stream>>>(Sr, inb, outb, Sw, out,
                                                   dtw, T, tm1, step == 0);
        fft_cols<<<256, 512, 0, stream>>>(Sw);
        float*  t1 = inb; inb = outb; outb = t1;
        float2* t2 = Sr;  Sr  = Sw;   Sw  = t2;
        ++step;
      }
    }
    // final state in inb is uncorrected; Sr holds its Poisson solution
    fft_inv_correct<<<256, 512, 0, stream>>>(Sr, inb);
    write_out_k<<<TOTAL/256, 256, 0, stream>>>(inb, inb+TOTAL, inb+2*TOTAL,
                                               out, T-1, T);
    return;
  }

  // ---- R9 3-kernel path (needs 8*TOTAL floats) ----
  if (ws_size >= (size_t)8*TOTAL*sizeof(float)) {
    float2* S = (float2*)(wsf + 6*TOTAL);
    init_state<<<TOTAL/256, 256, 0, stream>>>(y0, wsf, wsf+TOTAL, wsf+2*TOTAL);
    float* inb = wsf;
    float* outb = wsf + 3*TOTAL;
    for (int t = 0; t < T; ++t) {
      for (int s = 0; s < 10; ++s) {
        int tm1 = (s == 0) ? (t - 1) : -1;
        advect_div_fft <<<256, 512, 0, stream>>>(inb, outb, S, out, dtw, T, tm1);
        fft_cols_r9    <<<256, 512, 0, stream>>>(S);
        fft_inv_correct<<<256, 512, 0, stream>>>(S, outb);
        float* tmp = inb; inb = outb; outb = tmp;
      }
    }
    write_out_k<<<TOTAL/256, 256, 0, stream>>>(inb, inb+TOTAL, inb+2*TOTAL,
                                               out, T-1, T);
    return;
  }

  // ---- R5 5-kernel path with aliased S/Q (12.6 MB) ----
  float* bank0 = wsf;
  float* bank1 = wsf + 3*TOTAL;
  init_state<<<TOTAL/256, 256, 0, stream>>>(y0, bank0, bank0+TOTAL, bank0+2*TOTAL);
  float* inb = bank0;
  float* outb = bank1;
  for (int t = 0; t < T; ++t) {
    for (int s = 0; s < 10; ++s) {
      float *Ui = inb,  *Vi = inb + TOTAL,  *Di = inb + 2*TOTAL;
      float *Uo = outb, *Vo = outb + TOTAL, *Do_ = outb + 2*TOTAL;
      float2* S = (float2*)(inb + TOTAL);
      float*  Q = inb;
      advect_kernel_fb<<<TOTAL/256, 256, 0, stream>>>(Ui, Vi, Di, Uo, Vo, Do_, dtw);
      fft_rows_div_fb <<<BATCH*32, 256, 0, stream>>>(Uo, Vo, S);
      fft_cols_fb     <<<BATCH*32, 256, 0, stream>>>(S);
      fft_rows_inv_fb <<<BATCH*32, 256, 0, stream>>>(S, Q);
      correct_uv_fb   <<<TOTAL/256, 256, 0, stream>>>(Uo, Vo, Q);
      float* tmp = inb; inb = outb; outb = tmp;
    }
    write_out_k<<<TOTAL/256, 256, 0, stream>>>(inb, inb+TOTAL, inb+2*TOTAL, out, t, T);
  }
}

// Round 11
// 2000.094 us; speedup vs baseline: 1.0389x; 1.0389x over previous
//
#include <hip/hip_runtime.h>
#include <hip/hip_bf16.h>

// NS solver: 256x256 periodic, B=8, NC=3 (u,v,density), T outer x 10 inner steps.
// y0 = fp32, dt = fp32, out = fp32 (established R1-R5). Internal state fp32.
//
// R20: radix-16 rounds in A. R19 (radix-16 B) was neutral -> B wasn't the
// chain; A is LDS-throughput-bound (~1.9 MB LDS/block, 75% in its two FFT
// passes). Apply the R19-hardware-verified r16_* helpers to A:
//   phase 1 (inv, 14 rows): 2 rounds (inv_high stride-16, inv_low 16-blocks)
//   phase 5 (fwd, 8 rows):  2 rounds (fwd_low 16-blocks, fwd_high stride-16)
// 16-lane groups, cross-round exchange intra-wave -> wave_sync only.
// B reverted to R17 measured-best f2 form (single-change discipline).
// Same butterflies/order/twiddles -> numerics match prior rounds.

#define NN 256
#define NM 255
#define FIELD (NN*NN)
#define BATCH 8
#define TOTAL (BATCH*FIELD)
#define ROWF2 264   // padded LDS row stride in float2 (256 + 8)

constexpr float RDX  = 40.743665431525205f;   // N/(2*pi) = 1/DX
constexpr float VISC = 1e-3f;

__device__ __forceinline__ int rev8(int x) { return (int)(__brev((unsigned)x) >> 24); }
__device__ __forceinline__ int pdx(int x)  { return x + (x >> 5); }

// Intra-wave LDS exchange fence (R13-verified on gfx950): compiler fence +
// sched barrier. A wave's DS ops complete in program order -> no s_barrier
// needed when producer and consumer lanes share a wave.
__device__ __forceinline__ void wave_sync() {
  asm volatile("" ::: "memory");
  __builtin_amdgcn_wave_barrier();
}

__device__ __forceinline__ float decode_dt(const unsigned* dtw) {
  unsigned w = dtw[0];
  float cf = __uint_as_float(w);
  float cb = __uint_as_float((w & 0xFFFFu) << 16);
  bool v32 = (cf > 1e-8f) && (cf < 1.0f);          // NaN-safe
  bool vbf = (cb > 1e-8f) && (cb < 1.0f);
  return v32 ? cf : (vbf ? cb : 1e-3f);
}

// ---------------------------------------------------------------- advection
__device__ __forceinline__ float face_flux(float uf, float cm, float c0,
                                           float cp, float cpp, float hdtdx) {
  float dc = cp - c0;
  float f_low  = (uf >= 0.0f) ? uf*c0 : uf*cp;
  float f_high = uf*0.5f*(c0+cp) - hdtdx*uf*uf*dc;
  float dc_up  = (uf >= 0.0f) ? (c0 - cm) : (cpp - cp);
  float dc_safe = (fabsf(dc) > 1e-12f) ? dc : 1e-12f;
  // van Leer: (a*b>0) ? 2a/(a+b) : 0
  float phi = (dc_up * dc_safe > 0.0f) ? (2.0f*dc_up/(dc_up + dc_safe)) : 0.0f;
  return f_low + phi*(f_high - f_low);
}

// global-memory stencil variant (fallback paths)
template<int NEED_VD>
__device__ __forceinline__ void advect_point(
    const float* __restrict__ Ub, const float* __restrict__ Vb,
    const float* __restrict__ Db,
    int i, int j, float hdtdx, float dt,
    float& u1, float& v1, float& d1)
{
  int im2 = ((i-2)&NM)*NN, im1 = ((i-1)&NM)*NN, i0r = i*NN,
      ip1 = ((i+1)&NM)*NN, ip2 = ((i+2)&NM)*NN;
  int jm2 = (j-2)&NM, jm1 = (j-1)&NM, jp1 = (j+1)&NM, jp2 = (j+2)&NM;

  float u_c  = Ub[i0r+j];
  float u_im2= Ub[im2+j], u_im1 = Ub[im1+j], u_ip1 = Ub[ip1+j], u_ip2 = Ub[ip2+j];
  float u_jm2= Ub[i0r+jm2], u_jm1 = Ub[i0r+jm1], u_jp1 = Ub[i0r+jp1], u_jp2 = Ub[i0r+jp2];
  float v_c  = Vb[i0r+j];
  float v_jm1= Vb[i0r+jm1], v_jp1 = Vb[i0r+jp1];

  float ufI0 = 0.5f*(u_c + u_ip1);
  float ufIm = 0.5f*(u_im1 + u_c);
  float vfJ0 = 0.5f*(v_c + v_jp1);
  float vfJm = 0.5f*(v_jm1 + v_c);

  float tu = -(( face_flux(ufI0, u_im1, u_c, u_ip1, u_ip2, hdtdx)
               - face_flux(ufIm, u_im2, u_im1, u_c, u_ip1, hdtdx))
             + ( face_flux(vfJ0, u_jm1, u_c, u_jp1, u_jp2, hdtdx)
               - face_flux(vfJm, u_jm2, u_jm1, u_c, u_jp1, hdtdx))) * RDX;
  float lapu = (u_im1 + u_ip1 + u_jm1 + u_jp1 - 4.0f*u_c) * (RDX*RDX);
  u1 = u_c + dt*(tu + VISC*lapu);

  if (NEED_VD) {
    float v_im2= Vb[im2+j], v_im1 = Vb[im1+j], v_ip1 = Vb[ip1+j], v_ip2 = Vb[ip2+j];
    float v_jm2= Vb[i0r+jm2], v_jp2 = Vb[i0r+jp2];
    float d_c  = Db[i0r+j];
    float d_im2= Db[im2+j], d_im1 = Db[im1+j], d_ip1 = Db[ip1+j], d_ip2 = Db[ip2+j];
    float d_jm2= Db[i0r+jm2], d_jm1 = Db[i0r+jm1], d_jp1 = Db[i0r+jp1], d_jp2 = Db[i0r+jp2];

    float tv = -(( face_flux(ufI0, v_im1, v_c, v_ip1, v_ip2, hdtdx)
                 - face_flux(ufIm, v_im2, v_im1, v_c, v_ip1, hdtdx))
               + ( face_flux(vfJ0, v_jm1, v_c, v_jp1, v_jp2, hdtdx)
                 - face_flux(vfJm, v_jm2, v_jm1, v_c, v_jp1, hdtdx))) * RDX;
    float lapv = (v_im1 + v_ip1 + v_jm1 + v_jp1 - 4.0f*v_c) * (RDX*RDX);
    v1 = v_c + dt*(tv + VISC*lapv);

    float td = -(( face_flux(ufI0, d_im1, d_c, d_ip1, d_ip2, hdtdx)
                 - face_flux(ufIm, d_im2, d_im1, d_c, d_ip1, hdtdx))
               + ( face_flux(vfJ0, d_jm1, d_c, d_jp1, d_jp2, hdtdx)
                 - face_flux(vfJm, d_jm2, d_jm1, d_c, d_jp1, hdtdx))) * RDX;
    d1 = d_c + dt*td;
  }
}

// LDS-slab stencil variant (fused A kernel). ku = u-slab row of the point,
// kv = v/d-slab row of the point. Slabs are contiguous (no row wrap); j wraps.
template<int NEED_VD>
__device__ __forceinline__ void advect_point_lds(
    const float* __restrict__ U, const float* __restrict__ V,
    const float* __restrict__ D,
    int ku, int kv, int j, float hdtdx, float dt,
    float& u1, float& v1, float& d1)
{
  int jm2 = (j-2)&NM, jm1 = (j-1)&NM, jp1 = (j+1)&NM, jp2 = (j+2)&NM;

  const float* Ur = U + ku*NN;
  float u_c  = Ur[j];
  float u_im2= U[(ku-2)*NN+j], u_im1 = U[(ku-1)*NN+j],
        u_ip1= U[(ku+1)*NN+j], u_ip2 = U[(ku+2)*NN+j];
  float u_jm2= Ur[jm2], u_jm1 = Ur[jm1], u_jp1 = Ur[jp1], u_jp2 = Ur[jp2];
  const float* Vr = V + kv*NN;
  float v_c  = Vr[j];
  float v_jm1= Vr[jm1], v_jp1 = Vr[jp1];

  float ufI0 = 0.5f*(u_c + u_ip1);
  float ufIm = 0.5f*(u_im1 + u_c);
  float vfJ0 = 0.5f*(v_c + v_jp1);
  float vfJm = 0.5f*(v_jm1 + v_c);

  float tu = -(( face_flux(ufI0, u_im1, u_c, u_ip1, u_ip2, hdtdx)
               - face_flux(ufIm, u_im2, u_im1, u_c, u_ip1, hdtdx))
             + ( face_flux(vfJ0, u_jm1, u_c, u_jp1, u_jp2, hdtdx)
               - face_flux(vfJm, u_jm2, u_jm1, u_c, u_jp1, hdtdx))) * RDX;
  float lapu = (u_im1 + u_ip1 + u_jm1 + u_jp1 - 4.0f*u_c) * (RDX*RDX);
  u1 = u_c + dt*(tu + VISC*lapu);

  if (NEED_VD) {
    float v_im2= V[(kv-2)*NN+j], v_im1 = V[(kv-1)*NN+j],
          v_ip1= V[(kv+1)*NN+j], v_ip2 = V[(kv+2)*NN+j];
    float v_jm2= Vr[jm2], v_jp2 = Vr[jp2];
    const float* Dr = D + kv*NN;
    float d_c  = Dr[j];
    float d_im2= D[(kv-2)*NN+j], d_im1 = D[(kv-1)*NN+j],
          d_ip1= D[(kv+1)*NN+j], d_ip2 = D[(kv+2)*NN+j];
    float d_jm2= Dr[jm2], d_jm1 = Dr[jm1], d_jp1 = Dr[jp1], d_jp2 = Dr[jp2];

    float tv = -(( face_flux(ufI0, v_im1, v_c, v_ip1, v_ip2, hdtdx)
                 - face_flux(ufIm, v_im2, v_im1, v_c, v_ip1, hdtdx))
               + ( face_flux(vfJ0, v_jm1, v_c, v_jp1, v_jp2, hdtdx)
                 - face_flux(vfJm, v_jm2, v_jm1, v_c, v_jp1, hdtdx))) * RDX;
    float lapv = (v_im1 + v_ip1 + v_jm1 + v_jp1 - 4.0f*v_c) * (RDX*RDX);
    v1 = v_c + dt*(tv + VISC*lapv);

    float td = -(( face_flux(ufI0, d_im1, d_c, d_ip1, d_ip2, hdtdx)
                 - face_flux(ufIm, d_im2, d_im1, d_c, d_ip1, hdtdx))
               + ( face_flux(vfJ0, d_jm1, d_c, d_jp1, d_jp2, hdtdx)
                 - face_flux(vfJm, d_jm2, d_jm1, d_c, d_jp1, hdtdx))) * RDX;
    d1 = d_c + dt*td;
  }
}

// ---------------------------------------------------------------- FFT cores
// Table-driven, padded-LDS. tw[m] = exp(-2*pi*i*m/256), m<128. Stage-s
// twiddle = tw[q<<(8-s)] (fwd), conjugate for inverse. A = padded row base;
// element x lives at A[pdx(x)].
// WAVE-SYNCHRONOUS (R13): exchanges within a wave need only wave_sync().
//
// RADIX-16 ROUNDS (R19-HW-verified helpers): stages 1-4 confined to
// contiguous 16-blocks, stages 5-8 to stride-16 residue classes. One lane
// holds 16 float2 in regs -> 4 stages per LDS round -> 2 rounds per 256-pt
// FFT direction. Same butterflies/order/twiddles as the radix-2 network.

// --- radix-16 in-register stage groups (lane-local x[16]) ---
__device__ __forceinline__ void r16_fwd_low(float2* x, const float2* tw) {
  #pragma unroll
  for (int s = 1; s <= 4; ++s) {
    int h = 1 << (s-1);
    #pragma unroll
    for (int b = 0; b < 8; ++b) {
      int q = b & (h-1);
      int t = ((b >> (s-1)) << s) + q;
      float2 w = tw[q << (8-s)];
      float2 a = x[t], c = x[t+h];
      float wbx = w.x*c.x - w.y*c.y, wby = w.x*c.y + w.y*c.x;
      x[t]   = make_float2(a.x+wbx, a.y+wby);
      x[t+h] = make_float2(a.x-wbx, a.y-wby);
    }
  }
}
__device__ __forceinline__ void r16_fwd_high(float2* x, int r, const float2* tw) {
  #pragma unroll
  for (int s = 5; s <= 8; ++s) {
    int hp = 1 << (s-5);
    #pragma unroll
    for (int b = 0; b < 8; ++b) {
      int qp = b & (hp-1);
      int t = ((b >> (s-5)) << (s-4)) + qp;
      float2 w = tw[(r + (qp<<4)) << (8-s)];
      float2 a = x[t], c = x[t+hp];
      float wbx = w.x*c.x - w.y*c.y, wby = w.x*c.y + w.y*c.x;
      x[t]    = make_float2(a.x+wbx, a.y+wby);
      x[t+hp] = make_float2(a.x-wbx, a.y-wby);
    }
  }
}
__device__ __forceinline__ void r16_inv_high(float2* x, int r, const float2* tw) {
  #pragma unroll
  for (int s = 8; s >= 5; --s) {
    int hp = 1 << (s-5);
    #pragma unroll
    for (int b = 0; b < 8; ++b) {
      int qp = b & (hp-1);
      int t = ((b >> (s-5)) << (s-4)) + qp;
      float2 w = tw[(r + (qp<<4)) << (8-s)];
      float2 a = x[t], c = x[t+hp];
      float dx = a.x-c.x, dy = a.y-c.y;
      x[t]    = make_float2(a.x+c.x, a.y+c.y);
      x[t+hp] = make_float2(w.x*dx + w.y*dy, w.x*dy - w.y*dx);
    }
  }
}
__device__ __forceinline__ void r16_inv_low(float2* x, const float2* tw) {
  #pragma unroll
  for (int s = 4; s >= 1; --s) {
    int h = 1 << (s-1);
    #pragma unroll
    for (int b = 0; b < 8; ++b) {
      int q = b & (h-1);
      int t = ((b >> (s-1)) << s) + q;
      float2 w = tw[q << (8-s)];
      float2 a = x[t], c = x[t+h];
      float dx = a.x-c.x, dy = a.y-c.y;
      x[t]   = make_float2(a.x+c.x, a.y+c.y);
      x[t+h] = make_float2(w.x*dx + w.y*dy, w.x*dy - w.y*dx);
    }
  }
}

// --- R17 fused 2-stage rounds (B kernel) ---
// fwd DIT, fused stage pairs (1,2),(3,4),(5,6),(7,8). lane in [0,64).
__device__ __forceinline__ void fft256_fwd_f2(float2* __restrict__ A, int lane,
                                              const float2* __restrict__ tw,
                                              bool active)
{
  #pragma unroll
  for (int s = 1; s <= 8; s += 2) {
    if (active) {
      int half = 1 << (s-1);
      int q2 = lane & (half - 1);
      int i0 = ((lane >> (s-1)) << (s+1)) + q2;
      float2 a0 = A[pdx(i0)];
      float2 a1 = A[pdx(i0 + half)];
      float2 a2 = A[pdx(i0 + 2*half)];
      float2 a3 = A[pdx(i0 + 3*half)];
      // stage s: pairs (a0,a1),(a2,a3), twiddle tw[q2<<(8-s)]
      float2 w1 = tw[q2 << (8 - s)];
      float wbx = w1.x*a1.x - w1.y*a1.y, wby = w1.x*a1.y + w1.y*a1.x;
      float2 b0 = make_float2(a0.x + wbx, a0.y + wby);
      float2 b1 = make_float2(a0.x - wbx, a0.y - wby);
      wbx = w1.x*a3.x - w1.y*a3.y; wby = w1.x*a3.y + w1.y*a3.x;
      float2 b2 = make_float2(a2.x + wbx, a2.y + wby);
      float2 b3 = make_float2(a2.x - wbx, a2.y - wby);
      // stage s+1: pairs (b0,b2) tw[q2<<(7-s)], (b1,b3) tw[(q2+half)<<(7-s)]
      float2 w2 = tw[q2 << (7 - s)];
      float2 w3 = tw[(q2 + half) << (7 - s)];
      wbx = w2.x*b2.x - w2.y*b2.y; wby = w2.x*b2.y + w2.y*b2.x;
      A[pdx(i0)]            = make_float2(b0.x + wbx, b0.y + wby);
      A[pdx(i0 + 2*half)]   = make_float2(b0.x - wbx, b0.y - wby);
      wbx = w3.x*b3.x - w3.y*b3.y; wby = w3.x*b3.y + w3.y*b3.x;
      A[pdx(i0 + half)]     = make_float2(b1.x + wbx, b1.y + wby);
      A[pdx(i0 + 3*half)]   = make_float2(b1.x - wbx, b1.y - wby);
    }
    wave_sync();
  }
}

// inv DIF, fused stage pairs (8,7),(6,5),(4,3),(2,1). lane in [0,64).
__device__ __forceinline__ void fft256_inv_f2(float2* __restrict__ A, int lane,
                                              const float2* __restrict__ tw,
                                              bool active)
{
  #pragma unroll
  for (int s = 8; s >= 2; s -= 2) {
    if (active) {
      int h = 1 << (s-2);              // half of stage s-1
      int q2 = lane & (h - 1);
      int i0 = ((lane >> (s-2)) << s) + q2;
      float2 a0 = A[pdx(i0)];
      float2 a1 = A[pdx(i0 + h)];
      float2 a2 = A[pdx(i0 + 2*h)];
      float2 a3 = A[pdx(i0 + 3*h)];
      // stage s (half=2h): pairs (a0,a2) q=q2, (a1,a3) q=q2+h
      float2 w1 = tw[q2 << (8 - s)];
      float2 w2 = tw[(q2 + h) << (8 - s)];
      float dx = a0.x - a2.x, dy = a0.y - a2.y;
      float2 b0 = make_float2(a0.x + a2.x, a0.y + a2.y);
      float2 b2 = make_float2(w1.x*dx + w1.y*dy, w1.x*dy - w1.y*dx);
      dx = a1.x - a3.x; dy = a1.y - a3.y;
      float2 b1 = make_float2(a1.x + a3.x, a1.y + a3.y);
      float2 b3 = make_float2(w2.x*dx + w2.y*dy, w2.x*dy - w2.y*dx);
      // stage s-1 (half=h): pairs (b0,b1) and (b2,b3), both q=q2
      float2 w3 = tw[q2 << (9 - s)];
      dx = b0.x - b1.x; dy = b0.y - b1.y;
      A[pdx(i0)]       = make_float2(b0.x + b1.x, b0.y + b1.y);
      A[pdx(i0 + h)]   = make_float2(w3.x*dx + w3.y*dy, w3.x*dy - w3.y*dx);
      dx = b2.x - b3.x; dy = b2.y - b3.y;
      A[pdx(i0 + 2*h)] = make_float2(b2.x + b3.x, b2.y + b3.y);
      A[pdx(i0 + 3*h)] = make_float2(w3.x*dx + w3.y*dy, w3.x*dy - w3.y*dx);
    }
    wave_sync();
  }
}

// Legacy single-stage variants (fallback paths + final correction kernel).
template<int W>
__device__ __forceinline__ void fft256_dit_fwd(float2* __restrict__ A, int lane,
                                               const float2* __restrict__ tw,
                                               bool active)
{
  #pragma unroll
  for (int s = 1; s <= 8; ++s) {
    int half = 1 << (s-1);
    if (active) {
      #pragma unroll
      for (int r = 0; r < 128/W; ++r) {
        int bfly = lane + r*W;
        int q = bfly & (half - 1);
        int g = (bfly >> (s-1)) << s;
        float2 w = tw[q << (8 - s)];
        float2 a = A[pdx(g + q)];
        float2 b = A[pdx(g + q + half)];
        float wbx = w.x*b.x - w.y*b.y;
        float wby = w.x*b.y + w.y*b.x;
        A[pdx(g + q)]        = make_float2(a.x + wbx, a.y + wby);
        A[pdx(g + q + half)] = make_float2(a.x - wbx, a.y - wby);
      }
    }
    wave_sync();
  }
}

template<int W>
__device__ __forceinline__ void fft256_dif_inv(float2* __restrict__ A, int lane,
                                               const float2* __restrict__ tw,
                                               bool active)
{
  #pragma unroll
  for (int s = 8; s >= 1; --s) {
    int half = 1 << (s-1);
    if (active) {
      #pragma unroll
      for (int r = 0; r < 128/W; ++r) {
        int bfly = lane + r*W;
        int q = bfly & (half - 1);
        int g = (bfly >> (s-1)) << s;
        float2 w = tw[q << (8 - s)];      // conj applied below (inverse)
        float2 a = A[pdx(g + q)];
        float2 b = A[pdx(g + q + half)];
        float dx = a.x - b.x, dy = a.y - b.y;
        A[pdx(g + q)]        = make_float2(a.x + b.x, a.y + b.y);
        A[pdx(g + q + half)] = make_float2(w.x*dx + w.y*dy, w.x*dy - w.y*dx);
      }
    }
    wave_sync();
  }
}

// ================================================================ A (fused, 8-row, 1024 thr)
// 256 blocks x 1024 threads. Per block: batch b = bid>>5, rows row0..row0+7.
//  0. issue U/V/D global->reg staging loads (consumed in phase 2)
//  1. inv row FFT of 14 halo rows of S_prev (14 groups x 16 lanes, radix-16,
//     2 LDS rounds)
//  2. q gather; corrected u (13 rows), v (12), d (12) slabs in LDS (from regs)
//  3. optional trajectory write-out of corrected state t-1 (owned 8 rows)
//  4. advect from LDS: quarter q -> u-only row 2q-1, full rows 2q, 2q+1
//  5. div -> bit-rev scatter -> fwd row FFT (8 groups x 16, radix-16, 2
//     rounds) -> S_new
// Slab rows: q row k <-> global row0-3+k (k in [0,13])
//            u row k <-> global row0-3+k (k in [0,12])
//            v,d row k <-> global row0-2+k (k in [0,11])
// LDS aliasing (R12): Vs -> qs (dead after phase 2); Dss -> AbS rows 8..13
// (dead after phase 1; phase 5 uses rows 0..7). Total ~69 KB.
__global__ __launch_bounds__(1024) void proj_advect_fft8(
    const float2* __restrict__ Sprev, const float* __restrict__ inb,
    float* __restrict__ outb, float2* __restrict__ Snew,
    float* __restrict__ out, const unsigned* __restrict__ dtw,
    int T, int tm1, int first)
{
  __shared__ float2 tw[128];
  __shared__ float2 AbS[14*ROWF2];
  __shared__ float  qs [14*NN];
  __shared__ float  Ucs[13*NN];
  __shared__ float  Vcs[12*NN];
  float* Dss = (float*)(AbS + 8*ROWF2);  // 12*NN floats; phase-5 uses rows 0..7
  float* Vs  = qs;                       // 8*NN floats; qs dead after phase 2

  const int tid  = threadIdx.x;
  const int j    = tid & 255;
  const int qtr  = tid >> 8;           // 0..3
  const int b    = blockIdx.x >> 5;
  const int row0 = (blockIdx.x & 31) << 3;

  if (tid < 128) {
    float sw, cw;
    __sincosf(-0.02454369260617026f * (float)tid, &sw, &cw);  // -2pi/256
    tw[tid] = make_float2(cw, sw);
  }

  const float dt = decode_dt(dtw);
  const float hdtdx = 0.5f*dt*RDX;

  const float* Ub = inb + b*FIELD;
  const float* Vb = inb + TOTAL + b*FIELD;
  const float* Db = inb + 2*TOTAL + b*FIELD;
  float* Uo  = outb + b*FIELD;
  float* Vo  = outb + TOTAL + b*FIELD;
  float* Do_ = outb + 2*TOTAL + b*FIELD;

  // ---- phase 0: early global->reg staging (T14). Latency hides under phase 1.
  float u_reg[4], v_reg[3], d_reg[3];
  #pragma unroll
  for (int m = 0; m < 4; ++m) {        // U: 13 rows = 3328 elems
    int e = tid + (m << 10);
    if (e < 13*NN) {
      int k = e >> 8, jj = e & 255;
      u_reg[m] = Ub[((row0 - 3 + k) & NM)*NN + jj];
    }
  }
  #pragma unroll
  for (int m = 0; m < 3; ++m) {        // V, D: 12 rows = 3072 = 3*1024
    int e = tid + (m << 10);
    int k = e >> 8, jj = e & 255;
    int gr = ((row0 - 2 + k) & NM)*NN;
    v_reg[m] = Vb[gr + jj];
    d_reg[m] = Db[gr + jj];
  }

  // ---- phase 1: inv row FFT of 14 rows of S_prev -> qs (skip on step 0)
  if (!first) {
    const float2* Sb = Sprev + b*FIELD;
    #pragma unroll
    for (int m = 0; m < 4; ++m) {      // 14*256 = 3584 elems
      int e = tid + (m << 10);
      if (e < 14*NN) {
        int k = e >> 8, jj = e & 255;
        AbS[k*ROWF2 + pdx(jj)] = Sb[((row0 - 3 + k) & NM)*NN + jj];
      }
    }
    __syncthreads();                   // cross-wave: scatter -> FFT groups

    {
      const int g16 = tid >> 4;        // group = row 0..63; 14 active
      const int r   = tid & 15;        // lane role within group
      if (g16 < 14) {                  // round 1: inv stages 8-5 (stride-16)
        float2* Ar = AbS + g16*ROWF2;
        float2 x[16];
        #pragma unroll
        for (int k = 0; k < 16; ++k) x[k] = Ar[pdx(r + (k<<4))];
        r16_inv_high(x, r, tw);
        #pragma unroll
        for (int k = 0; k < 16; ++k) Ar[pdx(r + (k<<4))] = x[k];
      }
      wave_sync();
      if (g16 < 14) {                  // round 2: inv stages 4-1 (16-blocks)
        float2* Ar = AbS + g16*ROWF2;
        float2 x[16];
        #pragma unroll
        for (int t = 0; t < 16; ++t) x[t] = Ar[pdx((r<<4) + t)];
        r16_inv_low(x, tw);
        #pragma unroll
        for (int t = 0; t < 16; ++t) Ar[pdx((r<<4) + t)] = x[t];
      }
    }
    __syncthreads();                   // cross-wave: FFT rows -> qs gather

    #pragma unroll
    for (int m = 0; m < 4; ++m) {      // un-reverse gather -> qs natural
      int e = tid + (m << 10);
      if (e < 14*NN) {
        int k = e >> 8, jj = e & 255;
        qs[k*NN + jj] = AbS[k*ROWF2 + pdx(rev8(jj))].x;
      }
    }
    __syncthreads();
  } else {
    __syncthreads();                   // match table init visibility
  }

  // ---- phase 2: corrected u,v + d slabs in LDS (from staged registers)
  // (Dss writes land in AbS rows 8..13 -- dead scratch after phase 1.)
  #pragma unroll
  for (int m = 0; m < 4; ++m) {        // U: 13 rows
    int e = tid + (m << 10);
    if (e < 13*NN) {
      int k = e >> 8, jj = e & 255;
      Ucs[e] = first ? u_reg[m]
                     : (u_reg[m] - (qs[(k+1)*NN + jj] - qs[k*NN + jj])*RDX);
    }
  }
  #pragma unroll
  for (int m = 0; m < 3; ++m) {        // V, D: 12 rows
    int e = tid + (m << 10);
    int k = e >> 8, jj = e & 255;
    Vcs[e] = first ? v_reg[m]
                   : (v_reg[m] - (qs[(k+1)*NN + ((jj+1)&NM)] - qs[(k+1)*NN + jj])*RDX);
    Dss[e] = d_reg[m];
  }
  __syncthreads();                     // qs dead from here; Vs may reuse it

  // ---- phase 3: fused trajectory write-out of corrected state t-1
  if (tm1 >= 0) {
    #pragma unroll
    for (int m = 0; m < 2; ++m) {
      int e = tid + (m << 10);         // 8 owned rows x 256 = 2048
      int k = e >> 8, jj = e & 255;
      int pos = (row0 + k)*NN + jj;
      size_t o = ((size_t)(b*T + tm1)*FIELD + pos)*3u;
      out[o]   = Ucs[(k+3)*NN + jj];
      out[o+1] = Vcs[(k+2)*NN + jj];
      out[o+2] = Dss[(k+2)*NN + jj];
    }
  }

  // ---- phase 4: advect from LDS. Quarter qtr: u-only row 2q-1 (backward
  // halo for div), full rows 2q, 2q+1.
  const int kbeg = (qtr << 1) - 1;     // -1, 1, 3, 5
  float u1r[3];
  #pragma unroll
  for (int kk = 0; kk < 3; ++kk) {
    int k = kbeg + kk;                 // global row = row0 + k
    int ku = k + 3, kv = k + 2;
    float u1, v1, d1;
    if (kk == 0) {
      advect_point_lds<0>(Ucs, Vcs, Dss, ku, kv, j, hdtdx, dt, u1, v1, d1);
    } else {
      advect_point_lds<1>(Ucs, Vcs, Dss, ku, kv, j, hdtdx, dt, u1, v1, d1);
      int gi = (row0 + k)*NN + j;
      Uo[gi] = u1; Vo[gi] = v1; Do_[gi] = d1;
      Vs[k*NN + j] = v1;               // k in [0,7], owned
    }
    u1r[kk] = u1;
  }
  __syncthreads();                     // Vs visible across waves

  // ---- phase 5: div (backward) -> bit-rev scatter (AbS rows 0..7) -> fwd FFT
  {
    int jm1 = (j - 1) & NM, rj = rev8(j);
    #pragma unroll
    for (int m = 0; m < 2; ++m) {
      int k = (qtr << 1) + m;          // owned rows
      float dv = (u1r[m+1] - u1r[m] + Vs[k*NN + j] - Vs[k*NN + jm1]) * RDX;
      AbS[k*ROWF2 + pdx(rj)] = make_float2(dv, 0.0f);
    }
  }
  __syncthreads();                     // cross-wave: scatter -> FFT groups

  {
    const int g16 = tid >> 4;          // group = row 0..63; 8 active
    const int r   = tid & 15;
    if (g16 < 8) {                     // round 1: fwd stages 1-4 (16-blocks)
      float2* Ar = AbS + g16*ROWF2;
      float2 x[16];
      #pragma unroll
      for (int t = 0; t < 16; ++t) x[t] = Ar[pdx((r<<4) + t)];
      r16_fwd_low(x, tw);
      #pragma unroll
      for (int t = 0; t < 16; ++t) Ar[pdx((r<<4) + t)] = x[t];
    }
    wave_sync();
    if (g16 < 8) {                     // round 2: fwd stages 5-8 (stride-16)
      float2* Ar = AbS + g16*ROWF2;
      float2 x[16];
      #pragma unroll
      for (int k = 0; k < 16; ++k) x[k] = Ar[pdx(r + (k<<4))];
      r16_fwd_high(x, r, tw);
      #pragma unroll
      for (int k = 0; k < 16; ++k) Ar[pdx(r + (k<<4))] = x[k];
    }
  }
  __syncthreads();                     // cross-wave: FFT rows -> store

  float2* So = Snew + b*FIELD;
  #pragma unroll
  for (int m = 0; m < 2; ++m) {
    int e = tid + (m << 10);           // 8 rows x 256 = 2048
    int row = e >> 8, jj = e & 255;
    So[(row0 + row)*NN + jj] = AbS[row*ROWF2 + pdx(jj)];
  }
}

// ================================================================ B (R17 shape, fused rounds)
// 256 blocks x 512 threads. fwd col FFT * invLam/N^2 * inv col FFT, in
// place. 8 teams x 64 lanes, 4 fused rounds per FFT direction.
__global__ __launch_bounds__(512) void fft_cols(float2* __restrict__ S)
{
  __shared__ float2 Ab[8*ROWF2];
  __shared__ float2 tw[128];
  __shared__ float  lam[NN];
  int tid = threadIdx.x;
  int b = blockIdx.x >> 5;
  int col0 = (blockIdx.x & 31) << 3;

  if (tid < 128) {
    float sw, cw;
    __sincosf(-0.02454369260617026f * (float)tid, &sw, &cw);
    tw[tid] = make_float2(cw, sw);
  }
  if (tid < 256) {
    float s1 = __sinf(0.01227184630308512983f * (float)tid);   // pi/256 * k
    lam[tid] = -4.0f * s1 * s1 * (RDX*RDX);
  }

  float2* Sb = S + b*FIELD;
  #pragma unroll
  for (int k = 0; k < 4; ++k) {        // load transposed, bit-reversed
    int idx = tid + (k << 9);
    int i = idx >> 3, c = idx & 7;
    Ab[c*ROWF2 + pdx(rev8(i))] = Sb[i*NN + col0 + c];
  }
  __syncthreads();                     // cross-wave: scatter -> per-wave FFT

  int g = tid >> 6, lane = tid & 63;   // wave g owns column col0+g
  fft256_fwd_f2(Ab + g*ROWF2, lane, tw, true);

  // spectral scale: wave g touches only its own row -> wave order suffices
  float l2 = lam[col0 + g];
  #pragma unroll
  for (int r = 0; r < 4; ++r) {
    int k1 = lane + (r << 6);
    float den = lam[k1] + l2;
    float sc = ((k1 | (col0 + g)) == 0) ? 0.0f : (1.0f/den);
    sc *= (1.0f/65536.0f);             // fold in ifft2's 1/N^2
    float2 v = Ab[g*ROWF2 + pdx(k1)];
    Ab[g*ROWF2 + pdx(k1)] = make_float2(v.x*sc, v.y*sc);
  }
  wave_sync();

  fft256_inv_f2(Ab + g*ROWF2, lane, tw, true);
  __syncthreads();                     // cross-wave: FFT rows -> store

  #pragma unroll
  for (int k = 0; k < 4; ++k) {        // store transposed, un-reversed
    int idx = tid + (k << 9);
    int i = idx >> 3, c = idx & 7;
    Sb[i*NN + col0 + c] = Ab[c*ROWF2 + pdx(rev8(i))];
  }
}

// ================================================================ K1 (R9 fallback)
__global__ __launch_bounds__(512) void advect_div_fft(
    const float* __restrict__ inb, float* __restrict__ outb,
    float2* __restrict__ S, float* __restrict__ out,
    const unsigned* __restrict__ dtw, int T, int tm1)
{
  __shared__ float  Vs[8][NN];
  __shared__ float2 AbS[8*ROWF2];
  __shared__ float2 tw[128];
  const int tid = threadIdx.x;
  const int j   = tid & 255;
  const int h   = tid >> 8;           // 0 or 1
  const int b    = blockIdx.x >> 5;
  const int row0 = (blockIdx.x & 31) << 3;

  if (tid < 128) {
    float sw, cw;
    __sincosf(-0.02454369260617026f * (float)tid, &sw, &cw);  // -2pi/256
    tw[tid] = make_float2(cw, sw);
  }

  const float* Ub = inb + b*FIELD;
  const float* Vb = inb + TOTAL + b*FIELD;
  const float* Db = inb + 2*TOTAL + b*FIELD;
  float* Uo  = outb + b*FIELD;
  float* Vo  = outb + TOTAL + b*FIELD;
  float* Do_ = outb + 2*TOTAL + b*FIELD;

  const float dt = decode_dt(dtw);
  const float hdtdx = 0.5f*dt*RDX;

  if (tm1 >= 0) {                      // fused write_out of previous state
    #pragma unroll
    for (int k = 0; k < 4; ++k) {
      int pos = (row0 + h*4 + k)*NN + j;
      size_t o = ((size_t)(b*T + tm1)*FIELD + pos)*3u;
      out[o]   = Ub[pos];
      out[o+1] = Vb[pos];
      out[o+2] = Db[pos];
    }
  }

  const int kbeg = h ? 3 : -1;
  float u1r[5];
  #pragma unroll
  for (int kk = 0; kk < 5; ++kk) {
    int k = kbeg + kk;
    int r = (row0 + k) & NM;
    float u1, v1, d1;
    if (kk == 0) {
      advect_point<0>(Ub, Vb, Db, r, j, hdtdx, dt, u1, v1, d1);
    } else {
      advect_point<1>(Ub, Vb, Db, r, j, hdtdx, dt, u1, v1, d1);
      int gi = r*NN + j;
      Uo[gi] = u1; Vo[gi] = v1; Do_[gi] = d1;
      Vs[k][j] = v1;
    }
    u1r[kk] = u1;
  }
  __syncthreads();

  {  // div (backward diff) -> bit-reversed scatter (padded)
    int jm1 = (j - 1) & NM, rj = rev8(j);
    #pragma unroll
    for (int m = 0; m < 4; ++m) {
      int k = h*4 + m;
      float dv = (u1r[m+1] - u1r[m] + Vs[k][j] - Vs[k][jm1]) * RDX;
      AbS[k*ROWF2 + pdx(rj)] = make_float2(dv, 0.0f);
    }
  }
  __syncthreads();

  // fwd row FFT: 8 teams x 64 lanes
  const int g = tid >> 6, lane = tid & 63;
  fft256_dit_fwd<64>(AbS + g*ROWF2, lane, tw, true);
  __syncthreads();

  float2* Sb = S + b*FIELD;
  #pragma unroll
  for (int k = 0; k < 4; ++k) {
    int row = h*4 + k;
    Sb[(row0 + row)*NN + j] = AbS[row*ROWF2 + pdx(j)];
  }
}

// ================================================================ K2 (R9 fallback)
__global__ __launch_bounds__(512) void fft_cols_r9(float2* __restrict__ S)
{
  __shared__ float2 Ab[8*ROWF2];
  __shared__ float2 tw[128];
  __shared__ float  lam[NN];
  int tid = threadIdx.x;
  int b = blockIdx.x >> 5;
  int col0 = (blockIdx.x & 31) << 3;

  if (tid < 128) {
    float sw, cw;
    __sincosf(-0.02454369260617026f * (float)tid, &sw, &cw);
    tw[tid] = make_float2(cw, sw);
  }
  if (tid < 256) {
    float s1 = __sinf(0.01227184630308512983f * (float)tid);   // pi/256 * k
    lam[tid] = -4.0f * s1 * s1 * (RDX*RDX);
  }

  float2* Sb = S + b*FIELD;
  #pragma unroll
  for (int k = 0; k < 4; ++k) {        // load transposed, bit-reversed
    int idx = tid + (k << 9);
    int i = idx >> 3, c = idx & 7;
    Ab[c*ROWF2 + pdx(rev8(i))] = Sb[i*NN + col0 + c];
  }
  __syncthreads();                     // cross-wave: scatter -> per-wave FFT

  int g = tid >> 6, lane = tid & 63;   // wave g owns column-row g
  fft256_dit_fwd<64>(Ab + g*ROWF2, lane, tw, true);

  float l2 = lam[col0 + g];
  #pragma unroll
  for (int r = 0; r < 4; ++r) {
    int k1 = lane + (r << 6);
    float den = lam[k1] + l2;
    float sc = ((k1 | (col0 + g)) == 0) ? 0.0f : (1.0f/den);
    sc *= (1.0f/65536.0f);             // fold in ifft2's 1/N^2
    float2 v = Ab[g*ROWF2 + pdx(k1)];
    Ab[g*ROWF2 + pdx(k1)] = make_float2(v.x*sc, v.y*sc);
  }
  wave_sync();

  fft256_dif_inv<64>(Ab + g*ROWF2, lane, tw, true);
  __syncthreads();                     // cross-wave: FFT rows -> store

  #pragma unroll
  for (int k = 0; k < 4; ++k) {        // store transposed, un-reversed
    int idx = tid + (k << 9);
    int i = idx >> 3, c = idx & 7;
    Sb[i*NN + col0 + c] = Ab[c*ROWF2 + pdx(rev8(i))];
  }
}

// ================================================================ K3 (final correction)
__global__ __launch_bounds__(512) void fft_inv_correct(
    const float2* __restrict__ S, float* __restrict__ outb)
{
  __shared__ float2 Ab[9*ROWF2];
  __shared__ float  qs[9*NN];
  __shared__ float2 tw[128];
  int tid = threadIdx.x;
  int b = blockIdx.x >> 5;
  int row0 = (blockIdx.x & 31) << 3;

  if (tid < 128) {
    float sw, cw;
    __sincosf(-0.02454369260617026f * (float)tid, &sw, &cw);
    tw[tid] = make_float2(cw, sw);
  }

  const float2* Sb = S + b*FIELD;
  #pragma unroll
  for (int m = 0; m < 5; ++m) {        // load 9 rows, natural order (DIF in)
    int e = tid + m*512;
    if (e < 9*NN) {
      int k = e >> 8, j = e & 255;
      Ab[k*ROWF2 + pdx(j)] = Sb[((row0 + k) & NM)*NN + j];
    }
  }
  __syncthreads();

  int g = tid >> 5, lane = tid & 31;   // 16 teams of 32; 9 active
  bool active = (g < 9);
  fft256_dif_inv<32>(Ab + (active ? g : 8)*ROWF2, lane, tw, active);
  __syncthreads();

  #pragma unroll
  for (int m = 0; m < 5; ++m) {        // un-reverse gather -> qs natural
    int e = tid + m*512;
    if (e < 9*NN) {
      int k = e >> 8, j = e & 255;
      qs[k*NN + j] = Ab[k*ROWF2 + pdx(rev8(j))].x;
    }
  }
  __syncthreads();

  float* Ug = outb + b*FIELD;
  float* Vg = outb + TOTAL + b*FIELD;
  #pragma unroll
  for (int m = 0; m < 4; ++m) {
    int e = tid + m*512;               // 0..2047
    int k = e >> 8, j = e & 255;
    int gi = (row0 + k)*NN + j;
    float q0 = qs[k*NN + j];
    float q1 = qs[(k+1)*NN + j];
    float qj = qs[k*NN + ((j+1) & NM)];
    Ug[gi] -= (q1 - q0)*RDX;
    Vg[gi] -= (qj - q0)*RDX;
  }
}

// ================================================================ misc
__global__ __launch_bounds__(256) void write_out_k(
    const float* __restrict__ U, const float* __restrict__ V, const float* __restrict__ D,
    float* __restrict__ out, int t, int T)
{
  int idx = blockIdx.x*256 + threadIdx.x;
  int b = idx >> 16;
  int pos = idx & (FIELD-1);
  size_t o = ((size_t)(b*T + t)*FIELD + pos)*3u;
  out[o]   = U[idx];
  out[o+1] = V[idx];
  out[o+2] = D[idx];
}

__global__ __launch_bounds__(256) void init_state(
    const float* __restrict__ y0,
    float* __restrict__ U, float* __restrict__ V, float* __restrict__ D)
{
  int idx = blockIdx.x*256 + threadIdx.x;
  U[idx] = y0[idx*3];
  V[idx] = y0[idx*3+1];
  D[idx] = y0[idx*3+2];
}

// ================================================================ fallback
// R5-proven sincos/unpadded kernels (used only if ws too small).
__device__ __forceinline__ void fft_fwd_sc(float2* A, int lane) {
  #pragma unroll
  for (int s = 1; s <= 8; ++s) {
    int half = 1 << (s-1);
    float angscale = -6.28318530717958647692f / (float)(2*half);
    #pragma unroll
    for (int r = 0; r < 4; ++r) {
      int bfly = lane + (r << 5);
      int q = bfly & (half - 1);
      int g = (bfly >> (s-1)) << s;
      float sw, cw; __sincosf(angscale * (float)q, &sw, &cw);
      float2 a = A[g+q], b = A[g+q+half];
      float wbx = cw*b.x - sw*b.y, wby = cw*b.y + sw*b.x;
      A[g+q] = make_float2(a.x+wbx, a.y+wby);
      A[g+q+half] = make_float2(a.x-wbx, a.y-wby);
    }
    __syncthreads();
  }
}
__device__ __forceinline__ void fft_inv_sc(float2* A, int lane) {
  #pragma unroll
  for (int s = 8; s >= 1; --s) {
    int half = 1 << (s-1);
    float angscale = 6.28318530717958647692f / (float)(2*half);
    #pragma unroll
    for (int r = 0; r < 4; ++r) {
      int bfly = lane + (r << 5);
      int q = bfly & (half - 1);
      int g = (bfly >> (s-1)) << s;
      float sw, cw; __sincosf(angscale * (float)q, &sw, &cw);
      float2 a = A[g+q], b = A[g+q+half];
      float dx = a.x-b.x, dy = a.y-b.y;
      A[g+q] = make_float2(a.x+b.x, a.y+b.y);
      A[g+q+half] = make_float2(cw*dx - sw*dy, cw*dy + sw*dx);
    }
    __syncthreads();
  }
}

__global__ __launch_bounds__(256) void advect_kernel_fb(
    const float* __restrict__ U, const float* __restrict__ V, const float* __restrict__ D,
    float* __restrict__ Uo, float* __restrict__ Vo, float* __restrict__ Do_,
    const unsigned* __restrict__ dtw)
{
  int idx = blockIdx.x*256 + threadIdx.x;
  int j = idx & NM, i = (idx >> 8) & NM, base = (idx >> 16) * FIELD;
  float dt = decode_dt(dtw);
  float u1, v1, d1;
  advect_point<1>(U + base, V + base, D + base, i, j, 0.5f*dt*RDX, dt, u1, v1, d1);
  Uo[idx] = u1; Vo[idx] = v1; Do_[idx] = d1;
}

__global__ __launch_bounds__(256) void fft_rows_div_fb(
    const float* __restrict__ U2, const float* __restrict__ V2, float2* __restrict__ S)
{
  __shared__ float2 Ab[8*NN];
  int tid = threadIdx.x, b = blockIdx.x >> 5, row0 = (blockIdx.x & 31) << 3;
  const float* Ub = U2 + b*FIELD;
  const float* Vb = V2 + b*FIELD;
  int jm1 = (tid - 1) & NM, rj = rev8(tid);
  #pragma unroll
  for (int k = 0; k < 8; ++k) {
    int row = row0 + k, rm1 = (row - 1) & NM;
    float dv = (Ub[row*NN + tid] - Ub[rm1*NN + tid]
              + Vb[row*NN + tid] - Vb[row*NN + jm1]) * RDX;
    Ab[(k<<8) + rj] = make_float2(dv, 0.0f);
  }
  __syncthreads();
  int g = tid >> 5, lane = tid & 31;
  fft_fwd_sc(Ab + (g<<8), lane);
  float2* Sb = S + b*FIELD;
  #pragma unroll
  for (int k = 0; k < 8; ++k)
    Sb[(row0 + k)*NN + tid] = Ab[(k<<8) + tid];
}

__global__ __launch_bounds__(256) void fft_cols_fb(float2* __restrict__ S)
{
  __shared__ float2 Ab[8*NN];
  int tid = threadIdx.x, b = blockIdx.x >> 5, col0 = (blockIdx.x & 31) << 3;
  float2* Sb = S + b*FIELD;
  #pragma unroll
  for (int k = 0; k < 8; ++k) {
    int idx = tid + (k << 8);
    int i = idx >> 3, c = idx & 7;
    Ab[(c<<8) + rev8(i)] = Sb[i*NN + col0 + c];
  }
  __syncthreads();
  int g = tid >> 5, lane = tid & 31;
  fft_fwd_sc(Ab + (g<<8), lane);
  int k2 = col0 + g;
  float s2 = __sinf(0.01227184630308512983f * (float)k2);
  float l2 = -4.0f * s2 * s2 * (RDX*RDX);
  #pragma unroll
  for (int r = 0; r < 8; ++r) {
    int k1 = lane + (r << 5);
    float s1 = __sinf(0.01227184630308512983f * (float)k1);
    float l1 = -4.0f * s1 * s1 * (RDX*RDX);
    float den = l1 + l2;
    float sc = ((k1 | k2) == 0) ? 0.0f : (1.0f/den);
    sc *= (1.0f/65536.0f);
    float2 v = Ab[(g<<8) + k1];
    Ab[(g<<8) + k1] = make_float2(v.x*sc, v.y*sc);
  }
  __syncthreads();
  fft_inv_sc(Ab + (g<<8), lane);
  #pragma unroll
  for (int k = 0; k < 8; ++k) {
    int idx = tid + (k << 8);
    int i = idx >> 3, c = idx & 7;
    Sb[i*NN + col0 + c] = Ab[(c<<8) + rev8(i)];
  }
}

__global__ __launch_bounds__(256) void fft_rows_inv_fb(
    const float2* __restrict__ S, float* __restrict__ Q)
{
  __shared__ float2 Ab[8*NN];
  int tid = threadIdx.x, b = blockIdx.x >> 5, row0 = (blockIdx.x & 31) << 3;
  const float2* Sb = S + b*FIELD;
  #pragma unroll
  for (int k = 0; k < 8; ++k)
    Ab[(k<<8) + tid] = Sb[(row0 + k)*NN + tid];
  __syncthreads();
  int g = tid >> 5, lane = tid & 31;
  fft_inv_sc(Ab + (g<<8), lane);
  float* Qb = Q + b*FIELD;
  int rj = rev8(tid);
  #pragma unroll
  for (int k = 0; k < 8; ++k)
    Qb[(row0 + k)*NN + tid] = Ab[(k<<8) + rj].x;
}

__global__ __launch_bounds__(256) void correct_uv_fb(
    float* __restrict__ U2, float* __restrict__ V2, const float* __restrict__ Q)
{
  int idx = blockIdx.x*256 + threadIdx.x;
  int j = idx & NM, i = (idx >> 8) & NM, base = (idx >> 16) * FIELD;
  const float* Qb = Q + base;
  float q0 = Qb[i*NN + j];
  float qi = Qb[((i+1)&NM)*NN + j];
  float qj = Qb[i*NN + ((j+1)&NM)];
  U2[idx] -= (qi - q0)*RDX;
  V2[idx] -= (qj - q0)*RDX;
}

// ---------------------------------------------------------------- launch
extern "C" void kernel_launch(void* const* d_in, const int* in_sizes, int n_in,
                              void* d_out, int out_size, void* d_ws, size_t ws_size,
                              hipStream_t stream) {
  (void)in_sizes; (void)n_in;
  const float*    y0  = (const float*)d_in[0];
  const unsigned* dtw = (const unsigned*)d_in[1];
  float* out = (float*)d_out;

  int T = out_size / (3*FIELD*BATCH);
  if (T < 1) T = 1;

  float* wsf = (float*)d_ws;

  // ---- preferred: fused 2-kernel/step path (needs 10*TOTAL floats) ----
  if (ws_size >= (size_t)10*TOTAL*sizeof(float)) {
    float* stA = wsf;                  // 3*TOTAL
    float* stB = wsf + 3*TOTAL;        // 3*TOTAL
    float2* Sa = (float2*)(wsf + 6*TOTAL);   // TOTAL float2
    float2* Sc = (float2*)(wsf + 8*TOTAL);   // TOTAL float2

    init_state<<<TOTAL/256, 256, 0, stream>>>(y0, stA, stA+TOTAL, stA+2*TOTAL);
    float* inb  = stA;
    float* outb = stB;
    float2* Sr = Sa;                   // spectral q from previous step
    float2* Sw = Sc;                   // new div spectral
    int step = 0;
    for (int t = 0; t < T; ++t) {
      for (int s = 0; s < 10; ++s) {
        int tm1 = (s == 0) ? (t - 1) : -1;
        proj_advect_fft8<<<256, 1024, 0, stream>>>(Sr, inb, outb, Sw, out,
                                                   dtw, T, tm1, step == 0);
        fft_cols<<<256, 512, 0, stream>>>(Sw);
        float*  t1 = inb; inb = outb; outb = t1;
        float2* t2 = Sr;  Sr  = Sw;   Sw  = t2;
        ++step;
      }
    }
    // final state in inb is uncorrected; Sr holds its Poisson solution
    fft_inv_correct<<<256, 512, 0, stream>>>(Sr, inb);
    write_out_k<<<TOTAL/256, 256, 0, stream>>>(inb, inb+TOTAL, inb+2*TOTAL,
                                               out, T-1, T);
    return;
  }

  // ---- R9 3-kernel path (needs 8*TOTAL floats) ----
  if (ws_size >= (size_t)8*TOTAL*sizeof(float)) {
    float2* S = (float2*)(wsf + 6*TOTAL);
    init_state<<<TOTAL/256, 256, 0, stream>>>(y0, wsf, wsf+TOTAL, wsf+2*TOTAL);
    float* inb = wsf;
    float* outb = wsf + 3*TOTAL;
    for (int t = 0; t < T; ++t) {
      for (int s = 0; s < 10; ++s) {
        int tm1 = (s == 0) ? (t - 1) : -1;
        advect_div_fft <<<256, 512, 0, stream>>>(inb, outb, S, out, dtw, T, tm1);
        fft_cols_r9    <<<256, 512, 0, stream>>>(S);
        fft_inv_correct<<<256, 512, 0, stream>>>(S, outb);
        float* tmp = inb; inb = outb; outb = tmp;
      }
    }
    write_out_k<<<TOTAL/256, 256, 0, stream>>>(inb, inb+TOTAL, inb+2*TOTAL,
                                               out, T-1, T);
    return;
  }

  // ---- R5 5-kernel path with aliased S/Q (12.6 MB) ----
  float* bank0 = wsf;
  float* bank1 = wsf + 3*TOTAL;
  init_state<<<TOTAL/256, 256, 0, stream>>>(y0, bank0, bank0+TOTAL, bank0+2*TOTAL);
  float* inb = bank0;
  float* outb = bank1;
  for (int t = 0; t < T; ++t) {
    for (int s = 0; s < 10; ++s) {
      float *Ui = inb,  *Vi = inb + TOTAL,  *Di = inb + 2*TOTAL;
      float *Uo = outb, *Vo = outb + TOTAL, *Do_ = outb + 2*TOTAL;
      float2* S = (float2*)(inb + TOTAL);
      float*  Q = inb;
      advect_kernel_fb<<<TOTAL/256, 256, 0, stream>>>(Ui, Vi, Di, Uo, Vo, Do_, dtw);
      fft_rows_div_fb <<<BATCH*32, 256, 0, stream>>>(Uo, Vo, S);
      fft_cols_fb     <<<BATCH*32, 256, 0, stream>>>(S);
      fft_rows_inv_fb <<<BATCH*32, 256, 0, stream>>>(S, Q);
      correct_uv_fb   <<<TOTAL/256, 256, 0, stream>>>(Uo, Vo, Q);
      float* tmp = inb; inb = outb; outb = tmp;
    }
    write_out_k<<<TOTAL/256, 256, 0, stream>>>(inb, inb+TOTAL, inb+2*TOTAL, out, t, T);
  }
}

// Round 12
// 1993.843 us; speedup vs baseline: 1.0421x; 1.0031x over previous
//
#include <hip/hip_runtime.h>
#include <hip/hip_bf16.h>

// NS solver: 256x256 periodic, B=8, NC=3 (u,v,density), T outer x 10 inner steps.
// y0 = fp32, dt = fp32, out = fp32 (established R1-R5). Internal state fp32.
//
// R21: packed real-FFT pairs in A. R20 (radix-16 A) verified -2%; A's FFT
// LDS traffic is still ~40% of the kernel. Halve the FFT count algebraically:
//  - phase 1: S is Hermitian in j (div real; B's symmetric-lambda per-column
//    solve preserves it) -> IFFT(S_a + i S_b) = q_a + i q_b, both real.
//    14 row-FFTs -> 7 packed; gather reads .x/.y. No unpack needed.
//  - phase 5: div real; thread's quarter owns rows 2q,2q+1 (natural pair).
//    FFT(d_a + i d_b) then Hermitian unpack at store:
//    S_a[k]=(z[k]+conj(z[-k]))/2, S_b[k]=(z[k]-conj(z[-k]))/(2i).
//    8 row-FFTs -> 4 packed.
// Radix-16 2-round form kept (R19/R20-verified). B = R17-f2 (measured best).
// Algebraically exact; roundoff mixes row pairs (absmax may tick up slightly).

#define NN 256
#define NM 255
#define FIELD (NN*NN)
#define BATCH 8
#define TOTAL (BATCH*FIELD)
#define ROWF2 264   // padded LDS row stride in float2 (256 + 8)

constexpr float RDX  = 40.743665431525205f;   // N/(2*pi) = 1/DX
constexpr float VISC = 1e-3f;

__device__ __forceinline__ int rev8(int x) { return (int)(__brev((unsigned)x) >> 24); }
__device__ __forceinline__ int pdx(int x)  { return x + (x >> 5); }

// Intra-wave LDS exchange fence (R13-verified on gfx950): compiler fence +
// sched barrier. A wave's DS ops complete in program order -> no s_barrier
// needed when producer and consumer lanes share a wave.
__device__ __forceinline__ void wave_sync() {
  asm volatile("" ::: "memory");
  __builtin_amdgcn_wave_barrier();
}

__device__ __forceinline__ float decode_dt(const unsigned* dtw) {
  unsigned w = dtw[0];
  float cf = __uint_as_float(w);
  float cb = __uint_as_float((w & 0xFFFFu) << 16);
  bool v32 = (cf > 1e-8f) && (cf < 1.0f);          // NaN-safe
  bool vbf = (cb > 1e-8f) && (cb < 1.0f);
  return v32 ? cf : (vbf ? cb : 1e-3f);
}

// ---------------------------------------------------------------- advection
__device__ __forceinline__ float face_flux(float uf, float cm, float c0,
                                           float cp, float cpp, float hdtdx) {
  float dc = cp - c0;
  float f_low  = (uf >= 0.0f) ? uf*c0 : uf*cp;
  float f_high = uf*0.5f*(c0+cp) - hdtdx*uf*uf*dc;
  float dc_up  = (uf >= 0.0f) ? (c0 - cm) : (cpp - cp);
  float dc_safe = (fabsf(dc) > 1e-12f) ? dc : 1e-12f;
  // van Leer: (a*b>0) ? 2a/(a+b) : 0
  float phi = (dc_up * dc_safe > 0.0f) ? (2.0f*dc_up/(dc_up + dc_safe)) : 0.0f;
  return f_low + phi*(f_high - f_low);
}

// global-memory stencil variant (fallback paths)
template<int NEED_VD>
__device__ __forceinline__ void advect_point(
    const float* __restrict__ Ub, const float* __restrict__ Vb,
    const float* __restrict__ Db,
    int i, int j, float hdtdx, float dt,
    float& u1, float& v1, float& d1)
{
  int im2 = ((i-2)&NM)*NN, im1 = ((i-1)&NM)*NN, i0r = i*NN,
      ip1 = ((i+1)&NM)*NN, ip2 = ((i+2)&NM)*NN;
  int jm2 = (j-2)&NM, jm1 = (j-1)&NM, jp1 = (j+1)&NM, jp2 = (j+2)&NM;

  float u_c  = Ub[i0r+j];
  float u_im2= Ub[im2+j], u_im1 = Ub[im1+j], u_ip1 = Ub[ip1+j], u_ip2 = Ub[ip2+j];
  float u_jm2= Ub[i0r+jm2], u_jm1 = Ub[i0r+jm1], u_jp1 = Ub[i0r+jp1], u_jp2 = Ub[i0r+jp2];
  float v_c  = Vb[i0r+j];
  float v_jm1= Vb[i0r+jm1], v_jp1 = Vb[i0r+jp1];

  float ufI0 = 0.5f*(u_c + u_ip1);
  float ufIm = 0.5f*(u_im1 + u_c);
  float vfJ0 = 0.5f*(v_c + v_jp1);
  float vfJm = 0.5f*(v_jm1 + v_c);

  float tu = -(( face_flux(ufI0, u_im1, u_c, u_ip1, u_ip2, hdtdx)
               - face_flux(ufIm, u_im2, u_im1, u_c, u_ip1, hdtdx))
             + ( face_flux(vfJ0, u_jm1, u_c, u_jp1, u_jp2, hdtdx)
               - face_flux(vfJm, u_jm2, u_jm1, u_c, u_jp1, hdtdx))) * RDX;
  float lapu = (u_im1 + u_ip1 + u_jm1 + u_jp1 - 4.0f*u_c) * (RDX*RDX);
  u1 = u_c + dt*(tu + VISC*lapu);

  if (NEED_VD) {
    float v_im2= Vb[im2+j], v_im1 = Vb[im1+j], v_ip1 = Vb[ip1+j], v_ip2 = Vb[ip2+j];
    float v_jm2= Vb[i0r+jm2], v_jp2 = Vb[i0r+jp2];
    float d_c  = Db[i0r+j];
    float d_im2= Db[im2+j], d_im1 = Db[im1+j], d_ip1 = Db[ip1+j], d_ip2 = Db[ip2+j];
    float d_jm2= Db[i0r+jm2], d_jm1 = Db[i0r+jm1], d_jp1 = Db[i0r+jp1], d_jp2 = Db[i0r+jp2];

    float tv = -(( face_flux(ufI0, v_im1, v_c, v_ip1, v_ip2, hdtdx)
                 - face_flux(ufIm, v_im2, v_im1, v_c, v_ip1, hdtdx))
               + ( face_flux(vfJ0, v_jm1, v_c, v_jp1, v_jp2, hdtdx)
                 - face_flux(vfJm, v_jm2, v_jm1, v_c, v_jp1, hdtdx))) * RDX;
    float lapv = (v_im1 + v_ip1 + v_jm1 + v_jp1 - 4.0f*v_c) * (RDX*RDX);
    v1 = v_c + dt*(tv + VISC*lapv);

    float td = -(( face_flux(ufI0, d_im1, d_c, d_ip1, d_ip2, hdtdx)
                 - face_flux(ufIm, d_im2, d_im1, d_c, d_ip1, hdtdx))
               + ( face_flux(vfJ0, d_jm1, d_c, d_jp1, d_jp2, hdtdx)
                 - face_flux(vfJm, d_jm2, d_jm1, d_c, d_jp1, hdtdx))) * RDX;
    d1 = d_c + dt*td;
  }
}

// LDS-slab stencil variant (fused A kernel). ku = u-slab row of the point,
// kv = v/d-slab row of the point. Slabs are contiguous (no row wrap); j wraps.
template<int NEED_VD>
__device__ __forceinline__ void advect_point_lds(
    const float* __restrict__ U, const float* __restrict__ V,
    const float* __restrict__ D,
    int ku, int kv, int j, float hdtdx, float dt,
    float& u1, float& v1, float& d1)
{
  int jm2 = (j-2)&NM, jm1 = (j-1)&NM, jp1 = (j+1)&NM, jp2 = (j+2)&NM;

  const float* Ur = U + ku*NN;
  float u_c  = Ur[j];
  float u_im2= U[(ku-2)*NN+j], u_im1 = U[(ku-1)*NN+j],
        u_ip1= U[(ku+1)*NN+j], u_ip2 = U[(ku+2)*NN+j];
  float u_jm2= Ur[jm2], u_jm1 = Ur[jm1], u_jp1 = Ur[jp1], u_jp2 = Ur[jp2];
  const float* Vr = V + kv*NN;
  float v_c  = Vr[j];
  float v_jm1= Vr[jm1], v_jp1 = Vr[jp1];

  float ufI0 = 0.5f*(u_c + u_ip1);
  float ufIm = 0.5f*(u_im1 + u_c);
  float vfJ0 = 0.5f*(v_c + v_jp1);
  float vfJm = 0.5f*(v_jm1 + v_c);

  float tu = -(( face_flux(ufI0, u_im1, u_c, u_ip1, u_ip2, hdtdx)
               - face_flux(ufIm, u_im2, u_im1, u_c, u_ip1, hdtdx))
             + ( face_flux(vfJ0, u_jm1, u_c, u_jp1, u_jp2, hdtdx)
               - face_flux(vfJm, u_jm2, u_jm1, u_c, u_jp1, hdtdx))) * RDX;
  float lapu = (u_im1 + u_ip1 + u_jm1 + u_jp1 - 4.0f*u_c) * (RDX*RDX);
  u1 = u_c + dt*(tu + VISC*lapu);

  if (NEED_VD) {
    float v_im2= V[(kv-2)*NN+j], v_im1 = V[(kv-1)*NN+j],
          v_ip1= V[(kv+1)*NN+j], v_ip2 = V[(kv+2)*NN+j];
    float v_jm2= Vr[jm2], v_jp2 = Vr[jp2];
    const float* Dr = D + kv*NN;
    float d_c  = Dr[j];
    float d_im2= D[(kv-2)*NN+j], d_im1 = D[(kv-1)*NN+j],
          d_ip1= D[(kv+1)*NN+j], d_ip2 = D[(kv+2)*NN+j];
    float d_jm2= Dr[jm2], d_jm1 = Dr[jm1], d_jp1 = Dr[jp1], d_jp2 = Dr[jp2];

    float tv = -(( face_flux(ufI0, v_im1, v_c, v_ip1, v_ip2, hdtdx)
                 - face_flux(ufIm, v_im2, v_im1, v_c, v_ip1, hdtdx))
               + ( face_flux(vfJ0, v_jm1, v_c, v_jp1, v_jp2, hdtdx)
                 - face_flux(vfJm, v_jm2, v_jm1, v_c, v_jp1, hdtdx))) * RDX;
    float lapv = (v_im1 + v_ip1 + v_jm1 + v_jp1 - 4.0f*v_c) * (RDX*RDX);
    v1 = v_c + dt*(tv + VISC*lapv);

    float td = -(( face_flux(ufI0, d_im1, d_c, d_ip1, d_ip2, hdtdx)
                 - face_flux(ufIm, d_im2, d_im1, d_c, d_ip1, hdtdx))
               + ( face_flux(vfJ0, d_jm1, d_c, d_jp1, d_jp2, hdtdx)
                 - face_flux(vfJm, d_jm2, d_jm1, d_c, d_jp1, hdtdx))) * RDX;
    d1 = d_c + dt*td;
  }
}

// ---------------------------------------------------------------- FFT cores
// Table-driven, padded-LDS. tw[m] = exp(-2*pi*i*m/256), m<128. Stage-s
// twiddle = tw[q<<(8-s)] (fwd), conjugate for inverse. A = padded row base;
// element x lives at A[pdx(x)].
// WAVE-SYNCHRONOUS (R13): exchanges within a wave need only wave_sync().
//
// RADIX-16 ROUNDS (R19/R20-HW-verified): stages 1-4 confined to contiguous
// 16-blocks, stages 5-8 to stride-16 residue classes. One lane holds 16
// float2 in regs -> 4 stages per LDS round -> 2 rounds per direction.

// --- radix-16 in-register stage groups (lane-local x[16]) ---
__device__ __forceinline__ void r16_fwd_low(float2* x, const float2* tw) {
  #pragma unroll
  for (int s = 1; s <= 4; ++s) {
    int h = 1 << (s-1);
    #pragma unroll
    for (int b = 0; b < 8; ++b) {
      int q = b & (h-1);
      int t = ((b >> (s-1)) << s) + q;
      float2 w = tw[q << (8-s)];
      float2 a = x[t], c = x[t+h];
      float wbx = w.x*c.x - w.y*c.y, wby = w.x*c.y + w.y*c.x;
      x[t]   = make_float2(a.x+wbx, a.y+wby);
      x[t+h] = make_float2(a.x-wbx, a.y-wby);
    }
  }
}
__device__ __forceinline__ void r16_fwd_high(float2* x, int r, const float2* tw) {
  #pragma unroll
  for (int s = 5; s <= 8; ++s) {
    int hp = 1 << (s-5);
    #pragma unroll
    for (int b = 0; b < 8; ++b) {
      int qp = b & (hp-1);
      int t = ((b >> (s-5)) << (s-4)) + qp;
      float2 w = tw[(r + (qp<<4)) << (8-s)];
      float2 a = x[t], c = x[t+hp];
      float wbx = w.x*c.x - w.y*c.y, wby = w.x*c.y + w.y*c.x;
      x[t]    = make_float2(a.x+wbx, a.y+wby);
      x[t+hp] = make_float2(a.x-wbx, a.y-wby);
    }
  }
}
__device__ __forceinline__ void r16_inv_high(float2* x, int r, const float2* tw) {
  #pragma unroll
  for (int s = 8; s >= 5; --s) {
    int hp = 1 << (s-5);
    #pragma unroll
    for (int b = 0; b < 8; ++b) {
      int qp = b & (hp-1);
      int t = ((b >> (s-5)) << (s-4)) + qp;
      float2 w = tw[(r + (qp<<4)) << (8-s)];
      float2 a = x[t], c = x[t+hp];
      float dx = a.x-c.x, dy = a.y-c.y;
      x[t]    = make_float2(a.x+c.x, a.y+c.y);
      x[t+hp] = make_float2(w.x*dx + w.y*dy, w.x*dy - w.y*dx);
    }
  }
}
__device__ __forceinline__ void r16_inv_low(float2* x, const float2* tw) {
  #pragma unroll
  for (int s = 4; s >= 1; --s) {
    int h = 1 << (s-1);
    #pragma unroll
    for (int b = 0; b < 8; ++b) {
      int q = b & (h-1);
      int t = ((b >> (s-1)) << s) + q;
      float2 w = tw[q << (8-s)];
      float2 a = x[t], c = x[t+h];
      float dx = a.x-c.x, dy = a.y-c.y;
      x[t]   = make_float2(a.x+c.x, a.y+c.y);
      x[t+h] = make_float2(w.x*dx + w.y*dy, w.x*dy - w.y*dx);
    }
  }
}

// --- R17 fused 2-stage rounds (B kernel) ---
// fwd DIT, fused stage pairs (1,2),(3,4),(5,6),(7,8). lane in [0,64).
__device__ __forceinline__ void fft256_fwd_f2(float2* __restrict__ A, int lane,
                                              const float2* __restrict__ tw,
                                              bool active)
{
  #pragma unroll
  for (int s = 1; s <= 8; s += 2) {
    if (active) {
      int half = 1 << (s-1);
      int q2 = lane & (half - 1);
      int i0 = ((lane >> (s-1)) << (s+1)) + q2;
      float2 a0 = A[pdx(i0)];
      float2 a1 = A[pdx(i0 + half)];
      float2 a2 = A[pdx(i0 + 2*half)];
      float2 a3 = A[pdx(i0 + 3*half)];
      // stage s: pairs (a0,a1),(a2,a3), twiddle tw[q2<<(8-s)]
      float2 w1 = tw[q2 << (8 - s)];
      float wbx = w1.x*a1.x - w1.y*a1.y, wby = w1.x*a1.y + w1.y*a1.x;
      float2 b0 = make_float2(a0.x + wbx, a0.y + wby);
      float2 b1 = make_float2(a0.x - wbx, a0.y - wby);
      wbx = w1.x*a3.x - w1.y*a3.y; wby = w1.x*a3.y + w1.y*a3.x;
      float2 b2 = make_float2(a2.x + wbx, a2.y + wby);
      float2 b3 = make_float2(a2.x - wbx, a2.y - wby);
      // stage s+1: pairs (b0,b2) tw[q2<<(7-s)], (b1,b3) tw[(q2+half)<<(7-s)]
      float2 w2 = tw[q2 << (7 - s)];
      float2 w3 = tw[(q2 + half) << (7 - s)];
      wbx = w2.x*b2.x - w2.y*b2.y; wby = w2.x*b2.y + w2.y*b2.x;
      A[pdx(i0)]            = make_float2(b0.x + wbx, b0.y + wby);
      A[pdx(i0 + 2*half)]   = make_float2(b0.x - wbx, b0.y - wby);
      wbx = w3.x*b3.x - w3.y*b3.y; wby = w3.x*b3.y + w3.y*b3.x;
      A[pdx(i0 + half)]     = make_float2(b1.x + wbx, b1.y + wby);
      A[pdx(i0 + 3*half)]   = make_float2(b1.x - wbx, b1.y - wby);
    }
    wave_sync();
  }
}

// inv DIF, fused stage pairs (8,7),(6,5),(4,3),(2,1). lane in [0,64).
__device__ __forceinline__ void fft256_inv_f2(float2* __restrict__ A, int lane,
                                              const float2* __restrict__ tw,
                                              bool active)
{
  #pragma unroll
  for (int s = 8; s >= 2; s -= 2) {
    if (active) {
      int h = 1 << (s-2);              // half of stage s-1
      int q2 = lane & (h - 1);
      int i0 = ((lane >> (s-2)) << s) + q2;
      float2 a0 = A[pdx(i0)];
      float2 a1 = A[pdx(i0 + h)];
      float2 a2 = A[pdx(i0 + 2*h)];
      float2 a3 = A[pdx(i0 + 3*h)];
      // stage s (half=2h): pairs (a0,a2) q=q2, (a1,a3) q=q2+h
      float2 w1 = tw[q2 << (8 - s)];
      float2 w2 = tw[(q2 + h) << (8 - s)];
      float dx = a0.x - a2.x, dy = a0.y - a2.y;
      float2 b0 = make_float2(a0.x + a2.x, a0.y + a2.y);
      float2 b2 = make_float2(w1.x*dx + w1.y*dy, w1.x*dy - w1.y*dx);
      dx = a1.x - a3.x; dy = a1.y - a3.y;
      float2 b1 = make_float2(a1.x + a3.x, a1.y + a3.y);
      float2 b3 = make_float2(w2.x*dx + w2.y*dy, w2.x*dy - w2.y*dx);
      // stage s-1 (half=h): pairs (b0,b1) and (b2,b3), both q=q2
      float2 w3 = tw[q2 << (9 - s)];
      dx = b0.x - b1.x; dy = b0.y - b1.y;
      A[pdx(i0)]       = make_float2(b0.x + b1.x, b0.y + b1.y);
      A[pdx(i0 + h)]   = make_float2(w3.x*dx + w3.y*dy, w3.x*dy - w3.y*dx);
      dx = b2.x - b3.x; dy = b2.y - b3.y;
      A[pdx(i0 + 2*h)] = make_float2(b2.x + b3.x, b2.y + b3.y);
      A[pdx(i0 + 3*h)] = make_float2(w3.x*dx + w3.y*dy, w3.x*dy - w3.y*dx);
    }
    wave_sync();
  }
}

// Legacy single-stage variants (fallback paths + final correction kernel).
template<int W>
__device__ __forceinline__ void fft256_dit_fwd(float2* __restrict__ A, int lane,
                                               const float2* __restrict__ tw,
                                               bool active)
{
  #pragma unroll
  for (int s = 1; s <= 8; ++s) {
    int half = 1 << (s-1);
    if (active) {
      #pragma unroll
      for (int r = 0; r < 128/W; ++r) {
        int bfly = lane + r*W;
        int q = bfly & (half - 1);
        int g = (bfly >> (s-1)) << s;
        float2 w = tw[q << (8 - s)];
        float2 a = A[pdx(g + q)];
        float2 b = A[pdx(g + q + half)];
        float wbx = w.x*b.x - w.y*b.y;
        float wby = w.x*b.y + w.y*b.x;
        A[pdx(g + q)]        = make_float2(a.x + wbx, a.y + wby);
        A[pdx(g + q + half)] = make_float2(a.x - wbx, a.y - wby);
      }
    }
    wave_sync();
  }
}

template<int W>
__device__ __forceinline__ void fft256_dif_inv(float2* __restrict__ A, int lane,
                                               const float2* __restrict__ tw,
                                               bool active)
{
  #pragma unroll
  for (int s = 8; s >= 1; --s) {
    int half = 1 << (s-1);
    if (active) {
      #pragma unroll
      for (int r = 0; r < 128/W; ++r) {
        int bfly = lane + r*W;
        int q = bfly & (half - 1);
        int g = (bfly >> (s-1)) << s;
        float2 w = tw[q << (8 - s)];      // conj applied below (inverse)
        float2 a = A[pdx(g + q)];
        float2 b = A[pdx(g + q + half)];
        float dx = a.x - b.x, dy = a.y - b.y;
        A[pdx(g + q)]        = make_float2(a.x + b.x, a.y + b.y);
        A[pdx(g + q + half)] = make_float2(w.x*dx + w.y*dy, w.x*dy - w.y*dx);
      }
    }
    wave_sync();
  }
}

// ================================================================ A (fused, 8-row, 1024 thr)
// 256 blocks x 1024 threads. Per block: batch b = bid>>5, rows row0..row0+7.
//  0. issue U/V/D global->reg staging loads (consumed in phase 2)
//  1. PACKED inv row FFT: 7 packed pairs (S[2p]+i*S[2p+1]) of the 14 halo
//     rows of S_prev (7 groups x 16 lanes, radix-16, 2 LDS rounds);
//     IFFT output .x/.y = the two real q rows.
//  2. q gather; corrected u (13 rows), v (12), d (12) slabs in LDS (from regs)
//  3. optional trajectory write-out of corrected state t-1 (owned 8 rows)
//  4. advect from LDS: quarter q -> u-only row 2q-1, full rows 2q, 2q+1
//  5. div -> PACKED fwd row FFT: 4 packed pairs (div rows 2q + i*2q+1),
//     Hermitian unpack at store -> S_new (all 8 real rows)
// Slab rows: q row k <-> global row0-3+k (k in [0,13])
//            u row k <-> global row0-3+k (k in [0,12])
//            v,d row k <-> global row0-2+k (k in [0,11])
// LDS aliasing (R12): Vs -> qs (dead after phase 2); Dss -> AbS rows 8..13
// (phase-1 uses rows 0..6, phase-5 rows 0..3 -- disjoint). Total ~69 KB.
__global__ __launch_bounds__(1024) void proj_advect_fft8(
    const float2* __restrict__ Sprev, const float* __restrict__ inb,
    float* __restrict__ outb, float2* __restrict__ Snew,
    float* __restrict__ out, const unsigned* __restrict__ dtw,
    int T, int tm1, int first)
{
  __shared__ float2 tw[128];
  __shared__ float2 AbS[14*ROWF2];
  __shared__ float  qs [14*NN];
  __shared__ float  Ucs[13*NN];
  __shared__ float  Vcs[12*NN];
  float* Dss = (float*)(AbS + 8*ROWF2);  // 12*NN floats; phases 1/5 use rows 0..6
  float* Vs  = qs;                       // 8*NN floats; qs dead after phase 2

  const int tid  = threadIdx.x;
  const int j    = tid & 255;
  const int qtr  = tid >> 8;           // 0..3
  const int b    = blockIdx.x >> 5;
  const int row0 = (blockIdx.x & 31) << 3;

  if (tid < 128) {
    float sw, cw;
    __sincosf(-0.02454369260617026f * (float)tid, &sw, &cw);  // -2pi/256
    tw[tid] = make_float2(cw, sw);
  }

  const float dt = decode_dt(dtw);
  const float hdtdx = 0.5f*dt*RDX;

  const float* Ub = inb + b*FIELD;
  const float* Vb = inb + TOTAL + b*FIELD;
  const float* Db = inb + 2*TOTAL + b*FIELD;
  float* Uo  = outb + b*FIELD;
  float* Vo  = outb + TOTAL + b*FIELD;
  float* Do_ = outb + 2*TOTAL + b*FIELD;

  // ---- phase 0: early global->reg staging (T14). Latency hides under phase 1.
  float u_reg[4], v_reg[3], d_reg[3];
  #pragma unroll
  for (int m = 0; m < 4; ++m) {        // U: 13 rows = 3328 elems
    int e = tid + (m << 10);
    if (e < 13*NN) {
      int k = e >> 8, jj = e & 255;
      u_reg[m] = Ub[((row0 - 3 + k) & NM)*NN + jj];
    }
  }
  #pragma unroll
  for (int m = 0; m < 3; ++m) {        // V, D: 12 rows = 3072 = 3*1024
    int e = tid + (m << 10);
    int k = e >> 8, jj = e & 255;
    int gr = ((row0 - 2 + k) & NM)*NN;
    v_reg[m] = Vb[gr + jj];
    d_reg[m] = Db[gr + jj];
  }

  // ---- phase 1: PACKED inv row FFT of 14 rows -> qs (skip on step 0)
  // z_p[j] = S[row0-3+2p][j] + i*S[row0-3+2p+1][j]; IFFT(z) = q_a + i*q_b
  // (valid since S Hermitian in j -> q rows real).
  if (!first) {
    const float2* Sb = Sprev + b*FIELD;
    #pragma unroll
    for (int m = 0; m < 2; ++m) {      // 7*256 = 1792 elems
      int e = tid + (m << 10);
      if (e < 7*NN) {
        int p = e >> 8, jj = e & 255;
        float2 sa = Sb[((row0 - 3 + 2*p) & NM)*NN + jj];
        float2 sc = Sb[((row0 - 2 + 2*p) & NM)*NN + jj];
        AbS[p*ROWF2 + pdx(jj)] = make_float2(sa.x - sc.y, sa.y + sc.x);
      }
    }
    __syncthreads();                   // cross-wave: scatter -> FFT groups

    {
      const int g16 = tid >> 4;        // 7 active groups (threads 0..111)
      const int r   = tid & 15;
      if (g16 < 7) {                   // round 1: inv stages 8-5 (stride-16)
        float2* Ar = AbS + g16*ROWF2;
        float2 x[16];
        #pragma unroll
        for (int k = 0; k < 16; ++k) x[k] = Ar[pdx(r + (k<<4))];
        r16_inv_high(x, r, tw);
        #pragma unroll
        for (int k = 0; k < 16; ++k) Ar[pdx(r + (k<<4))] = x[k];
      }
      wave_sync();
      if (g16 < 7) {                   // round 2: inv stages 4-1 (16-blocks)
        float2* Ar = AbS + g16*ROWF2;
        float2 x[16];
        #pragma unroll
        for (int t = 0; t < 16; ++t) x[t] = Ar[pdx((r<<4) + t)];
        r16_inv_low(x, tw);
        #pragma unroll
        for (int t = 0; t < 16; ++t) Ar[pdx((r<<4) + t)] = x[t];
      }
    }
    __syncthreads();                   // cross-wave: FFT rows -> qs gather

    #pragma unroll
    for (int m = 0; m < 2; ++m) {      // un-reverse gather -> two q rows/pair
      int e = tid + (m << 10);
      if (e < 7*NN) {
        int p = e >> 8, jj = e & 255;
        float2 z = AbS[p*ROWF2 + pdx(rev8(jj))];
        qs[(2*p)*NN + jj]   = z.x;
        qs[(2*p+1)*NN + jj] = z.y;
      }
    }
    __syncthreads();
  } else {
    __syncthreads();                   // match table init visibility
  }

  // ---- phase 2: corrected u,v + d slabs in LDS (from staged registers)
  // (Dss writes land in AbS rows 8..13 -- phases 1/5 use rows 0..6 only.)
  #pragma unroll
  for (int m = 0; m < 4; ++m) {        // U: 13 rows
    int e = tid + (m << 10);
    if (e < 13*NN) {
      int k = e >> 8, jj = e & 255;
      Ucs[e] = first ? u_reg[m]
                     : (u_reg[m] - (qs[(k+1)*NN + jj] - qs[k*NN + jj])*RDX);
    }
  }
  #pragma unroll
  for (int m = 0; m < 3; ++m) {        // V, D: 12 rows
    int e = tid + (m << 10);
    int k = e >> 8, jj = e & 255;
    Vcs[e] = first ? v_reg[m]
                   : (v_reg[m] - (qs[(k+1)*NN + ((jj+1)&NM)] - qs[(k+1)*NN + jj])*RDX);
    Dss[e] = d_reg[m];
  }
  __syncthreads();                     // qs dead from here; Vs may reuse it

  // ---- phase 3: fused trajectory write-out of corrected state t-1
  if (tm1 >= 0) {
    #pragma unroll
    for (int m = 0; m < 2; ++m) {
      int e = tid + (m << 10);         // 8 owned rows x 256 = 2048
      int k = e >> 8, jj = e & 255;
      int pos = (row0 + k)*NN + jj;
      size_t o = ((size_t)(b*T + tm1)*FIELD + pos)*3u;
      out[o]   = Ucs[(k+3)*NN + jj];
      out[o+1] = Vcs[(k+2)*NN + jj];
      out[o+2] = Dss[(k+2)*NN + jj];
    }
  }

  // ---- phase 4: advect from LDS. Quarter qtr: u-only row 2q-1 (backward
  // halo for div), full rows 2q, 2q+1.
  const int kbeg = (qtr << 1) - 1;     // -1, 1, 3, 5
  float u1r[3];
  #pragma unroll
  for (int kk = 0; kk < 3; ++kk) {
    int k = kbeg + kk;                 // global row = row0 + k
    int ku = k + 3, kv = k + 2;
    float u1, v1, d1;
    if (kk == 0) {
      advect_point_lds<0>(Ucs, Vcs, Dss, ku, kv, j, hdtdx, dt, u1, v1, d1);
    } else {
      advect_point_lds<1>(Ucs, Vcs, Dss, ku, kv, j, hdtdx, dt, u1, v1, d1);
      int gi = (row0 + k)*NN + j;
      Uo[gi] = u1; Vo[gi] = v1; Do_[gi] = d1;
      Vs[k*NN + j] = v1;               // k in [0,7], owned
    }
    u1r[kk] = u1;
  }
  __syncthreads();                     // Vs visible across waves

  // ---- phase 5: div -> PACKED bit-rev scatter (pair p = qtr) -> fwd FFT
  {
    int jm1 = (j - 1) & NM, rj = rev8(j);
    float dv0 = (u1r[1] - u1r[0]
               + Vs[(2*qtr)*NN + j] - Vs[(2*qtr)*NN + jm1]) * RDX;
    float dv1 = (u1r[2] - u1r[1]
               + Vs[(2*qtr+1)*NN + j] - Vs[(2*qtr+1)*NN + jm1]) * RDX;
    AbS[qtr*ROWF2 + pdx(rj)] = make_float2(dv0, dv1);   // z = d_a + i*d_b
  }
  __syncthreads();                     // cross-wave: scatter -> FFT groups

  {
    const int g16 = tid >> 4;          // 4 active groups (threads 0..63)
    const int r   = tid & 15;
    if (g16 < 4) {                     // round 1: fwd stages 1-4 (16-blocks)
      float2* Ar = AbS + g16*ROWF2;
      float2 x[16];
      #pragma unroll
      for (int t = 0; t < 16; ++t) x[t] = Ar[pdx((r<<4) + t)];
      r16_fwd_low(x, tw);
      #pragma unroll
      for (int t = 0; t < 16; ++t) Ar[pdx((r<<4) + t)] = x[t];
    }
    wave_sync();
    if (g16 < 4) {                     // round 2: fwd stages 5-8 (stride-16)
      float2* Ar = AbS + g16*ROWF2;
      float2 x[16];
      #pragma unroll
      for (int k = 0; k < 16; ++k) x[k] = Ar[pdx(r + (k<<4))];
      r16_fwd_high(x, r, tw);
      #pragma unroll
      for (int k = 0; k < 16; ++k) Ar[pdx(r + (k<<4))] = x[k];
    }
  }
  __syncthreads();                     // cross-wave: FFT rows -> unpack+store

  // Hermitian unpack: S[2p][k] = (z[k]+conj(z[-k]))/2,
  //                   S[2p+1][k] = (z[k]-conj(z[-k]))/(2i)
  float2* So = Snew + b*FIELD;
  #pragma unroll
  for (int m = 0; m < 2; ++m) {
    int e = tid + (m << 10);           // 8 real rows x 256 = 2048
    int row = e >> 8, jj = e & 255;
    int p = row >> 1;
    float2 z  = AbS[p*ROWF2 + pdx(jj)];
    float2 z2 = AbS[p*ROWF2 + pdx((256 - jj) & 255)];
    float2 sv;
    if ((row & 1) == 0)
      sv = make_float2(0.5f*(z.x + z2.x), 0.5f*(z.y - z2.y));
    else
      sv = make_float2(0.5f*(z.y + z2.y), 0.5f*(z2.x - z.x));
    So[(row0 + row)*NN + jj] = sv;
  }
}

// ================================================================ B (R17 shape, fused rounds)
// 256 blocks x 512 threads. fwd col FFT * invLam/N^2 * inv col FFT, in
// place. 8 teams x 64 lanes, 4 fused rounds per FFT direction.
__global__ __launch_bounds__(512) void fft_cols(float2* __restrict__ S)
{
  __shared__ float2 Ab[8*ROWF2];
  __shared__ float2 tw[128];
  __shared__ float  lam[NN];
  int tid = threadIdx.x;
  int b = blockIdx.x >> 5;
  int col0 = (blockIdx.x & 31) << 3;

  if (tid < 128) {
    float sw, cw;
    __sincosf(-0.02454369260617026f * (float)tid, &sw, &cw);
    tw[tid] = make_float2(cw, sw);
  }
  if (tid < 256) {
    float s1 = __sinf(0.01227184630308512983f * (float)tid);   // pi/256 * k
    lam[tid] = -4.0f * s1 * s1 * (RDX*RDX);
  }

  float2* Sb = S + b*FIELD;
  #pragma unroll
  for (int k = 0; k < 4; ++k) {        // load transposed, bit-reversed
    int idx = tid + (k << 9);
    int i = idx >> 3, c = idx & 7;
    Ab[c*ROWF2 + pdx(rev8(i))] = Sb[i*NN + col0 + c];
  }
  __syncthreads();                     // cross-wave: scatter -> per-wave FFT

  int g = tid >> 6, lane = tid & 63;   // wave g owns column col0+g
  fft256_fwd_f2(Ab + g*ROWF2, lane, tw, true);

  // spectral scale: wave g touches only its own row -> wave order suffices
  float l2 = lam[col0 + g];
  #pragma unroll
  for (int r = 0; r < 4; ++r) {
    int k1 = lane + (r << 6);
    float den = lam[k1] + l2;
    float sc = ((k1 | (col0 + g)) == 0) ? 0.0f : (1.0f/den);
    sc *= (1.0f/65536.0f);             // fold in ifft2's 1/N^2
    float2 v = Ab[g*ROWF2 + pdx(k1)];
    Ab[g*ROWF2 + pdx(k1)] = make_float2(v.x*sc, v.y*sc);
  }
  wave_sync();

  fft256_inv_f2(Ab + g*ROWF2, lane, tw, true);
  __syncthreads();                     // cross-wave: FFT rows -> store

  #pragma unroll
  for (int k = 0; k < 4; ++k) {        // store transposed, un-reversed
    int idx = tid + (k << 9);
    int i = idx >> 3, c = idx & 7;
    Sb[i*NN + col0 + c] = Ab[c*ROWF2 + pdx(rev8(i))];
  }
}

// ================================================================ K1 (R9 fallback)
__global__ __launch_bounds__(512) void advect_div_fft(
    const float* __restrict__ inb, float* __restrict__ outb,
    float2* __restrict__ S, float* __restrict__ out,
    const unsigned* __restrict__ dtw, int T, int tm1)
{
  __shared__ float  Vs[8][NN];
  __shared__ float2 AbS[8*ROWF2];
  __shared__ float2 tw[128];
  const int tid = threadIdx.x;
  const int j   = tid & 255;
  const int h   = tid >> 8;           // 0 or 1
  const int b    = blockIdx.x >> 5;
  const int row0 = (blockIdx.x & 31) << 3;

  if (tid < 128) {
    float sw, cw;
    __sincosf(-0.02454369260617026f * (float)tid, &sw, &cw);  // -2pi/256
    tw[tid] = make_float2(cw, sw);
  }

  const float* Ub = inb + b*FIELD;
  const float* Vb = inb + TOTAL + b*FIELD;
  const float* Db = inb + 2*TOTAL + b*FIELD;
  float* Uo  = outb + b*FIELD;
  float* Vo  = outb + TOTAL + b*FIELD;
  float* Do_ = outb + 2*TOTAL + b*FIELD;

  const float dt = decode_dt(dtw);
  const float hdtdx = 0.5f*dt*RDX;

  if (tm1 >= 0) {                      // fused write_out of previous state
    #pragma unroll
    for (int k = 0; k < 4; ++k) {
      int pos = (row0 + h*4 + k)*NN + j;
      size_t o = ((size_t)(b*T + tm1)*FIELD + pos)*3u;
      out[o]   = Ub[pos];
      out[o+1] = Vb[pos];
      out[o+2] = Db[pos];
    }
  }

  const int kbeg = h ? 3 : -1;
  float u1r[5];
  #pragma unroll
  for (int kk = 0; kk < 5; ++kk) {
    int k = kbeg + kk;
    int r = (row0 + k) & NM;
    float u1, v1, d1;
    if (kk == 0) {
      advect_point<0>(Ub, Vb, Db, r, j, hdtdx, dt, u1, v1, d1);
    } else {
      advect_point<1>(Ub, Vb, Db, r, j, hdtdx, dt, u1, v1, d1);
      int gi = r*NN + j;
      Uo[gi] = u1; Vo[gi] = v1; Do_[gi] = d1;
      Vs[k][j] = v1;
    }
    u1r[kk] = u1;
  }
  __syncthreads();

  {  // div (backward diff) -> bit-reversed scatter (padded)
    int jm1 = (j - 1) & NM, rj = rev8(j);
    #pragma unroll
    for (int m = 0; m < 4; ++m) {
      int k = h*4 + m;
      float dv = (u1r[m+1] - u1r[m] + Vs[k][j] - Vs[k][jm1]) * RDX;
      AbS[k*ROWF2 + pdx(rj)] = make_float2(dv, 0.0f);
    }
  }
  __syncthreads();

  // fwd row FFT: 8 teams x 64 lanes
  const int g = tid >> 6, lane = tid & 63;
  fft256_dit_fwd<64>(AbS + g*ROWF2, lane, tw, true);
  __syncthreads();

  float2* Sb = S + b*FIELD;
  #pragma unroll
  for (int k = 0; k < 4; ++k) {
    int row = h*4 + k;
    Sb[(row0 + row)*NN + j] = AbS[row*ROWF2 + pdx(j)];
  }
}

// ================================================================ K2 (R9 fallback)
__global__ __launch_bounds__(512) void fft_cols_r9(float2* __restrict__ S)
{
  __shared__ float2 Ab[8*ROWF2];
  __shared__ float2 tw[128];
  __shared__ float  lam[NN];
  int tid = threadIdx.x;
  int b = blockIdx.x >> 5;
  int col0 = (blockIdx.x & 31) << 3;

  if (tid < 128) {
    float sw, cw;
    __sincosf(-0.02454369260617026f * (float)tid, &sw, &cw);
    tw[tid] = make_float2(cw, sw);
  }
  if (tid < 256) {
    float s1 = __sinf(0.01227184630308512983f * (float)tid);   // pi/256 * k
    lam[tid] = -4.0f * s1 * s1 * (RDX*RDX);
  }

  float2* Sb = S + b*FIELD;
  #pragma unroll
  for (int k = 0; k < 4; ++k) {        // load transposed, bit-reversed
    int idx = tid + (k << 9);
    int i = idx >> 3, c = idx & 7;
    Ab[c*ROWF2 + pdx(rev8(i))] = Sb[i*NN + col0 + c];
  }
  __syncthreads();                     // cross-wave: scatter -> per-wave FFT

  int g = tid >> 6, lane = tid & 63;   // wave g owns column-row g
  fft256_dit_fwd<64>(Ab + g*ROWF2, lane, tw, true);

  float l2 = lam[col0 + g];
  #pragma unroll
  for (int r = 0; r < 4; ++r) {
    int k1 = lane + (r << 6);
    float den = lam[k1] + l2;
    float sc = ((k1 | (col0 + g)) == 0) ? 0.0f : (1.0f/den);
    sc *= (1.0f/65536.0f);             // fold in ifft2's 1/N^2
    float2 v = Ab[g*ROWF2 + pdx(k1)];
    Ab[g*ROWF2 + pdx(k1)] = make_float2(v.x*sc, v.y*sc);
  }
  wave_sync();

  fft256_dif_inv<64>(Ab + g*ROWF2, lane, tw, true);
  __syncthreads();                     // cross-wave: FFT rows -> store

  #pragma unroll
  for (int k = 0; k < 4; ++k) {        // store transposed, un-reversed
    int idx = tid + (k << 9);
    int i = idx >> 3, c = idx & 7;
    Sb[i*NN + col0 + c] = Ab[c*ROWF2 + pdx(rev8(i))];
  }
}

// ================================================================ K3 (final correction)
__global__ __launch_bounds__(512) void fft_inv_correct(
    const float2* __restrict__ S, float* __restrict__ outb)
{
  __shared__ float2 Ab[9*ROWF2];
  __shared__ float  qs[9*NN];
  __shared__ float2 tw[128];
  int tid = threadIdx.x;
  int b = blockIdx.x >> 5;
  int row0 = (blockIdx.x & 31) << 3;

  if (tid < 128) {
    float sw, cw;
    __sincosf(-0.02454369260617026f * (float)tid, &sw, &cw);
    tw[tid] = make_float2(cw, sw);
  }

  const float2* Sb = S + b*FIELD;
  #pragma unroll
  for (int m = 0; m < 5; ++m) {        // load 9 rows, natural order (DIF in)
    int e = tid + m*512;
    if (e < 9*NN) {
      int k = e >> 8, j = e & 255;
      Ab[k*ROWF2 + pdx(j)] = Sb[((row0 + k) & NM)*NN + j];
    }
  }
  __syncthreads();

  int g = tid >> 5, lane = tid & 31;   // 16 teams of 32; 9 active
  bool active = (g < 9);
  fft256_dif_inv<32>(Ab + (active ? g : 8)*ROWF2, lane, tw, active);
  __syncthreads();

  #pragma unroll
  for (int m = 0; m < 5; ++m) {        // un-reverse gather -> qs natural
    int e = tid + m*512;
    if (e < 9*NN) {
      int k = e >> 8, j = e & 255;
      qs[k*NN + j] = Ab[k*ROWF2 + pdx(rev8(j))].x;
    }
  }
  __syncthreads();

  float* Ug = outb + b*FIELD;
  float* Vg = outb + TOTAL + b*FIELD;
  #pragma unroll
  for (int m = 0; m < 4; ++m) {
    int e = tid + m*512;               // 0..2047
    int k = e >> 8, j = e & 255;
    int gi = (row0 + k)*NN + j;
    float q0 = qs[k*NN + j];
    float q1 = qs[(k+1)*NN + j];
    float qj = qs[k*NN + ((j+1) & NM)];
    Ug[gi] -= (q1 - q0)*RDX;
    Vg[gi] -= (qj - q0)*RDX;
  }
}

// ================================================================ misc
__global__ __launch_bounds__(256) void write_out_k(
    const float* __restrict__ U, const float* __restrict__ V, const float* __restrict__ D,
    float* __restrict__ out, int t, int T)
{
  int idx = blockIdx.x*256 + threadIdx.x;
  int b = idx >> 16;
  int pos = idx & (FIELD-1);
  size_t o = ((size_t)(b*T + t)*FIELD + pos)*3u;
  out[o]   = U[idx];
  out[o+1] = V[idx];
  out[o+2] = D[idx];
}

__global__ __launch_bounds__(256) void init_state(
    const float* __restrict__ y0,
    float* __restrict__ U, float* __restrict__ V, float* __restrict__ D)
{
  int idx = blockIdx.x*256 + threadIdx.x;
  U[idx] = y0[idx*3];
  V[idx] = y0[idx*3+1];
  D[idx] = y0[idx*3+2];
}

// ================================================================ fallback
// R5-proven sincos/unpadded kernels (used only if ws too small).
__device__ __forceinline__ void fft_fwd_sc(float2* A, int lane) {
  #pragma unroll
  for (int s = 1; s <= 8; ++s) {
    int half = 1 << (s-1);
    float angscale = -6.28318530717958647692f / (float)(2*half);
    #pragma unroll
    for (int r = 0; r < 4; ++r) {
      int bfly = lane + (r << 5);
      int q = bfly & (half - 1);
      int g = (bfly >> (s-1)) << s;
      float sw, cw; __sincosf(angscale * (float)q, &sw, &cw);
      float2 a = A[g+q], b = A[g+q+half];
      float wbx = cw*b.x - sw*b.y, wby = cw*b.y + sw*b.x;
      A[g+q] = make_float2(a.x+wbx, a.y+wby);
      A[g+q+half] = make_float2(a.x-wbx, a.y-wby);
    }
    __syncthreads();
  }
}
__device__ __forceinline__ void fft_inv_sc(float2* A, int lane) {
  #pragma unroll
  for (int s = 8; s >= 1; --s) {
    int half = 1 << (s-1);
    float angscale = 6.28318530717958647692f / (float)(2*half);
    #pragma unroll
    for (int r = 0; r < 4; ++r) {
      int bfly = lane + (r << 5);
      int q = bfly & (half - 1);
      int g = (bfly >> (s-1)) << s;
      float sw, cw; __sincosf(angscale * (float)q, &sw, &cw);
      float2 a = A[g+q], b = A[g+q+half];
      float dx = a.x-b.x, dy = a.y-b.y;
      A[g+q] = make_float2(a.x+b.x, a.y+b.y);
      A[g+q+half] = make_float2(cw*dx - sw*dy, cw*dy + sw*dx);
    }
    __syncthreads();
  }
}

__global__ __launch_bounds__(256) void advect_kernel_fb(
    const float* __restrict__ U, const float* __restrict__ V, const float* __restrict__ D,
    float* __restrict__ Uo, float* __restrict__ Vo, float* __restrict__ Do_,
    const unsigned* __restrict__ dtw)
{
  int idx = blockIdx.x*256 + threadIdx.x;
  int j = idx & NM, i = (idx >> 8) & NM, base = (idx >> 16) * FIELD;
  float dt = decode_dt(dtw);
  float u1, v1, d1;
  advect_point<1>(U + base, V + base, D + base, i, j, 0.5f*dt*RDX, dt, u1, v1, d1);
  Uo[idx] = u1; Vo[idx] = v1; Do_[idx] = d1;
}

__global__ __launch_bounds__(256) void fft_rows_div_fb(
    const float* __restrict__ U2, const float* __restrict__ V2, float2* __restrict__ S)
{
  __shared__ float2 Ab[8*NN];
  int tid = threadIdx.x, b = blockIdx.x >> 5, row0 = (blockIdx.x & 31) << 3;
  const float* Ub = U2 + b*FIELD;
  const float* Vb = V2 + b*FIELD;
  int jm1 = (tid - 1) & NM, rj = rev8(tid);
  #pragma unroll
  for (int k = 0; k < 8; ++k) {
    int row = row0 + k, rm1 = (row - 1) & NM;
    float dv = (Ub[row*NN + tid] - Ub[rm1*NN + tid]
              + Vb[row*NN + tid] - Vb[row*NN + jm1]) * RDX;
    Ab[(k<<8) + rj] = make_float2(dv, 0.0f);
  }
  __syncthreads();
  int g = tid >> 5, lane = tid & 31;
  fft_fwd_sc(Ab + (g<<8), lane);
  float2* Sb = S + b*FIELD;
  #pragma unroll
  for (int k = 0; k < 8; ++k)
    Sb[(row0 + k)*NN + tid] = Ab[(k<<8) + tid];
}

__global__ __launch_bounds__(256) void fft_cols_fb(float2* __restrict__ S)
{
  __shared__ float2 Ab[8*NN];
  int tid = threadIdx.x, b = blockIdx.x >> 5, col0 = (blockIdx.x & 31) << 3;
  float2* Sb = S + b*FIELD;
  #pragma unroll
  for (int k = 0; k < 8; ++k) {
    int idx = tid + (k << 8);
    int i = idx >> 3, c = idx & 7;
    Ab[(c<<8) + rev8(i)] = Sb[i*NN + col0 + c];
  }
  __syncthreads();
  int g = tid >> 5, lane = tid & 31;
  fft_fwd_sc(Ab + (g<<8), lane);
  int k2 = col0 + g;
  float s2 = __sinf(0.01227184630308512983f * (float)k2);
  float l2 = -4.0f * s2 * s2 * (RDX*RDX);
  #pragma unroll
  for (int r = 0; r < 8; ++r) {
    int k1 = lane + (r << 5);
    float s1 = __sinf(0.01227184630308512983f * (float)k1);
    float l1 = -4.0f * s1 * s1 * (RDX*RDX);
    float den = l1 + l2;
    float sc = ((k1 | k2) == 0) ? 0.0f : (1.0f/den);
    sc *= (1.0f/65536.0f);
    float2 v = Ab[(g<<8) + k1];
    Ab[(g<<8) + k1] = make_float2(v.x*sc, v.y*sc);
  }
  __syncthreads();
  fft_inv_sc(Ab + (g<<8), lane);
  #pragma unroll
  for (int k = 0; k < 8; ++k) {
    int idx = tid + (k << 8);
    int i = idx >> 3, c = idx & 7;
    Sb[i*NN + col0 + c] = Ab[(c<<8) + rev8(i)];
  }
}

__global__ __launch_bounds__(256) void fft_rows_inv_fb(
    const float2* __restrict__ S, float* __restrict__ Q)
{
  __shared__ float2 Ab[8*NN];
  int tid = threadIdx.x, b = blockIdx.x >> 5, row0 = (blockIdx.x & 31) << 3;
  const float2* Sb = S + b*FIELD;
  #pragma unroll
  for (int k = 0; k < 8; ++k)
    Ab[(k<<8) + tid] = Sb[(row0 + k)*NN + tid];
  __syncthreads();
  int g = tid >> 5, lane = tid & 31;
  fft_inv_sc(Ab + (g<<8), lane);
  float* Qb = Q + b*FIELD;
  int rj = rev8(tid);
  #pragma unroll
  for (int k = 0; k < 8; ++k)
    Qb[(row0 + k)*NN + tid] = Ab[(k<<8) + rj].x;
}

__global__ __launch_bounds__(256) void correct_uv_fb(
    float* __restrict__ U2, float* __restrict__ V2, const float* __restrict__ Q)
{
  int idx = blockIdx.x*256 + threadIdx.x;
  int j = idx & NM, i = (idx >> 8) & NM, base = (idx >> 16) * FIELD;
  const float* Qb = Q + base;
  float q0 = Qb[i*NN + j];
  float qi = Qb[((i+1)&NM)*NN + j];
  float qj = Qb[i*NN + ((j+1)&NM)];
  U2[idx] -= (qi - q0)*RDX;
  V2[idx] -= (qj - q0)*RDX;
}

// ---------------------------------------------------------------- launch
extern "C" void kernel_launch(void* const* d_in, const int* in_sizes, int n_in,
                              void* d_out, int out_size, void* d_ws, size_t ws_size,
                              hipStream_t stream) {
  (void)in_sizes; (void)n_in;
  const float*    y0  = (const float*)d_in[0];
  const unsigned* dtw = (const unsigned*)d_in[1];
  float* out = (float*)d_out;

  int T = out_size / (3*FIELD*BATCH);
  if (T < 1) T = 1;

  float* wsf = (float*)d_ws;

  // ---- preferred: fused 2-kernel/step path (needs 10*TOTAL floats) ----
  if (ws_size >= (size_t)10*TOTAL*sizeof(float)) {
    float* stA = wsf;                  // 3*TOTAL
    float* stB = wsf + 3*TOTAL;        // 3*TOTAL
    float2* Sa = (float2*)(wsf + 6*TOTAL);   // TOTAL float2
    float2* Sc = (float2*)(wsf + 8*TOTAL);   // TOTAL float2

    init_state<<<TOTAL/256, 256, 0, stream>>>(y0, stA, stA+TOTAL, stA+2*TOTAL);
    float* inb  = stA;
    float* outb = stB;
    float2* Sr = Sa;                   // spectral q from previous step
    float2* Sw = Sc;                   // new div spectral
    int step = 0;
    for (int t = 0; t < T; ++t) {
      for (int s = 0; s < 10; ++s) {
        int tm1 = (s == 0) ? (t - 1) : -1;
        proj_advect_fft8<<<256, 1024, 0, stream>>>(Sr, inb, outb, Sw, out,
                                                   dtw, T, tm1, step == 0);
        fft_cols<<<256, 512, 0, stream>>>(Sw);
        float*  t1 = inb; inb = outb; outb = t1;
        float2* t2 = Sr;  Sr  = Sw;   Sw  = t2;
        ++step;
      }
    }
    // final state in inb is uncorrected; Sr holds its Poisson solution
    fft_inv_correct<<<256, 512, 0, stream>>>(Sr, inb);
    write_out_k<<<TOTAL/256, 256, 0, stream>>>(inb, inb+TOTAL, inb+2*TOTAL,
                                               out, T-1, T);
    return;
  }

  // ---- R9 3-kernel path (needs 8*TOTAL floats) ----
  if (ws_size >= (size_t)8*TOTAL*sizeof(float)) {
    float2* S = (float2*)(wsf + 6*TOTAL);
    init_state<<<TOTAL/256, 256, 0, stream>>>(y0, wsf, wsf+TOTAL, wsf+2*TOTAL);
    float* inb = wsf;
    float* outb = wsf + 3*TOTAL;
    for (int t = 0; t < T; ++t) {
      for (int s = 0; s < 10; ++s) {
        int tm1 = (s == 0) ? (t - 1) : -1;
        advect_div_fft <<<256, 512, 0, stream>>>(inb, outb, S, out, dtw, T, tm1);
        fft_cols_r9    <<<256, 512, 0, stream>>>(S);
        fft_inv_correct<<<256, 512, 0, stream>>>(S, outb);
        float* tmp = inb; inb = outb; outb = tmp;
      }
    }
    write_out_k<<<TOTAL/256, 256, 0, stream>>>(inb, inb+TOTAL, inb+2*TOTAL,
                                               out, T-1, T);
    return;
  }

  // ---- R5 5-kernel path with aliased S/Q (12.6 MB) ----
  float* bank0 = wsf;
  float* bank1 = wsf + 3*TOTAL;
  init_state<<<TOTAL/256, 256, 0, stream>>>(y0, bank0, bank0+TOTAL, bank0+2*TOTAL);
  float* inb = bank0;
  float* outb = bank1;
  for (int t = 0; t < T; ++t) {
    for (int s = 0; s < 10; ++s) {
      float *Ui = inb,  *Vi = inb + TOTAL,  *Di = inb + 2*TOTAL;
      float *Uo = outb, *Vo = outb + TOTAL, *Do_ = outb + 2*TOTAL;
      float2* S = (float2*)(inb + TOTAL);
      float*  Q = inb;
      advect_kernel_fb<<<TOTAL/256, 256, 0, stream>>>(Ui, Vi, Di, Uo, Vo, Do_, dtw);
      fft_rows_div_fb <<<BATCH*32, 256, 0, stream>>>(Uo, Vo, S);
      fft_cols_fb     <<<BATCH*32, 256, 0, stream>>>(S);
      fft_rows_inv_fb <<<BATCH*32, 256, 0, stream>>>(S, Q);
      correct_uv_fb   <<<TOTAL/256, 256, 0, stream>>>(Uo, Vo, Q);
      float* tmp = inb; inb = outb; outb = tmp;
    }
    write_out_k<<<TOTAL/256, 256, 0, stream>>>(inb, inb+TOTAL, inb+2*TOTAL, out, t, T);
  }
}

// Round 13
// 1955.295 us; speedup vs baseline: 1.0627x; 1.0197x over previous
//
#include <hip/hip_runtime.h>
#include <hip/hip_bf16.h>

// NS solver: 256x256 periodic, B=8, NC=3 (u,v,density), T outer x 10 inner steps.
// y0 = fp32, dt = fp32, out = fp32 (established R1-R5). Internal state fp32.
//
// R22: Hermitian-half B. R21 (packed real FFTs in A) was neutral -> FFT
// compute off the critical path. Cut B's TRAFFIC instead: S is Hermitian in
// j (A's phase-5 unpack writes it so), lambda symmetric in both wavenumbers
// -> C_{256-j}[i] = conj(C_j[i]). B processes only columns 0..128:
// grid 256 -> 136 blocks (dim3(17,8)), read traffic halved, FFT work -47%;
// mirror-write conj into cols 129..255 (write traffic unchanged). Last
// block's cols 129..135 computed but never stored (racy reads discarded --
// harmless). Algebraically identical output. A unchanged (R21-verified).

#define NN 256
#define NM 255
#define FIELD (NN*NN)
#define BATCH 8
#define TOTAL (BATCH*FIELD)
#define ROWF2 264   // padded LDS row stride in float2 (256 + 8)

constexpr float RDX  = 40.743665431525205f;   // N/(2*pi) = 1/DX
constexpr float VISC = 1e-3f;

__device__ __forceinline__ int rev8(int x) { return (int)(__brev((unsigned)x) >> 24); }
__device__ __forceinline__ int pdx(int x)  { return x + (x >> 5); }

// Intra-wave LDS exchange fence (R13-verified on gfx950): compiler fence +
// sched barrier. A wave's DS ops complete in program order -> no s_barrier
// needed when producer and consumer lanes share a wave.
__device__ __forceinline__ void wave_sync() {
  asm volatile("" ::: "memory");
  __builtin_amdgcn_wave_barrier();
}

__device__ __forceinline__ float decode_dt(const unsigned* dtw) {
  unsigned w = dtw[0];
  float cf = __uint_as_float(w);
  float cb = __uint_as_float((w & 0xFFFFu) << 16);
  bool v32 = (cf > 1e-8f) && (cf < 1.0f);          // NaN-safe
  bool vbf = (cb > 1e-8f) && (cb < 1.0f);
  return v32 ? cf : (vbf ? cb : 1e-3f);
}

// ---------------------------------------------------------------- advection
__device__ __forceinline__ float face_flux(float uf, float cm, float c0,
                                           float cp, float cpp, float hdtdx) {
  float dc = cp - c0;
  float f_low  = (uf >= 0.0f) ? uf*c0 : uf*cp;
  float f_high = uf*0.5f*(c0+cp) - hdtdx*uf*uf*dc;
  float dc_up  = (uf >= 0.0f) ? (c0 - cm) : (cpp - cp);
  float dc_safe = (fabsf(dc) > 1e-12f) ? dc : 1e-12f;
  // van Leer: (a*b>0) ? 2a/(a+b) : 0
  float phi = (dc_up * dc_safe > 0.0f) ? (2.0f*dc_up/(dc_up + dc_safe)) : 0.0f;
  return f_low + phi*(f_high - f_low);
}

// global-memory stencil variant (fallback paths)
template<int NEED_VD>
__device__ __forceinline__ void advect_point(
    const float* __restrict__ Ub, const float* __restrict__ Vb,
    const float* __restrict__ Db,
    int i, int j, float hdtdx, float dt,
    float& u1, float& v1, float& d1)
{
  int im2 = ((i-2)&NM)*NN, im1 = ((i-1)&NM)*NN, i0r = i*NN,
      ip1 = ((i+1)&NM)*NN, ip2 = ((i+2)&NM)*NN;
  int jm2 = (j-2)&NM, jm1 = (j-1)&NM, jp1 = (j+1)&NM, jp2 = (j+2)&NM;

  float u_c  = Ub[i0r+j];
  float u_im2= Ub[im2+j], u_im1 = Ub[im1+j], u_ip1 = Ub[ip1+j], u_ip2 = Ub[ip2+j];
  float u_jm2= Ub[i0r+jm2], u_jm1 = Ub[i0r+jm1], u_jp1 = Ub[i0r+jp1], u_jp2 = Ub[i0r+jp2];
  float v_c  = Vb[i0r+j];
  float v_jm1= Vb[i0r+jm1], v_jp1 = Vb[i0r+jp1];

  float ufI0 = 0.5f*(u_c + u_ip1);
  float ufIm = 0.5f*(u_im1 + u_c);
  float vfJ0 = 0.5f*(v_c + v_jp1);
  float vfJm = 0.5f*(v_jm1 + v_c);

  float tu = -(( face_flux(ufI0, u_im1, u_c, u_ip1, u_ip2, hdtdx)
               - face_flux(ufIm, u_im2, u_im1, u_c, u_ip1, hdtdx))
             + ( face_flux(vfJ0, u_jm1, u_c, u_jp1, u_jp2, hdtdx)
               - face_flux(vfJm, u_jm2, u_jm1, u_c, u_jp1, hdtdx))) * RDX;
  float lapu = (u_im1 + u_ip1 + u_jm1 + u_jp1 - 4.0f*u_c) * (RDX*RDX);
  u1 = u_c + dt*(tu + VISC*lapu);

  if (NEED_VD) {
    float v_im2= Vb[im2+j], v_im1 = Vb[im1+j], v_ip1 = Vb[ip1+j], v_ip2 = Vb[ip2+j];
    float v_jm2= Vb[i0r+jm2], v_jp2 = Vb[i0r+jp2];
    float d_c  = Db[i0r+j];
    float d_im2= Db[im2+j], d_im1 = Db[im1+j], d_ip1 = Db[ip1+j], d_ip2 = Db[ip2+j];
    float d_jm2= Db[i0r+jm2], d_jm1 = Db[i0r+jm1], d_jp1 = Db[i0r+jp1], d_jp2 = Db[i0r+jp2];

    float tv = -(( face_flux(ufI0, v_im1, v_c, v_ip1, v_ip2, hdtdx)
                 - face_flux(ufIm, v_im2, v_im1, v_c, v_ip1, hdtdx))
               + ( face_flux(vfJ0, v_jm1, v_c, v_jp1, v_jp2, hdtdx)
                 - face_flux(vfJm, v_jm2, v_jm1, v_c, v_jp1, hdtdx))) * RDX;
    float lapv = (v_im1 + v_ip1 + v_jm1 + v_jp1 - 4.0f*v_c) * (RDX*RDX);
    v1 = v_c + dt*(tv + VISC*lapv);

    float td = -(( face_flux(ufI0, d_im1, d_c, d_ip1, d_ip2, hdtdx)
                 - face_flux(ufIm, d_im2, d_im1, d_c, d_ip1, hdtdx))
               + ( face_flux(vfJ0, d_jm1, d_c, d_jp1, d_jp2, hdtdx)
                 - face_flux(vfJm, d_jm2, d_jm1, d_c, d_jp1, hdtdx))) * RDX;
    d1 = d_c + dt*td;
  }
}

// LDS-slab stencil variant (fused A kernel). ku = u-slab row of the point,
// kv = v/d-slab row of the point. Slabs are contiguous (no row wrap); j wraps.
template<int NEED_VD>
__device__ __forceinline__ void advect_point_lds(
    const float* __restrict__ U, const float* __restrict__ V,
    const float* __restrict__ D,
    int ku, int kv, int j, float hdtdx, float dt,
    float& u1, float& v1, float& d1)
{
  int jm2 = (j-2)&NM, jm1 = (j-1)&NM, jp1 = (j+1)&NM, jp2 = (j+2)&NM;

  const float* Ur = U + ku*NN;
  float u_c  = Ur[j];
  float u_im2= U[(ku-2)*NN+j], u_im1 = U[(ku-1)*NN+j],
        u_ip1= U[(ku+1)*NN+j], u_ip2 = U[(ku+2)*NN+j];
  float u_jm2= Ur[jm2], u_jm1 = Ur[jm1], u_jp1 = Ur[jp1], u_jp2 = Ur[jp2];
  const float* Vr = V + kv*NN;
  float v_c  = Vr[j];
  float v_jm1= Vr[jm1], v_jp1 = Vr[jp1];

  float ufI0 = 0.5f*(u_c + u_ip1);
  float ufIm = 0.5f*(u_im1 + u_c);
  float vfJ0 = 0.5f*(v_c + v_jp1);
  float vfJm = 0.5f*(v_jm1 + v_c);

  float tu = -(( face_flux(ufI0, u_im1, u_c, u_ip1, u_ip2, hdtdx)
               - face_flux(ufIm, u_im2, u_im1, u_c, u_ip1, hdtdx))
             + ( face_flux(vfJ0, u_jm1, u_c, u_jp1, u_jp2, hdtdx)
               - face_flux(vfJm, u_jm2, u_jm1, u_c, u_jp1, hdtdx))) * RDX;
  float lapu = (u_im1 + u_ip1 + u_jm1 + u_jp1 - 4.0f*u_c) * (RDX*RDX);
  u1 = u_c + dt*(tu + VISC*lapu);

  if (NEED_VD) {
    float v_im2= V[(kv-2)*NN+j], v_im1 = V[(kv-1)*NN+j],
          v_ip1= V[(kv+1)*NN+j], v_ip2 = V[(kv+2)*NN+j];
    float v_jm2= Vr[jm2], v_jp2 = Vr[jp2];
    const float* Dr = D + kv*NN;
    float d_c  = Dr[j];
    float d_im2= D[(kv-2)*NN+j], d_im1 = D[(kv-1)*NN+j],
          d_ip1= D[(kv+1)*NN+j], d_ip2 = D[(kv+2)*NN+j];
    float d_jm2= Dr[jm2], d_jm1 = Dr[jm1], d_jp1 = Dr[jp1], d_jp2 = Dr[jp2];

    float tv = -(( face_flux(ufI0, v_im1, v_c, v_ip1, v_ip2, hdtdx)
                 - face_flux(ufIm, v_im2, v_im1, v_c, v_ip1, hdtdx))
               + ( face_flux(vfJ0, v_jm1, v_c, v_jp1, v_jp2, hdtdx)
                 - face_flux(vfJm, v_jm2, v_jm1, v_c, v_jp1, hdtdx))) * RDX;
    float lapv = (v_im1 + v_ip1 + v_jm1 + v_jp1 - 4.0f*v_c) * (RDX*RDX);
    v1 = v_c + dt*(tv + VISC*lapv);

    float td = -(( face_flux(ufI0, d_im1, d_c, d_ip1, d_ip2, hdtdx)
                 - face_flux(ufIm, d_im2, d_im1, d_c, d_ip1, hdtdx))
               + ( face_flux(vfJ0, d_jm1, d_c, d_jp1, d_jp2, hdtdx)
                 - face_flux(vfJm, d_jm2, d_jm1, d_c, d_jp1, hdtdx))) * RDX;
    d1 = d_c + dt*td;
  }
}

// ---------------------------------------------------------------- FFT cores
// Table-driven, padded-LDS. tw[m] = exp(-2*pi*i*m/256), m<128. Stage-s
// twiddle = tw[q<<(8-s)] (fwd), conjugate for inverse. A = padded row base;
// element x lives at A[pdx(x)].
// WAVE-SYNCHRONOUS (R13): exchanges within a wave need only wave_sync().
//
// RADIX-16 ROUNDS (R19/R20-HW-verified): stages 1-4 confined to contiguous
// 16-blocks, stages 5-8 to stride-16 residue classes. One lane holds 16
// float2 in regs -> 4 stages per LDS round -> 2 rounds per direction.

// --- radix-16 in-register stage groups (lane-local x[16]) ---
__device__ __forceinline__ void r16_fwd_low(float2* x, const float2* tw) {
  #pragma unroll
  for (int s = 1; s <= 4; ++s) {
    int h = 1 << (s-1);
    #pragma unroll
    for (int b = 0; b < 8; ++b) {
      int q = b & (h-1);
      int t = ((b >> (s-1)) << s) + q;
      float2 w = tw[q << (8-s)];
      float2 a = x[t], c = x[t+h];
      float wbx = w.x*c.x - w.y*c.y, wby = w.x*c.y + w.y*c.x;
      x[t]   = make_float2(a.x+wbx, a.y+wby);
      x[t+h] = make_float2(a.x-wbx, a.y-wby);
    }
  }
}
__device__ __forceinline__ void r16_fwd_high(float2* x, int r, const float2* tw) {
  #pragma unroll
  for (int s = 5; s <= 8; ++s) {
    int hp = 1 << (s-5);
    #pragma unroll
    for (int b = 0; b < 8; ++b) {
      int qp = b & (hp-1);
      int t = ((b >> (s-5)) << (s-4)) + qp;
      float2 w = tw[(r + (qp<<4)) << (8-s)];
      float2 a = x[t], c = x[t+hp];
      float wbx = w.x*c.x - w.y*c.y, wby = w.x*c.y + w.y*c.x;
      x[t]    = make_float2(a.x+wbx, a.y+wby);
      x[t+hp] = make_float2(a.x-wbx, a.y-wby);
    }
  }
}
__device__ __forceinline__ void r16_inv_high(float2* x, int r, const float2* tw) {
  #pragma unroll
  for (int s = 8; s >= 5; --s) {
    int hp = 1 << (s-5);
    #pragma unroll
    for (int b = 0; b < 8; ++b) {
      int qp = b & (hp-1);
      int t = ((b >> (s-5)) << (s-4)) + qp;
      float2 w = tw[(r + (qp<<4)) << (8-s)];
      float2 a = x[t], c = x[t+hp];
      float dx = a.x-c.x, dy = a.y-c.y;
      x[t]    = make_float2(a.x+c.x, a.y+c.y);
      x[t+hp] = make_float2(w.x*dx + w.y*dy, w.x*dy - w.y*dx);
    }
  }
}
__device__ __forceinline__ void r16_inv_low(float2* x, const float2* tw) {
  #pragma unroll
  for (int s = 4; s >= 1; --s) {
    int h = 1 << (s-1);
    #pragma unroll
    for (int b = 0; b < 8; ++b) {
      int q = b & (h-1);
      int t = ((b >> (s-1)) << s) + q;
      float2 w = tw[q << (8-s)];
      float2 a = x[t], c = x[t+h];
      float dx = a.x-c.x, dy = a.y-c.y;
      x[t]   = make_float2(a.x+c.x, a.y+c.y);
      x[t+h] = make_float2(w.x*dx + w.y*dy, w.x*dy - w.y*dx);
    }
  }
}

// --- R17 fused 2-stage rounds (B kernel) ---
// fwd DIT, fused stage pairs (1,2),(3,4),(5,6),(7,8). lane in [0,64).
__device__ __forceinline__ void fft256_fwd_f2(float2* __restrict__ A, int lane,
                                              const float2* __restrict__ tw,
                                              bool active)
{
  #pragma unroll
  for (int s = 1; s <= 8; s += 2) {
    if (active) {
      int half = 1 << (s-1);
      int q2 = lane & (half - 1);
      int i0 = ((lane >> (s-1)) << (s+1)) + q2;
      float2 a0 = A[pdx(i0)];
      float2 a1 = A[pdx(i0 + half)];
      float2 a2 = A[pdx(i0 + 2*half)];
      float2 a3 = A[pdx(i0 + 3*half)];
      // stage s: pairs (a0,a1),(a2,a3), twiddle tw[q2<<(8-s)]
      float2 w1 = tw[q2 << (8 - s)];
      float wbx = w1.x*a1.x - w1.y*a1.y, wby = w1.x*a1.y + w1.y*a1.x;
      float2 b0 = make_float2(a0.x + wbx, a0.y + wby);
      float2 b1 = make_float2(a0.x - wbx, a0.y - wby);
      wbx = w1.x*a3.x - w1.y*a3.y; wby = w1.x*a3.y + w1.y*a3.x;
      float2 b2 = make_float2(a2.x + wbx, a2.y + wby);
      float2 b3 = make_float2(a2.x - wbx, a2.y - wby);
      // stage s+1: pairs (b0,b2) tw[q2<<(7-s)], (b1,b3) tw[(q2+half)<<(7-s)]
      float2 w2 = tw[q2 << (7 - s)];
      float2 w3 = tw[(q2 + half) << (7 - s)];
      wbx = w2.x*b2.x - w2.y*b2.y; wby = w2.x*b2.y + w2.y*b2.x;
      A[pdx(i0)]            = make_float2(b0.x + wbx, b0.y + wby);
      A[pdx(i0 + 2*half)]   = make_float2(b0.x - wbx, b0.y - wby);
      wbx = w3.x*b3.x - w3.y*b3.y; wby = w3.x*b3.y + w3.y*b3.x;
      A[pdx(i0 + half)]     = make_float2(b1.x + wbx, b1.y + wby);
      A[pdx(i0 + 3*half)]   = make_float2(b1.x - wbx, b1.y - wby);
    }
    wave_sync();
  }
}

// inv DIF, fused stage pairs (8,7),(6,5),(4,3),(2,1). lane in [0,64).
__device__ __forceinline__ void fft256_inv_f2(float2* __restrict__ A, int lane,
                                              const float2* __restrict__ tw,
                                              bool active)
{
  #pragma unroll
  for (int s = 8; s >= 2; s -= 2) {
    if (active) {
      int h = 1 << (s-2);              // half of stage s-1
      int q2 = lane & (h - 1);
      int i0 = ((lane >> (s-2)) << s) + q2;
      float2 a0 = A[pdx(i0)];
      float2 a1 = A[pdx(i0 + h)];
      float2 a2 = A[pdx(i0 + 2*h)];
      float2 a3 = A[pdx(i0 + 3*h)];
      // stage s (half=2h): pairs (a0,a2) q=q2, (a1,a3) q=q2+h
      float2 w1 = tw[q2 << (8 - s)];
      float2 w2 = tw[(q2 + h) << (8 - s)];
      float dx = a0.x - a2.x, dy = a0.y - a2.y;
      float2 b0 = make_float2(a0.x + a2.x, a0.y + a2.y);
      float2 b2 = make_float2(w1.x*dx + w1.y*dy, w1.x*dy - w1.y*dx);
      dx = a1.x - a3.x; dy = a1.y - a3.y;
      float2 b1 = make_float2(a1.x + a3.x, a1.y + a3.y);
      float2 b3 = make_float2(w2.x*dx + w2.y*dy, w2.x*dy - w2.y*dx);
      // stage s-1 (half=h): pairs (b0,b1) and (b2,b3), both q=q2
      float2 w3 = tw[q2 << (9 - s)];
      dx = b0.x - b1.x; dy = b0.y - b1.y;
      A[pdx(i0)]       = make_float2(b0.x + b1.x, b0.y + b1.y);
      A[pdx(i0 + h)]   = make_float2(w3.x*dx + w3.y*dy, w3.x*dy - w3.y*dx);
      dx = b2.x - b3.x; dy = b2.y - b3.y;
      A[pdx(i0 + 2*h)] = make_float2(b2.x + b3.x, b2.y + b3.y);
      A[pdx(i0 + 3*h)] = make_float2(w3.x*dx + w3.y*dy, w3.x*dy - w3.y*dx);
    }
    wave_sync();
  }
}

// Legacy single-stage variants (fallback paths + final correction kernel).
template<int W>
__device__ __forceinline__ void fft256_dit_fwd(float2* __restrict__ A, int lane,
                                               const float2* __restrict__ tw,
                                               bool active)
{
  #pragma unroll
  for (int s = 1; s <= 8; ++s) {
    int half = 1 << (s-1);
    if (active) {
      #pragma unroll
      for (int r = 0; r < 128/W; ++r) {
        int bfly = lane + r*W;
        int q = bfly & (half - 1);
        int g = (bfly >> (s-1)) << s;
        float2 w = tw[q << (8 - s)];
        float2 a = A[pdx(g + q)];
        float2 b = A[pdx(g + q + half)];
        float wbx = w.x*b.x - w.y*b.y;
        float wby = w.x*b.y + w.y*b.x;
        A[pdx(g + q)]        = make_float2(a.x + wbx, a.y + wby);
        A[pdx(g + q + half)] = make_float2(a.x - wbx, a.y - wby);
      }
    }
    wave_sync();
  }
}

template<int W>
__device__ __forceinline__ void fft256_dif_inv(float2* __restrict__ A, int lane,
                                               const float2* __restrict__ tw,
                                               bool active)
{
  #pragma unroll
  for (int s = 8; s >= 1; --s) {
    int half = 1 << (s-1);
    if (active) {
      #pragma unroll
      for (int r = 0; r < 128/W; ++r) {
        int bfly = lane + r*W;
        int q = bfly & (half - 1);
        int g = (bfly >> (s-1)) << s;
        float2 w = tw[q << (8 - s)];      // conj applied below (inverse)
        float2 a = A[pdx(g + q)];
        float2 b = A[pdx(g + q + half)];
        float dx = a.x - b.x, dy = a.y - b.y;
        A[pdx(g + q)]        = make_float2(a.x + b.x, a.y + b.y);
        A[pdx(g + q + half)] = make_float2(w.x*dx + w.y*dy, w.x*dy - w.y*dx);
      }
    }
    wave_sync();
  }
}

// ================================================================ A (fused, 8-row, 1024 thr)
// 256 blocks x 1024 threads. Per block: batch b = bid>>5, rows row0..row0+7.
//  0. issue U/V/D global->reg staging loads (consumed in phase 2)
//  1. PACKED inv row FFT: 7 packed pairs (S[2p]+i*S[2p+1]) of the 14 halo
//     rows of S_prev (7 groups x 16 lanes, radix-16, 2 LDS rounds);
//     IFFT output .x/.y = the two real q rows.
//  2. q gather; corrected u (13 rows), v (12), d (12) slabs in LDS (from regs)
//  3. optional trajectory write-out of corrected state t-1 (owned 8 rows)
//  4. advect from LDS: quarter q -> u-only row 2q-1, full rows 2q, 2q+1
//  5. div -> PACKED fwd row FFT: 4 packed pairs (div rows 2q + i*2q+1),
//     Hermitian unpack at store -> S_new (all 8 real rows)
// Slab rows: q row k <-> global row0-3+k (k in [0,13])
//            u row k <-> global row0-3+k (k in [0,12])
//            v,d row k <-> global row0-2+k (k in [0,11])
// LDS aliasing (R12): Vs -> qs (dead after phase 2); Dss -> AbS rows 8..13
// (phase-1 uses rows 0..6, phase-5 rows 0..3 -- disjoint). Total ~69 KB.
__global__ __launch_bounds__(1024) void proj_advect_fft8(
    const float2* __restrict__ Sprev, const float* __restrict__ inb,
    float* __restrict__ outb, float2* __restrict__ Snew,
    float* __restrict__ out, const unsigned* __restrict__ dtw,
    int T, int tm1, int first)
{
  __shared__ float2 tw[128];
  __shared__ float2 AbS[14*ROWF2];
  __shared__ float  qs [14*NN];
  __shared__ float  Ucs[13*NN];
  __shared__ float  Vcs[12*NN];
  float* Dss = (float*)(AbS + 8*ROWF2);  // 12*NN floats; phases 1/5 use rows 0..6
  float* Vs  = qs;                       // 8*NN floats; qs dead after phase 2

  const int tid  = threadIdx.x;
  const int j    = tid & 255;
  const int qtr  = tid >> 8;           // 0..3
  const int b    = blockIdx.x >> 5;
  const int row0 = (blockIdx.x & 31) << 3;

  if (tid < 128) {
    float sw, cw;
    __sincosf(-0.02454369260617026f * (float)tid, &sw, &cw);  // -2pi/256
    tw[tid] = make_float2(cw, sw);
  }

  const float dt = decode_dt(dtw);
  const float hdtdx = 0.5f*dt*RDX;

  const float* Ub = inb + b*FIELD;
  const float* Vb = inb + TOTAL + b*FIELD;
  const float* Db = inb + 2*TOTAL + b*FIELD;
  float* Uo  = outb + b*FIELD;
  float* Vo  = outb + TOTAL + b*FIELD;
  float* Do_ = outb + 2*TOTAL + b*FIELD;

  // ---- phase 0: early global->reg staging (T14). Latency hides under phase 1.
  float u_reg[4], v_reg[3], d_reg[3];
  #pragma unroll
  for (int m = 0; m < 4; ++m) {        // U: 13 rows = 3328 elems
    int e = tid + (m << 10);
    if (e < 13*NN) {
      int k = e >> 8, jj = e & 255;
      u_reg[m] = Ub[((row0 - 3 + k) & NM)*NN + jj];
    }
  }
  #pragma unroll
  for (int m = 0; m < 3; ++m) {        // V, D: 12 rows = 3072 = 3*1024
    int e = tid + (m << 10);
    int k = e >> 8, jj = e & 255;
    int gr = ((row0 - 2 + k) & NM)*NN;
    v_reg[m] = Vb[gr + jj];
    d_reg[m] = Db[gr + jj];
  }

  // ---- phase 1: PACKED inv row FFT of 14 rows -> qs (skip on step 0)
  // z_p[j] = S[row0-3+2p][j] + i*S[row0-3+2p+1][j]; IFFT(z) = q_a + i*q_b
  // (valid since S Hermitian in j -> q rows real).
  if (!first) {
    const float2* Sb = Sprev + b*FIELD;
    #pragma unroll
    for (int m = 0; m < 2; ++m) {      // 7*256 = 1792 elems
      int e = tid + (m << 10);
      if (e < 7*NN) {
        int p = e >> 8, jj = e & 255;
        float2 sa = Sb[((row0 - 3 + 2*p) & NM)*NN + jj];
        float2 sc = Sb[((row0 - 2 + 2*p) & NM)*NN + jj];
        AbS[p*ROWF2 + pdx(jj)] = make_float2(sa.x - sc.y, sa.y + sc.x);
      }
    }
    __syncthreads();                   // cross-wave: scatter -> FFT groups

    {
      const int g16 = tid >> 4;        // 7 active groups (threads 0..111)
      const int r   = tid & 15;
      if (g16 < 7) {                   // round 1: inv stages 8-5 (stride-16)
        float2* Ar = AbS + g16*ROWF2;
        float2 x[16];
        #pragma unroll
        for (int k = 0; k < 16; ++k) x[k] = Ar[pdx(r + (k<<4))];
        r16_inv_high(x, r, tw);
        #pragma unroll
        for (int k = 0; k < 16; ++k) Ar[pdx(r + (k<<4))] = x[k];
      }
      wave_sync();
      if (g16 < 7) {                   // round 2: inv stages 4-1 (16-blocks)
        float2* Ar = AbS + g16*ROWF2;
        float2 x[16];
        #pragma unroll
        for (int t = 0; t < 16; ++t) x[t] = Ar[pdx((r<<4) + t)];
        r16_inv_low(x, tw);
        #pragma unroll
        for (int t = 0; t < 16; ++t) Ar[pdx((r<<4) + t)] = x[t];
      }
    }
    __syncthreads();                   // cross-wave: FFT rows -> qs gather

    #pragma unroll
    for (int m = 0; m < 2; ++m) {      // un-reverse gather -> two q rows/pair
      int e = tid + (m << 10);
      if (e < 7*NN) {
        int p = e >> 8, jj = e & 255;
        float2 z = AbS[p*ROWF2 + pdx(rev8(jj))];
        qs[(2*p)*NN + jj]   = z.x;
        qs[(2*p+1)*NN + jj] = z.y;
      }
    }
    __syncthreads();
  } else {
    __syncthreads();                   // match table init visibility
  }

  // ---- phase 2: corrected u,v + d slabs in LDS (from staged registers)
  // (Dss writes land in AbS rows 8..13 -- phases 1/5 use rows 0..6 only.)
  #pragma unroll
  for (int m = 0; m < 4; ++m) {        // U: 13 rows
    int e = tid + (m << 10);
    if (e < 13*NN) {
      int k = e >> 8, jj = e & 255;
      Ucs[e] = first ? u_reg[m]
                     : (u_reg[m] - (qs[(k+1)*NN + jj] - qs[k*NN + jj])*RDX);
    }
  }
  #pragma unroll
  for (int m = 0; m < 3; ++m) {        // V, D: 12 rows
    int e = tid + (m << 10);
    int k = e >> 8, jj = e & 255;
    Vcs[e] = first ? v_reg[m]
                   : (v_reg[m] - (qs[(k+1)*NN + ((jj+1)&NM)] - qs[(k+1)*NN + jj])*RDX);
    Dss[e] = d_reg[m];
  }
  __syncthreads();                     // qs dead from here; Vs may reuse it

  // ---- phase 3: fused trajectory write-out of corrected state t-1
  if (tm1 >= 0) {
    #pragma unroll
    for (int m = 0; m < 2; ++m) {
      int e = tid + (m << 10);         // 8 owned rows x 256 = 2048
      int k = e >> 8, jj = e & 255;
      int pos = (row0 + k)*NN + jj;
      size_t o = ((size_t)(b*T + tm1)*FIELD + pos)*3u;
      out[o]   = Ucs[(k+3)*NN + jj];
      out[o+1] = Vcs[(k+2)*NN + jj];
      out[o+2] = Dss[(k+2)*NN + jj];
    }
  }

  // ---- phase 4: advect from LDS. Quarter qtr: u-only row 2q-1 (backward
  // halo for div), full rows 2q, 2q+1.
  const int kbeg = (qtr << 1) - 1;     // -1, 1, 3, 5
  float u1r[3];
  #pragma unroll
  for (int kk = 0; kk < 3; ++kk) {
    int k = kbeg + kk;                 // global row = row0 + k
    int ku = k + 3, kv = k + 2;
    float u1, v1, d1;
    if (kk == 0) {
      advect_point_lds<0>(Ucs, Vcs, Dss, ku, kv, j, hdtdx, dt, u1, v1, d1);
    } else {
      advect_point_lds<1>(Ucs, Vcs, Dss, ku, kv, j, hdtdx, dt, u1, v1, d1);
      int gi = (row0 + k)*NN + j;
      Uo[gi] = u1; Vo[gi] = v1; Do_[gi] = d1;
      Vs[k*NN + j] = v1;               // k in [0,7], owned
    }
    u1r[kk] = u1;
  }
  __syncthreads();                     // Vs visible across waves

  // ---- phase 5: div -> PACKED bit-rev scatter (pair p = qtr) -> fwd FFT
  {
    int jm1 = (j - 1) & NM, rj = rev8(j);
    float dv0 = (u1r[1] - u1r[0]
               + Vs[(2*qtr)*NN + j] - Vs[(2*qtr)*NN + jm1]) * RDX;
    float dv1 = (u1r[2] - u1r[1]
               + Vs[(2*qtr+1)*NN + j] - Vs[(2*qtr+1)*NN + jm1]) * RDX;
    AbS[qtr*ROWF2 + pdx(rj)] = make_float2(dv0, dv1);   // z = d_a + i*d_b
  }
  __syncthreads();                     // cross-wave: scatter -> FFT groups

  {
    const int g16 = tid >> 4;          // 4 active groups (threads 0..63)
    const int r   = tid & 15;
    if (g16 < 4) {                     // round 1: fwd stages 1-4 (16-blocks)
      float2* Ar = AbS + g16*ROWF2;
      float2 x[16];
      #pragma unroll
      for (int t = 0; t < 16; ++t) x[t] = Ar[pdx((r<<4) + t)];
      r16_fwd_low(x, tw);
      #pragma unroll
      for (int t = 0; t < 16; ++t) Ar[pdx((r<<4) + t)] = x[t];
    }
    wave_sync();
    if (g16 < 4) {                     // round 2: fwd stages 5-8 (stride-16)
      float2* Ar = AbS + g16*ROWF2;
      float2 x[16];
      #pragma unroll
      for (int k = 0; k < 16; ++k) x[k] = Ar[pdx(r + (k<<4))];
      r16_fwd_high(x, r, tw);
      #pragma unroll
      for (int k = 0; k < 16; ++k) Ar[pdx(r + (k<<4))] = x[k];
    }
  }
  __syncthreads();                     // cross-wave: FFT rows -> unpack+store

  // Hermitian unpack: S[2p][k] = (z[k]+conj(z[-k]))/2,
  //                   S[2p+1][k] = (z[k]-conj(z[-k]))/(2i)
  float2* So = Snew + b*FIELD;
  #pragma unroll
  for (int m = 0; m < 2; ++m) {
    int e = tid + (m << 10);           // 8 real rows x 256 = 2048
    int row = e >> 8, jj = e & 255;
    int p = row >> 1;
    float2 z  = AbS[p*ROWF2 + pdx(jj)];
    float2 z2 = AbS[p*ROWF2 + pdx((256 - jj) & 255)];
    float2 sv;
    if ((row & 1) == 0)
      sv = make_float2(0.5f*(z.x + z2.x), 0.5f*(z.y - z2.y));
    else
      sv = make_float2(0.5f*(z.y + z2.y), 0.5f*(z2.x - z.x));
    So[(row0 + row)*NN + jj] = sv;
  }
}

// ================================================================ B (Hermitian-half)
// dim3(17, BATCH) x 512 threads. Processes columns 0..135 (only 0..128
// stored); mirror-writes conj into columns 129..255. 8 teams x 64 lanes,
// R17-f2 fused rounds. C_{256-j}[i] = conj(C_j[i]) (S Hermitian in j,
// lambda symmetric).
__global__ __launch_bounds__(512) void fft_cols_h(float2* __restrict__ S)
{
  __shared__ float2 Ab[8*ROWF2];
  __shared__ float2 tw[128];
  __shared__ float  lam[NN];
  int tid = threadIdx.x;
  int b = blockIdx.y;
  int col0 = blockIdx.x << 3;          // 0, 8, ..., 128

  if (tid < 128) {
    float sw, cw;
    __sincosf(-0.02454369260617026f * (float)tid, &sw, &cw);
    tw[tid] = make_float2(cw, sw);
  }
  if (tid < 256) {
    float s1 = __sinf(0.01227184630308512983f * (float)tid);   // pi/256 * k
    lam[tid] = -4.0f * s1 * s1 * (RDX*RDX);
  }

  float2* Sb = S + b*FIELD;
  #pragma unroll
  for (int k = 0; k < 4; ++k) {        // load transposed, bit-reversed
    int idx = tid + (k << 9);
    int i = idx >> 3, c = idx & 7;
    Ab[c*ROWF2 + pdx(rev8(i))] = Sb[i*NN + col0 + c];
  }
  __syncthreads();                     // cross-wave: scatter -> per-wave FFT

  int g = tid >> 6, lane = tid & 63;   // wave g owns column col0+g
  fft256_fwd_f2(Ab + g*ROWF2, lane, tw, true);

  // spectral scale: wave g touches only its own row -> wave order suffices
  float l2 = lam[(col0 + g) & 255];
  #pragma unroll
  for (int r = 0; r < 4; ++r) {
    int k1 = lane + (r << 6);
    float den = lam[k1] + l2;
    float sc = ((k1 | (col0 + g)) == 0) ? 0.0f : (1.0f/den);
    sc *= (1.0f/65536.0f);             // fold in ifft2's 1/N^2
    float2 v = Ab[g*ROWF2 + pdx(k1)];
    Ab[g*ROWF2 + pdx(k1)] = make_float2(v.x*sc, v.y*sc);
  }
  wave_sync();

  fft256_inv_f2(Ab + g*ROWF2, lane, tw, true);
  __syncthreads();                     // cross-wave: FFT rows -> store

  #pragma unroll
  for (int k = 0; k < 4; ++k) {        // store + Hermitian mirror
    int idx = tid + (k << 9);
    int i = idx >> 3, c = idx & 7;
    int j = col0 + c;
    float2 v = Ab[c*ROWF2 + pdx(rev8(i))];
    if (j <= 128) Sb[i*NN + j] = v;
    if (j >= 1 && j <= 127)
      Sb[i*NN + (256 - j)] = make_float2(v.x, -v.y);
  }
}

// ================================================================ K1 (R9 fallback)
__global__ __launch_bounds__(512) void advect_div_fft(
    const float* __restrict__ inb, float* __restrict__ outb,
    float2* __restrict__ S, float* __restrict__ out,
    const unsigned* __restrict__ dtw, int T, int tm1)
{
  __shared__ float  Vs[8][NN];
  __shared__ float2 AbS[8*ROWF2];
  __shared__ float2 tw[128];
  const int tid = threadIdx.x;
  const int j   = tid & 255;
  const int h   = tid >> 8;           // 0 or 1
  const int b    = blockIdx.x >> 5;
  const int row0 = (blockIdx.x & 31) << 3;

  if (tid < 128) {
    float sw, cw;
    __sincosf(-0.02454369260617026f * (float)tid, &sw, &cw);  // -2pi/256
    tw[tid] = make_float2(cw, sw);
  }

  const float* Ub = inb + b*FIELD;
  const float* Vb = inb + TOTAL + b*FIELD;
  const float* Db = inb + 2*TOTAL + b*FIELD;
  float* Uo  = outb + b*FIELD;
  float* Vo  = outb + TOTAL + b*FIELD;
  float* Do_ = outb + 2*TOTAL + b*FIELD;

  const float dt = decode_dt(dtw);
  const float hdtdx = 0.5f*dt*RDX;

  if (tm1 >= 0) {                      // fused write_out of previous state
    #pragma unroll
    for (int k = 0; k < 4; ++k) {
      int pos = (row0 + h*4 + k)*NN + j;
      size_t o = ((size_t)(b*T + tm1)*FIELD + pos)*3u;
      out[o]   = Ub[pos];
      out[o+1] = Vb[pos];
      out[o+2] = Db[pos];
    }
  }

  const int kbeg = h ? 3 : -1;
  float u1r[5];
  #pragma unroll
  for (int kk = 0; kk < 5; ++kk) {
    int k = kbeg + kk;
    int r = (row0 + k) & NM;
    float u1, v1, d1;
    if (kk == 0) {
      advect_point<0>(Ub, Vb, Db, r, j, hdtdx, dt, u1, v1, d1);
    } else {
      advect_point<1>(Ub, Vb, Db, r, j, hdtdx, dt, u1, v1, d1);
      int gi = r*NN + j;
      Uo[gi] = u1; Vo[gi] = v1; Do_[gi] = d1;
      Vs[k][j] = v1;
    }
    u1r[kk] = u1;
  }
  __syncthreads();

  {  // div (backward diff) -> bit-reversed scatter (padded)
    int jm1 = (j - 1) & NM, rj = rev8(j);
    #pragma unroll
    for (int m = 0; m < 4; ++m) {
      int k = h*4 + m;
      float dv = (u1r[m+1] - u1r[m] + Vs[k][j] - Vs[k][jm1]) * RDX;
      AbS[k*ROWF2 + pdx(rj)] = make_float2(dv, 0.0f);
    }
  }
  __syncthreads();

  // fwd row FFT: 8 teams x 64 lanes
  const int g = tid >> 6, lane = tid & 63;
  fft256_dit_fwd<64>(AbS + g*ROWF2, lane, tw, true);
  __syncthreads();

  float2* Sb = S + b*FIELD;
  #pragma unroll
  for (int k = 0; k < 4; ++k) {
    int row = h*4 + k;
    Sb[(row0 + row)*NN + j] = AbS[row*ROWF2 + pdx(j)];
  }
}

// ================================================================ K2 (R9 fallback)
__global__ __launch_bounds__(512) void fft_cols_r9(float2* __restrict__ S)
{
  __shared__ float2 Ab[8*ROWF2];
  __shared__ float2 tw[128];
  __shared__ float  lam[NN];
  int tid = threadIdx.x;
  int b = blockIdx.x >> 5;
  int col0 = (blockIdx.x & 31) << 3;

  if (tid < 128) {
    float sw, cw;
    __sincosf(-0.02454369260617026f * (float)tid, &sw, &cw);
    tw[tid] = make_float2(cw, sw);
  }
  if (tid < 256) {
    float s1 = __sinf(0.01227184630308512983f * (float)tid);   // pi/256 * k
    lam[tid] = -4.0f * s1 * s1 * (RDX*RDX);
  }

  float2* Sb = S + b*FIELD;
  #pragma unroll
  for (int k = 0; k < 4; ++k) {        // load transposed, bit-reversed
    int idx = tid + (k << 9);
    int i = idx >> 3, c = idx & 7;
    Ab[c*ROWF2 + pdx(rev8(i))] = Sb[i*NN + col0 + c];
  }
  __syncthreads();                     // cross-wave: scatter -> per-wave FFT

  int g = tid >> 6, lane = tid & 63;   // wave g owns column-row g
  fft256_dit_fwd<64>(Ab + g*ROWF2, lane, tw, true);

  float l2 = lam[col0 + g];
  #pragma unroll
  for (int r = 0; r < 4; ++r) {
    int k1 = lane + (r << 6);
    float den = lam[k1] + l2;
    float sc = ((k1 | (col0 + g)) == 0) ? 0.0f : (1.0f/den);
    sc *= (1.0f/65536.0f);             // fold in ifft2's 1/N^2
    float2 v = Ab[g*ROWF2 + pdx(k1)];
    Ab[g*ROWF2 + pdx(k1)] = make_float2(v.x*sc, v.y*sc);
  }
  wave_sync();

  fft256_dif_inv<64>(Ab + g*ROWF2, lane, tw, true);
  __syncthreads();                     // cross-wave: FFT rows -> store

  #pragma unroll
  for (int k = 0; k < 4; ++k) {        // store transposed, un-reversed
    int idx = tid + (k << 9);
    int i = idx >> 3, c = idx & 7;
    Sb[i*NN + col0 + c] = Ab[c*ROWF2 + pdx(rev8(i))];
  }
}

// ================================================================ K3 (final correction)
__global__ __launch_bounds__(512) void fft_inv_correct(
    const float2* __restrict__ S, float* __restrict__ outb)
{
  __shared__ float2 Ab[9*ROWF2];
  __shared__ float  qs[9*NN];
  __shared__ float2 tw[128];
  int tid = threadIdx.x;
  int b = blockIdx.x >> 5;
  int row0 = (blockIdx.x & 31) << 3;

  if (tid < 128) {
    float sw, cw;
    __sincosf(-0.02454369260617026f * (float)tid, &sw, &cw);
    tw[tid] = make_float2(cw, sw);
  }

  const float2* Sb = S + b*FIELD;
  #pragma unroll
  for (int m = 0; m < 5; ++m) {        // load 9 rows, natural order (DIF in)
    int e = tid + m*512;
    if (e < 9*NN) {
      int k = e >> 8, j = e & 255;
      Ab[k*ROWF2 + pdx(j)] = Sb[((row0 + k) & NM)*NN + j];
    }
  }
  __syncthreads();

  int g = tid >> 5, lane = tid & 31;   // 16 teams of 32; 9 active
  bool active = (g < 9);
  fft256_dif_inv<32>(Ab + (active ? g : 8)*ROWF2, lane, tw, active);
  __syncthreads();

  #pragma unroll
  for (int m = 0; m < 5; ++m) {        // un-reverse gather -> qs natural
    int e = tid + m*512;
    if (e < 9*NN) {
      int k = e >> 8, j = e & 255;
      qs[k*NN + j] = Ab[k*ROWF2 + pdx(rev8(j))].x;
    }
  }
  __syncthreads();

  float* Ug = outb + b*FIELD;
  float* Vg = outb + TOTAL + b*FIELD;
  #pragma unroll
  for (int m = 0; m < 4; ++m) {
    int e = tid + m*512;               // 0..2047
    int k = e >> 8, j = e & 255;
    int gi = (row0 + k)*NN + j;
    float q0 = qs[k*NN + j];
    float q1 = qs[(k+1)*NN + j];
    float qj = qs[k*NN + ((j+1) & NM)];
    Ug[gi] -= (q1 - q0)*RDX;
    Vg[gi] -= (qj - q0)*RDX;
  }
}

// ================================================================ misc
__global__ __launch_bounds__(256) void write_out_k(
    const float* __restrict__ U, const float* __restrict__ V, const float* __restrict__ D,
    float* __restrict__ out, int t, int T)
{
  int idx = blockIdx.x*256 + threadIdx.x;
  int b = idx >> 16;
  int pos = idx & (FIELD-1);
  size_t o = ((size_t)(b*T + t)*FIELD + pos)*3u;
  out[o]   = U[idx];
  out[o+1] = V[idx];
  out[o+2] = D[idx];
}

__global__ __launch_bounds__(256) void init_state(
    const float* __restrict__ y0,
    float* __restrict__ U, float* __restrict__ V, float* __restrict__ D)
{
  int idx = blockIdx.x*256 + threadIdx.x;
  U[idx] = y0[idx*3];
  V[idx] = y0[idx*3+1];
  D[idx] = y0[idx*3+2];
}

// ================================================================ fallback
// R5-proven sincos/unpadded kernels (used only if ws too small).
__device__ __forceinline__ void fft_fwd_sc(float2* A, int lane) {
  #pragma unroll
  for (int s = 1; s <= 8; ++s) {
    int half = 1 << (s-1);
    float angscale = -6.28318530717958647692f / (float)(2*half);
    #pragma unroll
    for (int r = 0; r < 4; ++r) {
      int bfly = lane + (r << 5);
      int q = bfly & (half - 1);
      int g = (bfly >> (s-1)) << s;
      float sw, cw; __sincosf(angscale * (float)q, &sw, &cw);
      float2 a = A[g+q], b = A[g+q+half];
      float wbx = cw*b.x - sw*b.y, wby = cw*b.y + sw*b.x;
      A[g+q] = make_float2(a.x+wbx, a.y+wby);
      A[g+q+half] = make_float2(a.x-wbx, a.y-wby);
    }
    __syncthreads();
  }
}
__device__ __forceinline__ void fft_inv_sc(float2* A, int lane) {
  #pragma unroll
  for (int s = 8; s >= 1; --s) {
    int half = 1 << (s-1);
    float angscale = 6.28318530717958647692f / (float)(2*half);
    #pragma unroll
    for (int r = 0; r < 4; ++r) {
      int bfly = lane + (r << 5);
      int q = bfly & (half - 1);
      int g = (bfly >> (s-1)) << s;
      float sw, cw; __sincosf(angscale * (float)q, &sw, &cw);
      float2 a = A[g+q], b = A[g+q+half];
      float dx = a.x-b.x, dy = a.y-b.y;
      A[g+q] = make_float2(a.x+b.x, a.y+b.y);
      A[g+q+half] = make_float2(cw*dx - sw*dy, cw*dy + sw*dx);
    }
    __syncthreads();
  }
}

__global__ __launch_bounds__(256) void advect_kernel_fb(
    const float* __restrict__ U, const float* __restrict__ V, const float* __restrict__ D,
    float* __restrict__ Uo, float* __restrict__ Vo, float* __restrict__ Do_,
    const unsigned* __restrict__ dtw)
{
  int idx = blockIdx.x*256 + threadIdx.x;
  int j = idx & NM, i = (idx >> 8) & NM, base = (idx >> 16) * FIELD;
  float dt = decode_dt(dtw);
  float u1, v1, d1;
  advect_point<1>(U + base, V + base, D + base, i, j, 0.5f*dt*RDX, dt, u1, v1, d1);
  Uo[idx] = u1; Vo[idx] = v1; Do_[idx] = d1;
}

__global__ __launch_bounds__(256) void fft_rows_div_fb(
    const float* __restrict__ U2, const float* __restrict__ V2, float2* __restrict__ S)
{
  __shared__ float2 Ab[8*NN];
  int tid = threadIdx.x, b = blockIdx.x >> 5, row0 = (blockIdx.x & 31) << 3;
  const float* Ub = U2 + b*FIELD;
  const float* Vb = V2 + b*FIELD;
  int jm1 = (tid - 1) & NM, rj = rev8(tid);
  #pragma unroll
  for (int k = 0; k < 8; ++k) {
    int row = row0 + k, rm1 = (row - 1) & NM;
    float dv = (Ub[row*NN + tid] - Ub[rm1*NN + tid]
              + Vb[row*NN + tid] - Vb[row*NN + jm1]) * RDX;
    Ab[(k<<8) + rj] = make_float2(dv, 0.0f);
  }
  __syncthreads();
  int g = tid >> 5, lane = tid & 31;
  fft_fwd_sc(Ab + (g<<8), lane);
  float2* Sb = S + b*FIELD;
  #pragma unroll
  for (int k = 0; k < 8; ++k)
    Sb[(row0 + k)*NN + tid] = Ab[(k<<8) + tid];
}

__global__ __launch_bounds__(256) void fft_cols_fb(float2* __restrict__ S)
{
  __shared__ float2 Ab[8*NN];
  int tid = threadIdx.x, b = blockIdx.x >> 5, col0 = (blockIdx.x & 31) << 3;
  float2* Sb = S + b*FIELD;
  #pragma unroll
  for (int k = 0; k < 8; ++k) {
    int idx = tid + (k << 8);
    int i = idx >> 3, c = idx & 7;
    Ab[(c<<8) + rev8(i)] = Sb[i*NN + col0 + c];
  }
  __syncthreads();
  int g = tid >> 5, lane = tid & 31;
  fft_fwd_sc(Ab + (g<<8), lane);
  int k2 = col0 + g;
  float s2 = __sinf(0.01227184630308512983f * (float)k2);
  float l2 = -4.0f * s2 * s2 * (RDX*RDX);
  #pragma unroll
  for (int r = 0; r < 8; ++r) {
    int k1 = lane + (r << 5);
    float s1 = __sinf(0.01227184630308512983f * (float)k1);
    float l1 = -4.0f * s1 * s1 * (RDX*RDX);
    float den = l1 + l2;
    float sc = ((k1 | k2) == 0) ? 0.0f : (1.0f/den);
    sc *= (1.0f/65536.0f);
    float2 v = Ab[(g<<8) + k1];
    Ab[(g<<8) + k1] = make_float2(v.x*sc, v.y*sc);
  }
  __syncthreads();
  fft_inv_sc(Ab + (g<<8), lane);
  #pragma unroll
  for (int k = 0; k < 8; ++k) {
    int idx = tid + (k << 8);
    int i = idx >> 3, c = idx & 7;
    Sb[i*NN + col0 + c] = Ab[(c<<8) + rev8(i)];
  }
}

__global__ __launch_bounds__(256) void fft_rows_inv_fb(
    const float2* __restrict__ S, float* __restrict__ Q)
{
  __shared__ float2 Ab[8*NN];
  int tid = threadIdx.x, b = blockIdx.x >> 5, row0 = (blockIdx.x & 31) << 3;
  const float2* Sb = S + b*FIELD;
  #pragma unroll
  for (int k = 0; k < 8; ++k)
    Ab[(k<<8) + tid] = Sb[(row0 + k)*NN + tid];
  __syncthreads();
  int g = tid >> 5, lane = tid & 31;
  fft_inv_sc(Ab + (g<<8), lane);
  float* Qb = Q + b*FIELD;
  int rj = rev8(tid);
  #pragma unroll
  for (int k = 0; k < 8; ++k)
    Qb[(row0 + k)*NN + tid] = Ab[(k<<8) + rj].x;
}

__global__ __launch_bounds__(256) void correct_uv_fb(
    float* __restrict__ U2, float* __restrict__ V2, const float* __restrict__ Q)
{
  int idx = blockIdx.x*256 + threadIdx.x;
  int j = idx & NM, i = (idx >> 8) & NM, base = (idx >> 16) * FIELD;
  const float* Qb = Q + base;
  float q0 = Qb[i*NN + j];
  float qi = Qb[((i+1)&NM)*NN + j];
  float qj = Qb[i*NN + ((j+1)&NM)];
  U2[idx] -= (qi - q0)*RDX;
  V2[idx] -= (qj - q0)*RDX;
}

// ---------------------------------------------------------------- launch
extern "C" void kernel_launch(void* const* d_in, const int* in_sizes, int n_in,
                              void* d_out, int out_size, void* d_ws, size_t ws_size,
                              hipStream_t stream) {
  (void)in_sizes; (void)n_in;
  const float*    y0  = (const float*)d_in[0];
  const unsigned* dtw = (const unsigned*)d_in[1];
  float* out = (float*)d_out;

  int T = out_size / (3*FIELD*BATCH);
  if (T < 1) T = 1;

  float* wsf = (float*)d_ws;

  // ---- preferred: fused 2-kernel/step path (needs 10*TOTAL floats) ----
  if (ws_size >= (size_t)10*TOTAL*sizeof(float)) {
    float* stA = wsf;                  // 3*TOTAL
    float* stB = wsf + 3*TOTAL;        // 3*TOTAL
    float2* Sa = (float2*)(wsf + 6*TOTAL);   // TOTAL float2
    float2* Sc = (float2*)(wsf + 8*TOTAL);   // TOTAL float2

    init_state<<<TOTAL/256, 256, 0, stream>>>(y0, stA, stA+TOTAL, stA+2*TOTAL);
    float* inb  = stA;
    float* outb = stB;
    float2* Sr = Sa;                   // spectral q from previous step
    float2* Sw = Sc;                   // new div spectral
    int step = 0;
    for (int t = 0; t < T; ++t) {
      for (int s = 0; s < 10; ++s) {
        int tm1 = (s == 0) ? (t - 1) : -1;
        proj_advect_fft8<<<256, 1024, 0, stream>>>(Sr, inb, outb, Sw, out,
                                                   dtw, T, tm1, step == 0);
        fft_cols_h<<<dim3(17, BATCH), 512, 0, stream>>>(Sw);
        float*  t1 = inb; inb = outb; outb = t1;
        float2* t2 = Sr;  Sr  = Sw;   Sw  = t2;
        ++step;
      }
    }
    // final state in inb is uncorrected; Sr holds its Poisson solution
    fft_inv_correct<<<256, 512, 0, stream>>>(Sr, inb);
    write_out_k<<<TOTAL/256, 256, 0, stream>>>(inb, inb+TOTAL, inb+2*TOTAL,
                                               out, T-1, T);
    return;
  }

  // ---- R9 3-kernel path (needs 8*TOTAL floats) ----
  if (ws_size >= (size_t)8*TOTAL*sizeof(float)) {
    float2* S = (float2*)(wsf + 6*TOTAL);
    init_state<<<TOTAL/256, 256, 0, stream>>>(y0, wsf, wsf+TOTAL, wsf+2*TOTAL);
    float* inb = wsf;
    float* outb = wsf + 3*TOTAL;
    for (int t = 0; t < T; ++t) {
      for (int s = 0; s < 10; ++s) {
        int tm1 = (s == 0) ? (t - 1) : -1;
        advect_div_fft <<<256, 512, 0, stream>>>(inb, outb, S, out, dtw, T, tm1);
        fft_cols_r9    <<<256, 512, 0, stream>>>(S);
        fft_inv_correct<<<256, 512, 0, stream>>>(S, outb);
        float* tmp = inb; inb = outb; outb = tmp;
      }
    }
    write_out_k<<<TOTAL/256, 256, 0, stream>>>(inb, inb+TOTAL, inb+2*TOTAL,
                                               out, T-1, T);
    return;
  }

  // ---- R5 5-kernel path with aliased S/Q (12.6 MB) ----
  float* bank0 = wsf;
  float* bank1 = wsf + 3*TOTAL;
  init_state<<<TOTAL/256, 256, 0, stream>>>(y0, bank0, bank0+TOTAL, bank0+2*TOTAL);
  float* inb = bank0;
  float* outb = bank1;
  for (int t = 0; t < T; ++t) {
    for (int s = 0; s < 10; ++s) {
      float *Ui = inb,  *Vi = inb + TOTAL,  *Di = inb + 2*TOTAL;
      float *Uo = outb, *Vo = outb + TOTAL, *Do_ = outb + 2*TOTAL;
      float2* S = (float2*)(inb + TOTAL);
      float*  Q = inb;
      advect_kernel_fb<<<TOTAL/256, 256, 0, stream>>>(Ui, Vi, Di, Uo, Vo, Do_, dtw);
      fft_rows_div_fb <<<BATCH*32, 256, 0, stream>>>(Uo, Vo, S);
      fft_cols_fb     <<<BATCH*32, 256, 0, stream>>>(S);
      fft_rows_inv_fb <<<BATCH*32, 256, 0, stream>>>(S, Q);
      correct_uv_fb   <<<TOTAL/256, 256, 0, stream>>>(Uo, Vo, Q);
      float* tmp = inb; inb = outb; outb = tmp;
    }
    write_out_k<<<TOTAL/256, 256, 0, stream>>>(inb, inb+TOTAL, inb+2*TOTAL, out, t, T);
  }
}

// Round 14
// 1846.216 us; speedup vs baseline: 1.1255x; 1.0591x over previous
//
#include <hip/hip_runtime.h>
#include <hip/hip_bf16.h>

// NS solver: 256x256 periodic, B=8, NC=3 (u,v,density), T outer x 10 inner steps.
// y0 = fp32, dt = fp32, out = fp32 (established R1-R5). Internal state fp32.
//
// R23: full Hermitian-half S pipeline. R22 (half-B) verified -2%. Drop the
// redundant spectrum half EVERYWHERE:
//  - A phase-5 stores only S cols 0..128 (write -50%); cols 129..135 read by
//    B's last block feed only discarded outputs (col FFTs independent).
//  - B stores only cols 0..128 (mirror write removed).
//  - A phase-1 reconstructs j>128 via conj(S[256-j]) on load (exact identity,
//    bit-identical to the old mirror values); HBM reads halve.
//  - fft_inv_correct reconstructs the same way (valid for both paths).
// Everything else unchanged from R22 (packed real FFTs, radix-16 rounds,
// wave-sync, R17-f2 B core).

#define NN 256
#define NM 255
#define FIELD (NN*NN)
#define BATCH 8
#define TOTAL (BATCH*FIELD)
#define ROWF2 264   // padded LDS row stride in float2 (256 + 8)

constexpr float RDX  = 40.743665431525205f;   // N/(2*pi) = 1/DX
constexpr float VISC = 1e-3f;

__device__ __forceinline__ int rev8(int x) { return (int)(__brev((unsigned)x) >> 24); }
__device__ __forceinline__ int pdx(int x)  { return x + (x >> 5); }

// Intra-wave LDS exchange fence (R13-verified on gfx950): compiler fence +
// sched barrier. A wave's DS ops complete in program order -> no s_barrier
// needed when producer and consumer lanes share a wave.
__device__ __forceinline__ void wave_sync() {
  asm volatile("" ::: "memory");
  __builtin_amdgcn_wave_barrier();
}

__device__ __forceinline__ float decode_dt(const unsigned* dtw) {
  unsigned w = dtw[0];
  float cf = __uint_as_float(w);
  float cb = __uint_as_float((w & 0xFFFFu) << 16);
  bool v32 = (cf > 1e-8f) && (cf < 1.0f);          // NaN-safe
  bool vbf = (cb > 1e-8f) && (cb < 1.0f);
  return v32 ? cf : (vbf ? cb : 1e-3f);
}

// ---------------------------------------------------------------- advection
__device__ __forceinline__ float face_flux(float uf, float cm, float c0,
                                           float cp, float cpp, float hdtdx) {
  float dc = cp - c0;
  float f_low  = (uf >= 0.0f) ? uf*c0 : uf*cp;
  float f_high = uf*0.5f*(c0+cp) - hdtdx*uf*uf*dc;
  float dc_up  = (uf >= 0.0f) ? (c0 - cm) : (cpp - cp);
  float dc_safe = (fabsf(dc) > 1e-12f) ? dc : 1e-12f;
  // van Leer: (a*b>0) ? 2a/(a+b) : 0
  float phi = (dc_up * dc_safe > 0.0f) ? (2.0f*dc_up/(dc_up + dc_safe)) : 0.0f;
  return f_low + phi*(f_high - f_low);
}

// global-memory stencil variant (fallback paths)
template<int NEED_VD>
__device__ __forceinline__ void advect_point(
    const float* __restrict__ Ub, const float* __restrict__ Vb,
    const float* __restrict__ Db,
    int i, int j, float hdtdx, float dt,
    float& u1, float& v1, float& d1)
{
  int im2 = ((i-2)&NM)*NN, im1 = ((i-1)&NM)*NN, i0r = i*NN,
      ip1 = ((i+1)&NM)*NN, ip2 = ((i+2)&NM)*NN;
  int jm2 = (j-2)&NM, jm1 = (j-1)&NM, jp1 = (j+1)&NM, jp2 = (j+2)&NM;

  float u_c  = Ub[i0r+j];
  float u_im2= Ub[im2+j], u_im1 = Ub[im1+j], u_ip1 = Ub[ip1+j], u_ip2 = Ub[ip2+j];
  float u_jm2= Ub[i0r+jm2], u_jm1 = Ub[i0r+jm1], u_jp1 = Ub[i0r+jp1], u_jp2 = Ub[i0r+jp2];
  float v_c  = Vb[i0r+j];
  float v_jm1= Vb[i0r+jm1], v_jp1 = Vb[i0r+jp1];

  float ufI0 = 0.5f*(u_c + u_ip1);
  float ufIm = 0.5f*(u_im1 + u_c);
  float vfJ0 = 0.5f*(v_c + v_jp1);
  float vfJm = 0.5f*(v_jm1 + v_c);

  float tu = -(( face_flux(ufI0, u_im1, u_c, u_ip1, u_ip2, hdtdx)
               - face_flux(ufIm, u_im2, u_im1, u_c, u_ip1, hdtdx))
             + ( face_flux(vfJ0, u_jm1, u_c, u_jp1, u_jp2, hdtdx)
               - face_flux(vfJm, u_jm2, u_jm1, u_c, u_jp1, hdtdx))) * RDX;
  float lapu = (u_im1 + u_ip1 + u_jm1 + u_jp1 - 4.0f*u_c) * (RDX*RDX);
  u1 = u_c + dt*(tu + VISC*lapu);

  if (NEED_VD) {
    float v_im2= Vb[im2+j], v_im1 = Vb[im1+j], v_ip1 = Vb[ip1+j], v_ip2 = Vb[ip2+j];
    float v_jm2= Vb[i0r+jm2], v_jp2 = Vb[i0r+jp2];
    float d_c  = Db[i0r+j];
    float d_im2= Db[im2+j], d_im1 = Db[im1+j], d_ip1 = Db[ip1+j], d_ip2 = Db[ip2+j];
    float d_jm2= Db[i0r+jm2], d_jm1 = Db[i0r+jm1], d_jp1 = Db[i0r+jp1], d_jp2 = Db[i0r+jp2];

    float tv = -(( face_flux(ufI0, v_im1, v_c, v_ip1, v_ip2, hdtdx)
                 - face_flux(ufIm, v_im2, v_im1, v_c, v_ip1, hdtdx))
               + ( face_flux(vfJ0, v_jm1, v_c, v_jp1, v_jp2, hdtdx)
                 - face_flux(vfJm, v_jm2, v_jm1, v_c, v_jp1, hdtdx))) * RDX;
    float lapv = (v_im1 + v_ip1 + v_jm1 + v_jp1 - 4.0f*v_c) * (RDX*RDX);
    v1 = v_c + dt*(tv + VISC*lapv);

    float td = -(( face_flux(ufI0, d_im1, d_c, d_ip1, d_ip2, hdtdx)
                 - face_flux(ufIm, d_im2, d_im1, d_c, d_ip1, hdtdx))
               + ( face_flux(vfJ0, d_jm1, d_c, d_jp1, d_jp2, hdtdx)
                 - face_flux(vfJm, d_jm2, d_jm1, d_c, d_jp1, hdtdx))) * RDX;
    d1 = d_c + dt*td;
  }
}

// LDS-slab stencil variant (fused A kernel). ku = u-slab row of the point,
// kv = v/d-slab row of the point. Slabs are contiguous (no row wrap); j wraps.
template<int NEED_VD>
__device__ __forceinline__ void advect_point_lds(
    const float* __restrict__ U, const float* __restrict__ V,
    const float* __restrict__ D,
    int ku, int kv, int j, float hdtdx, float dt,
    float& u1, float& v1, float& d1)
{
  int jm2 = (j-2)&NM, jm1 = (j-1)&NM, jp1 = (j+1)&NM, jp2 = (j+2)&NM;

  const float* Ur = U + ku*NN;
  float u_c  = Ur[j];
  float u_im2= U[(ku-2)*NN+j], u_im1 = U[(ku-1)*NN+j],
        u_ip1= U[(ku+1)*NN+j], u_ip2 = U[(ku+2)*NN+j];
  float u_jm2= Ur[jm2], u_jm1 = Ur[jm1], u_jp1 = Ur[jp1], u_jp2 = Ur[jp2];
  const float* Vr = V + kv*NN;
  float v_c  = Vr[j];
  float v_jm1= Vr[jm1], v_jp1 = Vr[jp1];

  float ufI0 = 0.5f*(u_c + u_ip1);
  float ufIm = 0.5f*(u_im1 + u_c);
  float vfJ0 = 0.5f*(v_c + v_jp1);
  float vfJm = 0.5f*(v_jm1 + v_c);

  float tu = -(( face_flux(ufI0, u_im1, u_c, u_ip1, u_ip2, hdtdx)
               - face_flux(ufIm, u_im2, u_im1, u_c, u_ip1, hdtdx))
             + ( face_flux(vfJ0, u_jm1, u_c, u_jp1, u_jp2, hdtdx)
               - face_flux(vfJm, u_jm2, u_jm1, u_c, u_jp1, hdtdx))) * RDX;
  float lapu = (u_im1 + u_ip1 + u_jm1 + u_jp1 - 4.0f*u_c) * (RDX*RDX);
  u1 = u_c + dt*(tu + VISC*lapu);

  if (NEED_VD) {
    float v_im2= V[(kv-2)*NN+j], v_im1 = V[(kv-1)*NN+j],
          v_ip1= V[(kv+1)*NN+j], v_ip2 = V[(kv+2)*NN+j];
    float v_jm2= Vr[jm2], v_jp2 = Vr[jp2];
    const float* Dr = D + kv*NN;
    float d_c  = Dr[j];
    float d_im2= D[(kv-2)*NN+j], d_im1 = D[(kv-1)*NN+j],
          d_ip1= D[(kv+1)*NN+j], d_ip2 = D[(kv+2)*NN+j];
    float d_jm2= Dr[jm2], d_jm1 = Dr[jm1], d_jp1 = Dr[jp1], d_jp2 = Dr[jp2];

    float tv = -(( face_flux(ufI0, v_im1, v_c, v_ip1, v_ip2, hdtdx)
                 - face_flux(ufIm, v_im2, v_im1, v_c, v_ip1, hdtdx))
               + ( face_flux(vfJ0, v_jm1, v_c, v_jp1, v_jp2, hdtdx)
                 - face_flux(vfJm, v_jm2, v_jm1, v_c, v_jp1, hdtdx))) * RDX;
    float lapv = (v_im1 + v_ip1 + v_jm1 + v_jp1 - 4.0f*v_c) * (RDX*RDX);
    v1 = v_c + dt*(tv + VISC*lapv);

    float td = -(( face_flux(ufI0, d_im1, d_c, d_ip1, d_ip2, hdtdx)
                 - face_flux(ufIm, d_im2, d_im1, d_c, d_ip1, hdtdx))
               + ( face_flux(vfJ0, d_jm1, d_c, d_jp1, d_jp2, hdtdx)
                 - face_flux(vfJm, d_jm2, d_jm1, d_c, d_jp1, hdtdx))) * RDX;
    d1 = d_c + dt*td;
  }
}

// ---------------------------------------------------------------- FFT cores
// Table-driven, padded-LDS. tw[m] = exp(-2*pi*i*m/256), m<128. Stage-s
// twiddle = tw[q<<(8-s)] (fwd), conjugate for inverse. A = padded row base;
// element x lives at A[pdx(x)].
// WAVE-SYNCHRONOUS (R13): exchanges within a wave need only wave_sync().
//
// RADIX-16 ROUNDS (R19/R20-HW-verified): stages 1-4 confined to contiguous
// 16-blocks, stages 5-8 to stride-16 residue classes. One lane holds 16
// float2 in regs -> 4 stages per LDS round -> 2 rounds per direction.

// --- radix-16 in-register stage groups (lane-local x[16]) ---
__device__ __forceinline__ void r16_fwd_low(float2* x, const float2* tw) {
  #pragma unroll
  for (int s = 1; s <= 4; ++s) {
    int h = 1 << (s-1);
    #pragma unroll
    for (int b = 0; b < 8; ++b) {
      int q = b & (h-1);
      int t = ((b >> (s-1)) << s) + q;
      float2 w = tw[q << (8-s)];
      float2 a = x[t], c = x[t+h];
      float wbx = w.x*c.x - w.y*c.y, wby = w.x*c.y + w.y*c.x;
      x[t]   = make_float2(a.x+wbx, a.y+wby);
      x[t+h] = make_float2(a.x-wbx, a.y-wby);
    }
  }
}
__device__ __forceinline__ void r16_fwd_high(float2* x, int r, const float2* tw) {
  #pragma unroll
  for (int s = 5; s <= 8; ++s) {
    int hp = 1 << (s-5);
    #pragma unroll
    for (int b = 0; b < 8; ++b) {
      int qp = b & (hp-1);
      int t = ((b >> (s-5)) << (s-4)) + qp;
      float2 w = tw[(r + (qp<<4)) << (8-s)];
      float2 a = x[t], c = x[t+hp];
      float wbx = w.x*c.x - w.y*c.y, wby = w.x*c.y + w.y*c.x;
      x[t]    = make_float2(a.x+wbx, a.y+wby);
      x[t+hp] = make_float2(a.x-wbx, a.y-wby);
    }
  }
}
__device__ __forceinline__ void r16_inv_high(float2* x, int r, const float2* tw) {
  #pragma unroll
  for (int s = 8; s >= 5; --s) {
    int hp = 1 << (s-5);
    #pragma unroll
    for (int b = 0; b < 8; ++b) {
      int qp = b & (hp-1);
      int t = ((b >> (s-5)) << (s-4)) + qp;
      float2 w = tw[(r + (qp<<4)) << (8-s)];
      float2 a = x[t], c = x[t+hp];
      float dx = a.x-c.x, dy = a.y-c.y;
      x[t]    = make_float2(a.x+c.x, a.y+c.y);
      x[t+hp] = make_float2(w.x*dx + w.y*dy, w.x*dy - w.y*dx);
    }
  }
}
__device__ __forceinline__ void r16_inv_low(float2* x, const float2* tw) {
  #pragma unroll
  for (int s = 4; s >= 1; --s) {
    int h = 1 << (s-1);
    #pragma unroll
    for (int b = 0; b < 8; ++b) {
      int q = b & (h-1);
      int t = ((b >> (s-1)) << s) + q;
      float2 w = tw[q << (8-s)];
      float2 a = x[t], c = x[t+h];
      float dx = a.x-c.x, dy = a.y-c.y;
      x[t]   = make_float2(a.x+c.x, a.y+c.y);
      x[t+h] = make_float2(w.x*dx + w.y*dy, w.x*dy - w.y*dx);
    }
  }
}

// --- R17 fused 2-stage rounds (B kernel) ---
// fwd DIT, fused stage pairs (1,2),(3,4),(5,6),(7,8). lane in [0,64).
__device__ __forceinline__ void fft256_fwd_f2(float2* __restrict__ A, int lane,
                                              const float2* __restrict__ tw,
                                              bool active)
{
  #pragma unroll
  for (int s = 1; s <= 8; s += 2) {
    if (active) {
      int half = 1 << (s-1);
      int q2 = lane & (half - 1);
      int i0 = ((lane >> (s-1)) << (s+1)) + q2;
      float2 a0 = A[pdx(i0)];
      float2 a1 = A[pdx(i0 + half)];
      float2 a2 = A[pdx(i0 + 2*half)];
      float2 a3 = A[pdx(i0 + 3*half)];
      // stage s: pairs (a0,a1),(a2,a3), twiddle tw[q2<<(8-s)]
      float2 w1 = tw[q2 << (8 - s)];
      float wbx = w1.x*a1.x - w1.y*a1.y, wby = w1.x*a1.y + w1.y*a1.x;
      float2 b0 = make_float2(a0.x + wbx, a0.y + wby);
      float2 b1 = make_float2(a0.x - wbx, a0.y - wby);
      wbx = w1.x*a3.x - w1.y*a3.y; wby = w1.x*a3.y + w1.y*a3.x;
      float2 b2 = make_float2(a2.x + wbx, a2.y + wby);
      float2 b3 = make_float2(a2.x - wbx, a2.y - wby);
      // stage s+1: pairs (b0,b2) tw[q2<<(7-s)], (b1,b3) tw[(q2+half)<<(7-s)]
      float2 w2 = tw[q2 << (7 - s)];
      float2 w3 = tw[(q2 + half) << (7 - s)];
      wbx = w2.x*b2.x - w2.y*b2.y; wby = w2.x*b2.y + w2.y*b2.x;
      A[pdx(i0)]            = make_float2(b0.x + wbx, b0.y + wby);
      A[pdx(i0 + 2*half)]   = make_float2(b0.x - wbx, b0.y - wby);
      wbx = w3.x*b3.x - w3.y*b3.y; wby = w3.x*b3.y + w3.y*b3.x;
      A[pdx(i0 + half)]     = make_float2(b1.x + wbx, b1.y + wby);
      A[pdx(i0 + 3*half)]   = make_float2(b1.x - wbx, b1.y - wby);
    }
    wave_sync();
  }
}

// inv DIF, fused stage pairs (8,7),(6,5),(4,3),(2,1). lane in [0,64).
__device__ __forceinline__ void fft256_inv_f2(float2* __restrict__ A, int lane,
                                              const float2* __restrict__ tw,
                                              bool active)
{
  #pragma unroll
  for (int s = 8; s >= 2; s -= 2) {
    if (active) {
      int h = 1 << (s-2);              // half of stage s-1
      int q2 = lane & (h - 1);
      int i0 = ((lane >> (s-2)) << s) + q2;
      float2 a0 = A[pdx(i0)];
      float2 a1 = A[pdx(i0 + h)];
      float2 a2 = A[pdx(i0 + 2*h)];
      float2 a3 = A[pdx(i0 + 3*h)];
      // stage s (half=2h): pairs (a0,a2) q=q2, (a1,a3) q=q2+h
      float2 w1 = tw[q2 << (8 - s)];
      float2 w2 = tw[(q2 + h) << (8 - s)];
      float dx = a0.x - a2.x, dy = a0.y - a2.y;
      float2 b0 = make_float2(a0.x + a2.x, a0.y + a2.y);
      float2 b2 = make_float2(w1.x*dx + w1.y*dy, w1.x*dy - w1.y*dx);
      dx = a1.x - a3.x; dy = a1.y - a3.y;
      float2 b1 = make_float2(a1.x + a3.x, a1.y + a3.y);
      float2 b3 = make_float2(w2.x*dx + w2.y*dy, w2.x*dy - w2.y*dx);
      // stage s-1 (half=h): pairs (b0,b1) and (b2,b3), both q=q2
      float2 w3 = tw[q2 << (9 - s)];
      dx = b0.x - b1.x; dy = b0.y - b1.y;
      A[pdx(i0)]       = make_float2(b0.x + b1.x, b0.y + b1.y);
      A[pdx(i0 + h)]   = make_float2(w3.x*dx + w3.y*dy, w3.x*dy - w3.y*dx);
      dx = b2.x - b3.x; dy = b2.y - b3.y;
      A[pdx(i0 + 2*h)] = make_float2(b2.x + b3.x, b2.y + b3.y);
      A[pdx(i0 + 3*h)] = make_float2(w3.x*dx + w3.y*dy, w3.x*dy - w3.y*dx);
    }
    wave_sync();
  }
}

// Legacy single-stage variants (fallback paths + final correction kernel).
template<int W>
__device__ __forceinline__ void fft256_dit_fwd(float2* __restrict__ A, int lane,
                                               const float2* __restrict__ tw,
                                               bool active)
{
  #pragma unroll
  for (int s = 1; s <= 8; ++s) {
    int half = 1 << (s-1);
    if (active) {
      #pragma unroll
      for (int r = 0; r < 128/W; ++r) {
        int bfly = lane + r*W;
        int q = bfly & (half - 1);
        int g = (bfly >> (s-1)) << s;
        float2 w = tw[q << (8 - s)];
        float2 a = A[pdx(g + q)];
        float2 b = A[pdx(g + q + half)];
        float wbx = w.x*b.x - w.y*b.y;
        float wby = w.x*b.y + w.y*b.x;
        A[pdx(g + q)]        = make_float2(a.x + wbx, a.y + wby);
        A[pdx(g + q + half)] = make_float2(a.x - wbx, a.y - wby);
      }
    }
    wave_sync();
  }
}

template<int W>
__device__ __forceinline__ void fft256_dif_inv(float2* __restrict__ A, int lane,
                                               const float2* __restrict__ tw,
                                               bool active)
{
  #pragma unroll
  for (int s = 8; s >= 1; --s) {
    int half = 1 << (s-1);
    if (active) {
      #pragma unroll
      for (int r = 0; r < 128/W; ++r) {
        int bfly = lane + r*W;
        int q = bfly & (half - 1);
        int g = (bfly >> (s-1)) << s;
        float2 w = tw[q << (8 - s)];      // conj applied below (inverse)
        float2 a = A[pdx(g + q)];
        float2 b = A[pdx(g + q + half)];
        float dx = a.x - b.x, dy = a.y - b.y;
        A[pdx(g + q)]        = make_float2(a.x + b.x, a.y + b.y);
        A[pdx(g + q + half)] = make_float2(w.x*dx + w.y*dy, w.x*dy - w.y*dx);
      }
    }
    wave_sync();
  }
}

// ================================================================ A (fused, 8-row, 1024 thr)
// 256 blocks x 1024 threads. Per block: batch b = bid>>5, rows row0..row0+7.
//  0. issue U/V/D global->reg staging loads (consumed in phase 2)
//  1. PACKED inv row FFT: 7 packed pairs (S[2p]+i*S[2p+1]) of the 14 halo
//     rows of S_prev; j>128 reconstructed as conj(S[256-j]) (S stored
//     Hermitian-half). 7 groups x 16 lanes, radix-16, 2 LDS rounds.
//  2. q gather; corrected u (13 rows), v (12), d (12) slabs in LDS (from regs)
//  3. optional trajectory write-out of corrected state t-1 (owned 8 rows)
//  4. advect from LDS: quarter q -> u-only row 2q-1, full rows 2q, 2q+1
//  5. div -> PACKED fwd row FFT: 4 packed pairs, Hermitian unpack at store;
//     only cols 0..128 stored (B reads only those meaningfully).
// Slab rows: q row k <-> global row0-3+k (k in [0,13])
//            u row k <-> global row0-3+k (k in [0,12])
//            v,d row k <-> global row0-2+k (k in [0,11])
// LDS aliasing (R12): Vs -> qs (dead after phase 2); Dss -> AbS rows 8..13
// (phase-1 uses rows 0..6, phase-5 rows 0..3 -- disjoint). Total ~69 KB.
__global__ __launch_bounds__(1024) void proj_advect_fft8(
    const float2* __restrict__ Sprev, const float* __restrict__ inb,
    float* __restrict__ outb, float2* __restrict__ Snew,
    float* __restrict__ out, const unsigned* __restrict__ dtw,
    int T, int tm1, int first)
{
  __shared__ float2 tw[128];
  __shared__ float2 AbS[14*ROWF2];
  __shared__ float  qs [14*NN];
  __shared__ float  Ucs[13*NN];
  __shared__ float  Vcs[12*NN];
  float* Dss = (float*)(AbS + 8*ROWF2);  // 12*NN floats; phases 1/5 use rows 0..6
  float* Vs  = qs;                       // 8*NN floats; qs dead after phase 2

  const int tid  = threadIdx.x;
  const int j    = tid & 255;
  const int qtr  = tid >> 8;           // 0..3
  const int b    = blockIdx.x >> 5;
  const int row0 = (blockIdx.x & 31) << 3;

  if (tid < 128) {
    float sw, cw;
    __sincosf(-0.02454369260617026f * (float)tid, &sw, &cw);  // -2pi/256
    tw[tid] = make_float2(cw, sw);
  }

  const float dt = decode_dt(dtw);
  const float hdtdx = 0.5f*dt*RDX;

  const float* Ub = inb + b*FIELD;
  const float* Vb = inb + TOTAL + b*FIELD;
  const float* Db = inb + 2*TOTAL + b*FIELD;
  float* Uo  = outb + b*FIELD;
  float* Vo  = outb + TOTAL + b*FIELD;
  float* Do_ = outb + 2*TOTAL + b*FIELD;

  // ---- phase 0: early global->reg staging (T14). Latency hides under phase 1.
  float u_reg[4], v_reg[3], d_reg[3];
  #pragma unroll
  for (int m = 0; m < 4; ++m) {        // U: 13 rows = 3328 elems
    int e = tid + (m << 10);
    if (e < 13*NN) {
      int k = e >> 8, jj = e & 255;
      u_reg[m] = Ub[((row0 - 3 + k) & NM)*NN + jj];
    }
  }
  #pragma unroll
  for (int m = 0; m < 3; ++m) {        // V, D: 12 rows = 3072 = 3*1024
    int e = tid + (m << 10);
    int k = e >> 8, jj = e & 255;
    int gr = ((row0 - 2 + k) & NM)*NN;
    v_reg[m] = Vb[gr + jj];
    d_reg[m] = Db[gr + jj];
  }

  // ---- phase 1: PACKED inv row FFT of 14 rows -> qs (skip on step 0)
  // z_p[j] = S[row0-3+2p][j] + i*S[row0-3+2p+1][j]; IFFT(z) = q_a + i*q_b.
  // S stored Hermitian-half: j>128 read as conj(S[256-j]) (exact identity).
  if (!first) {
    const float2* Sb = Sprev + b*FIELD;
    #pragma unroll
    for (int m = 0; m < 2; ++m) {      // 7*256 = 1792 elems
      int e = tid + (m << 10);
      if (e < 7*NN) {
        int p = e >> 8, jj = e & 255;
        int jr = (jj <= 128) ? jj : (256 - jj);
        float sgn = (jj <= 128) ? 1.0f : -1.0f;
        float2 sa = Sb[((row0 - 3 + 2*p) & NM)*NN + jr];
        float2 sc = Sb[((row0 - 2 + 2*p) & NM)*NN + jr];
        sa.y *= sgn; sc.y *= sgn;
        AbS[p*ROWF2 + pdx(jj)] = make_float2(sa.x - sc.y, sa.y + sc.x);
      }
    }
    __syncthreads();                   // cross-wave: scatter -> FFT groups

    {
      const int g16 = tid >> 4;        // 7 active groups (threads 0..111)
      const int r   = tid & 15;
      if (g16 < 7) {                   // round 1: inv stages 8-5 (stride-16)
        float2* Ar = AbS + g16*ROWF2;
        float2 x[16];
        #pragma unroll
        for (int k = 0; k < 16; ++k) x[k] = Ar[pdx(r + (k<<4))];
        r16_inv_high(x, r, tw);
        #pragma unroll
        for (int k = 0; k < 16; ++k) Ar[pdx(r + (k<<4))] = x[k];
      }
      wave_sync();
      if (g16 < 7) {                   // round 2: inv stages 4-1 (16-blocks)
        float2* Ar = AbS + g16*ROWF2;
        float2 x[16];
        #pragma unroll
        for (int t = 0; t < 16; ++t) x[t] = Ar[pdx((r<<4) + t)];
        r16_inv_low(x, tw);
        #pragma unroll
        for (int t = 0; t < 16; ++t) Ar[pdx((r<<4) + t)] = x[t];
      }
    }
    __syncthreads();                   // cross-wave: FFT rows -> qs gather

    #pragma unroll
    for (int m = 0; m < 2; ++m) {      // un-reverse gather -> two q rows/pair
      int e = tid + (m << 10);
      if (e < 7*NN) {
        int p = e >> 8, jj = e & 255;
        float2 z = AbS[p*ROWF2 + pdx(rev8(jj))];
        qs[(2*p)*NN + jj]   = z.x;
        qs[(2*p+1)*NN + jj] = z.y;
      }
    }
    __syncthreads();
  } else {
    __syncthreads();                   // match table init visibility
  }

  // ---- phase 2: corrected u,v + d slabs in LDS (from staged registers)
  // (Dss writes land in AbS rows 8..13 -- phases 1/5 use rows 0..6 only.)
  #pragma unroll
  for (int m = 0; m < 4; ++m) {        // U: 13 rows
    int e = tid + (m << 10);
    if (e < 13*NN) {
      int k = e >> 8, jj = e & 255;
      Ucs[e] = first ? u_reg[m]
                     : (u_reg[m] - (qs[(k+1)*NN + jj] - qs[k*NN + jj])*RDX);
    }
  }
  #pragma unroll
  for (int m = 0; m < 3; ++m) {        // V, D: 12 rows
    int e = tid + (m << 10);
    int k = e >> 8, jj = e & 255;
    Vcs[e] = first ? v_reg[m]
                   : (v_reg[m] - (qs[(k+1)*NN + ((jj+1)&NM)] - qs[(k+1)*NN + jj])*RDX);
    Dss[e] = d_reg[m];
  }
  __syncthreads();                     // qs dead from here; Vs may reuse it

  // ---- phase 3: fused trajectory write-out of corrected state t-1
  if (tm1 >= 0) {
    #pragma unroll
    for (int m = 0; m < 2; ++m) {
      int e = tid + (m << 10);         // 8 owned rows x 256 = 2048
      int k = e >> 8, jj = e & 255;
      int pos = (row0 + k)*NN + jj;
      size_t o = ((size_t)(b*T + tm1)*FIELD + pos)*3u;
      out[o]   = Ucs[(k+3)*NN + jj];
      out[o+1] = Vcs[(k+2)*NN + jj];
      out[o+2] = Dss[(k+2)*NN + jj];
    }
  }

  // ---- phase 4: advect from LDS. Quarter qtr: u-only row 2q-1 (backward
  // halo for div), full rows 2q, 2q+1.
  const int kbeg = (qtr << 1) - 1;     // -1, 1, 3, 5
  float u1r[3];
  #pragma unroll
  for (int kk = 0; kk < 3; ++kk) {
    int k = kbeg + kk;                 // global row = row0 + k
    int ku = k + 3, kv = k + 2;
    float u1, v1, d1;
    if (kk == 0) {
      advect_point_lds<0>(Ucs, Vcs, Dss, ku, kv, j, hdtdx, dt, u1, v1, d1);
    } else {
      advect_point_lds<1>(Ucs, Vcs, Dss, ku, kv, j, hdtdx, dt, u1, v1, d1);
      int gi = (row0 + k)*NN + j;
      Uo[gi] = u1; Vo[gi] = v1; Do_[gi] = d1;
      Vs[k*NN + j] = v1;               // k in [0,7], owned
    }
    u1r[kk] = u1;
  }
  __syncthreads();                     // Vs visible across waves

  // ---- phase 5: div -> PACKED bit-rev scatter (pair p = qtr) -> fwd FFT
  {
    int jm1 = (j - 1) & NM, rj = rev8(j);
    float dv0 = (u1r[1] - u1r[0]
               + Vs[(2*qtr)*NN + j] - Vs[(2*qtr)*NN + jm1]) * RDX;
    float dv1 = (u1r[2] - u1r[1]
               + Vs[(2*qtr+1)*NN + j] - Vs[(2*qtr+1)*NN + jm1]) * RDX;
    AbS[qtr*ROWF2 + pdx(rj)] = make_float2(dv0, dv1);   // z = d_a + i*d_b
  }
  __syncthreads();                     // cross-wave: scatter -> FFT groups

  {
    const int g16 = tid >> 4;          // 4 active groups (threads 0..63)
    const int r   = tid & 15;
    if (g16 < 4) {                     // round 1: fwd stages 1-4 (16-blocks)
      float2* Ar = AbS + g16*ROWF2;
      float2 x[16];
      #pragma unroll
      for (int t = 0; t < 16; ++t) x[t] = Ar[pdx((r<<4) + t)];
      r16_fwd_low(x, tw);
      #pragma unroll
      for (int t = 0; t < 16; ++t) Ar[pdx((r<<4) + t)] = x[t];
    }
    wave_sync();
    if (g16 < 4) {                     // round 2: fwd stages 5-8 (stride-16)
      float2* Ar = AbS + g16*ROWF2;
      float2 x[16];
      #pragma unroll
      for (int k = 0; k < 16; ++k) x[k] = Ar[pdx(r + (k<<4))];
      r16_fwd_high(x, r, tw);
      #pragma unroll
      for (int k = 0; k < 16; ++k) Ar[pdx(r + (k<<4))] = x[k];
    }
  }
  __syncthreads();                     // cross-wave: FFT rows -> unpack+store

  // Hermitian unpack: S[2p][k] = (z[k]+conj(z[-k]))/2,
  //                   S[2p+1][k] = (z[k]-conj(z[-k]))/(2i)
  // Store only cols 0..128 (Hermitian-half S).
  float2* So = Snew + b*FIELD;
  #pragma unroll
  for (int m = 0; m < 2; ++m) {
    int e = tid + (m << 10);           // 8 real rows x 256 = 2048
    int row = e >> 8, jj = e & 255;
    if (jj <= 128) {
      int p = row >> 1;
      float2 z  = AbS[p*ROWF2 + pdx(jj)];
      float2 z2 = AbS[p*ROWF2 + pdx((256 - jj) & 255)];
      float2 sv;
      if ((row & 1) == 0)
        sv = make_float2(0.5f*(z.x + z2.x), 0.5f*(z.y - z2.y));
      else
        sv = make_float2(0.5f*(z.y + z2.y), 0.5f*(z2.x - z.x));
      So[(row0 + row)*NN + jj] = sv;
    }
  }
}

// ================================================================ B (Hermitian-half)
// dim3(17, BATCH) x 512 threads. Processes columns 0..135; stores only
// cols 0..128 (consumers reconstruct j>128 via conj). 8 teams x 64 lanes,
// R17-f2 fused rounds.
__global__ __launch_bounds__(512) void fft_cols_h(float2* __restrict__ S)
{
  __shared__ float2 Ab[8*ROWF2];
  __shared__ float2 tw[128];
  __shared__ float  lam[NN];
  int tid = threadIdx.x;
  int b = blockIdx.y;
  int col0 = blockIdx.x << 3;          // 0, 8, ..., 128

  if (tid < 128) {
    float sw, cw;
    __sincosf(-0.02454369260617026f * (float)tid, &sw, &cw);
    tw[tid] = make_float2(cw, sw);
  }
  if (tid < 256) {
    float s1 = __sinf(0.01227184630308512983f * (float)tid);   // pi/256 * k
    lam[tid] = -4.0f * s1 * s1 * (RDX*RDX);
  }

  float2* Sb = S + b*FIELD;
  #pragma unroll
  for (int k = 0; k < 4; ++k) {        // load transposed, bit-reversed
    int idx = tid + (k << 9);
    int i = idx >> 3, c = idx & 7;
    Ab[c*ROWF2 + pdx(rev8(i))] = Sb[i*NN + col0 + c];
  }
  __syncthreads();                     // cross-wave: scatter -> per-wave FFT

  int g = tid >> 6, lane = tid & 63;   // wave g owns column col0+g
  fft256_fwd_f2(Ab + g*ROWF2, lane, tw, true);

  // spectral scale: wave g touches only its own row -> wave order suffices
  float l2 = lam[(col0 + g) & 255];
  #pragma unroll
  for (int r = 0; r < 4; ++r) {
    int k1 = lane + (r << 6);
    float den = lam[k1] + l2;
    float sc = ((k1 | (col0 + g)) == 0) ? 0.0f : (1.0f/den);
    sc *= (1.0f/65536.0f);             // fold in ifft2's 1/N^2
    float2 v = Ab[g*ROWF2 + pdx(k1)];
    Ab[g*ROWF2 + pdx(k1)] = make_float2(v.x*sc, v.y*sc);
  }
  wave_sync();

  fft256_inv_f2(Ab + g*ROWF2, lane, tw, true);
  __syncthreads();                     // cross-wave: FFT rows -> store

  #pragma unroll
  for (int k = 0; k < 4; ++k) {        // store cols 0..128 only
    int idx = tid + (k << 9);
    int i = idx >> 3, c = idx & 7;
    int j = col0 + c;
    if (j <= 128)
      Sb[i*NN + j] = Ab[c*ROWF2 + pdx(rev8(i))];
  }
}

// ================================================================ K1 (R9 fallback)
__global__ __launch_bounds__(512) void advect_div_fft(
    const float* __restrict__ inb, float* __restrict__ outb,
    float2* __restrict__ S, float* __restrict__ out,
    const unsigned* __restrict__ dtw, int T, int tm1)
{
  __shared__ float  Vs[8][NN];
  __shared__ float2 AbS[8*ROWF2];
  __shared__ float2 tw[128];
  const int tid = threadIdx.x;
  const int j   = tid & 255;
  const int h   = tid >> 8;           // 0 or 1
  const int b    = blockIdx.x >> 5;
  const int row0 = (blockIdx.x & 31) << 3;

  if (tid < 128) {
    float sw, cw;
    __sincosf(-0.02454369260617026f * (float)tid, &sw, &cw);  // -2pi/256
    tw[tid] = make_float2(cw, sw);
  }

  const float* Ub = inb + b*FIELD;
  const float* Vb = inb + TOTAL + b*FIELD;
  const float* Db = inb + 2*TOTAL + b*FIELD;
  float* Uo  = outb + b*FIELD;
  float* Vo  = outb + TOTAL + b*FIELD;
  float* Do_ = outb + 2*TOTAL + b*FIELD;

  const float dt = decode_dt(dtw);
  const float hdtdx = 0.5f*dt*RDX;

  if (tm1 >= 0) {                      // fused write_out of previous state
    #pragma unroll
    for (int k = 0; k < 4; ++k) {
      int pos = (row0 + h*4 + k)*NN + j;
      size_t o = ((size_t)(b*T + tm1)*FIELD + pos)*3u;
      out[o]   = Ub[pos];
      out[o+1] = Vb[pos];
      out[o+2] = Db[pos];
    }
  }

  const int kbeg = h ? 3 : -1;
  float u1r[5];
  #pragma unroll
  for (int kk = 0; kk < 5; ++kk) {
    int k = kbeg + kk;
    int r = (row0 + k) & NM;
    float u1, v1, d1;
    if (kk == 0) {
      advect_point<0>(Ub, Vb, Db, r, j, hdtdx, dt, u1, v1, d1);
    } else {
      advect_point<1>(Ub, Vb, Db, r, j, hdtdx, dt, u1, v1, d1);
      int gi = r*NN + j;
      Uo[gi] = u1; Vo[gi] = v1; Do_[gi] = d1;
      Vs[k][j] = v1;
    }
    u1r[kk] = u1;
  }
  __syncthreads();

  {  // div (backward diff) -> bit-reversed scatter (padded)
    int jm1 = (j - 1) & NM, rj = rev8(j);
    #pragma unroll
    for (int m = 0; m < 4; ++m) {
      int k = h*4 + m;
      float dv = (u1r[m+1] - u1r[m] + Vs[k][j] - Vs[k][jm1]) * RDX;
      AbS[k*ROWF2 + pdx(rj)] = make_float2(dv, 0.0f);
    }
  }
  __syncthreads();

  // fwd row FFT: 8 teams x 64 lanes
  const int g = tid >> 6, lane = tid & 63;
  fft256_dit_fwd<64>(AbS + g*ROWF2, lane, tw, true);
  __syncthreads();

  float2* Sb = S + b*FIELD;
  #pragma unroll
  for (int k = 0; k < 4; ++k) {
    int row = h*4 + k;
    Sb[(row0 + row)*NN + j] = AbS[row*ROWF2 + pdx(j)];
  }
}

// ================================================================ K2 (R9 fallback)
__global__ __launch_bounds__(512) void fft_cols_r9(float2* __restrict__ S)
{
  __shared__ float2 Ab[8*ROWF2];
  __shared__ float2 tw[128];
  __shared__ float  lam[NN];
  int tid = threadIdx.x;
  int b = blockIdx.x >> 5;
  int col0 = (blockIdx.x & 31) << 3;

  if (tid < 128) {
    float sw, cw;
    __sincosf(-0.02454369260617026f * (float)tid, &sw, &cw);
    tw[tid] = make_float2(cw, sw);
  }
  if (tid < 256) {
    float s1 = __sinf(0.01227184630308512983f * (float)tid);   // pi/256 * k
    lam[tid] = -4.0f * s1 * s1 * (RDX*RDX);
  }

  float2* Sb = S + b*FIELD;
  #pragma unroll
  for (int k = 0; k < 4; ++k) {        // load transposed, bit-reversed
    int idx = tid + (k << 9);
    int i = idx >> 3, c = idx & 7;
    Ab[c*ROWF2 + pdx(rev8(i))] = Sb[i*NN + col0 + c];
  }
  __syncthreads();                     // cross-wave: scatter -> per-wave FFT

  int g = tid >> 6, lane = tid & 63;   // wave g owns column-row g
  fft256_dit_fwd<64>(Ab + g*ROWF2, lane, tw, true);

  float l2 = lam[col0 + g];
  #pragma unroll
  for (int r = 0; r < 4; ++r) {
    int k1 = lane + (r << 6);
    float den = lam[k1] + l2;
    float sc = ((k1 | (col0 + g)) == 0) ? 0.0f : (1.0f/den);
    sc *= (1.0f/65536.0f);             // fold in ifft2's 1/N^2
    float2 v = Ab[g*ROWF2 + pdx(k1)];
    Ab[g*ROWF2 + pdx(k1)] = make_float2(v.x*sc, v.y*sc);
  }
  wave_sync();

  fft256_dif_inv<64>(Ab + g*ROWF2, lane, tw, true);
  __syncthreads();                     // cross-wave: FFT rows -> store

  #pragma unroll
  for (int k = 0; k < 4; ++k) {        // store transposed, un-reversed
    int idx = tid + (k << 9);
    int i = idx >> 3, c = idx & 7;
    Sb[i*NN + col0 + c] = Ab[c*ROWF2 + pdx(rev8(i))];
  }
}

// ================================================================ K3 (final correction)
// Reads S with Hermitian reconstruction for j>128 (works for both the
// Hermitian-half preferred path and the full-S R9 fallback).
__global__ __launch_bounds__(512) void fft_inv_correct(
    const float2* __restrict__ S, float* __restrict__ outb)
{
  __shared__ float2 Ab[9*ROWF2];
  __shared__ float  qs[9*NN];
  __shared__ float2 tw[128];
  int tid = threadIdx.x;
  int b = blockIdx.x >> 5;
  int row0 = (blockIdx.x & 31) << 3;

  if (tid < 128) {
    float sw, cw;
    __sincosf(-0.02454369260617026f * (float)tid, &sw, &cw);
    tw[tid] = make_float2(cw, sw);
  }

  const float2* Sb = S + b*FIELD;
  #pragma unroll
  for (int m = 0; m < 5; ++m) {        // load 9 rows, natural order (DIF in)
    int e = tid + m*512;
    if (e < 9*NN) {
      int k = e >> 8, j = e & 255;
      int jr = (j <= 128) ? j : (256 - j);
      float2 v = Sb[((row0 + k) & NM)*NN + jr];
      if (j > 128) v.y = -v.y;
      Ab[k*ROWF2 + pdx(j)] = v;
    }
  }
  __syncthreads();

  int g = tid >> 5, lane = tid & 31;   // 16 teams of 32; 9 active
  bool active = (g < 9);
  fft256_dif_inv<32>(Ab + (active ? g : 8)*ROWF2, lane, tw, active);
  __syncthreads();

  #pragma unroll
  for (int m = 0; m < 5; ++m) {        // un-reverse gather -> qs natural
    int e = tid + m*512;
    if (e < 9*NN) {
      int k = e >> 8, j = e & 255;
      qs[k*NN + j] = Ab[k*ROWF2 + pdx(rev8(j))].x;
    }
  }
  __syncthreads();

  float* Ug = outb + b*FIELD;
  float* Vg = outb + TOTAL + b*FIELD;
  #pragma unroll
  for (int m = 0; m < 4; ++m) {
    int e = tid + m*512;               // 0..2047
    int k = e >> 8, j = e & 255;
    int gi = (row0 + k)*NN + j;
    float q0 = qs[k*NN + j];
    float q1 = qs[(k+1)*NN + j];
    float qj = qs[k*NN + ((j+1) & NM)];
    Ug[gi] -= (q1 - q0)*RDX;
    Vg[gi] -= (qj - q0)*RDX;
  }
}

// ================================================================ misc
__global__ __launch_bounds__(256) void write_out_k(
    const float* __restrict__ U, const float* __restrict__ V, const float* __restrict__ D,
    float* __restrict__ out, int t, int T)
{
  int idx = blockIdx.x*256 + threadIdx.x;
  int b = idx >> 16;
  int pos = idx & (FIELD-1);
  size_t o = ((size_t)(b*T + t)*FIELD + pos)*3u;
  out[o]   = U[idx];
  out[o+1] = V[idx];
  out[o+2] = D[idx];
}

__global__ __launch_bounds__(256) void init_state(
    const float* __restrict__ y0,
    float* __restrict__ U, float* __restrict__ V, float* __restrict__ D)
{
  int idx = blockIdx.x*256 + threadIdx.x;
  U[idx] = y0[idx*3];
  V[idx] = y0[idx*3+1];
  D[idx] = y0[idx*3+2];
}

// ================================================================ fallback
// R5-proven sincos/unpadded kernels (used only if ws too small).
__device__ __forceinline__ void fft_fwd_sc(float2* A, int lane) {
  #pragma unroll
  for (int s = 1; s <= 8; ++s) {
    int half = 1 << (s-1);
    float angscale = -6.28318530717958647692f / (float)(2*half);
    #pragma unroll
    for (int r = 0; r < 4; ++r) {
      int bfly = lane + (r << 5);
      int q = bfly & (half - 1);
      int g = (bfly >> (s-1)) << s;
      float sw, cw; __sincosf(angscale * (float)q, &sw, &cw);
      float2 a = A[g+q], b = A[g+q+half];
      float wbx = cw*b.x - sw*b.y, wby = cw*b.y + sw*b.x;
      A[g+q] = make_float2(a.x+wbx, a.y+wby);
      A[g+q+half] = make_float2(a.x-wbx, a.y-wby);
    }
    __syncthreads();
  }
}
__device__ __forceinline__ void fft_inv_sc(float2* A, int lane) {
  #pragma unroll
  for (int s = 8; s >= 1; --s) {
    int half = 1 << (s-1);
    float angscale = 6.28318530717958647692f / (float)(2*half);
    #pragma unroll
    for (int r = 0; r < 4; ++r) {
      int bfly = lane + (r << 5);
      int q = bfly & (half - 1);
      int g = (bfly >> (s-1)) << s;
      float sw, cw; __sincosf(angscale * (float)q, &sw, &cw);
      float2 a = A[g+q], b = A[g+q+half];
      float dx = a.x-b.x, dy = a.y-b.y;
      A[g+q] = make_float2(a.x+b.x, a.y+b.y);
      A[g+q+half] = make_float2(cw*dx - sw*dy, cw*dy + sw*dx);
    }
    __syncthreads();
  }
}

__global__ __launch_bounds__(256) void advect_kernel_fb(
    const float* __restrict__ U, const float* __restrict__ V, const float* __restrict__ D,
    float* __restrict__ Uo, float* __restrict__ Vo, float* __restrict__ Do_,
    const unsigned* __restrict__ dtw)
{
  int idx = blockIdx.x*256 + threadIdx.x;
  int j = idx & NM, i = (idx >> 8) & NM, base = (idx >> 16) * FIELD;
  float dt = decode_dt(dtw);
  float u1, v1, d1;
  advect_point<1>(U + base, V + base, D + base, i, j, 0.5f*dt*RDX, dt, u1, v1, d1);
  Uo[idx] = u1; Vo[idx] = v1; Do_[idx] = d1;
}

__global__ __launch_bounds__(256) void fft_rows_div_fb(
    const float* __restrict__ U2, const float* __restrict__ V2, float2* __restrict__ S)
{
  __shared__ float2 Ab[8*NN];
  int tid = threadIdx.x, b = blockIdx.x >> 5, row0 = (blockIdx.x & 31) << 3;
  const float* Ub = U2 + b*FIELD;
  const float* Vb = V2 + b*FIELD;
  int jm1 = (tid - 1) & NM, rj = rev8(tid);
  #pragma unroll
  for (int k = 0; k < 8; ++k) {
    int row = row0 + k, rm1 = (row - 1) & NM;
    float dv = (Ub[row*NN + tid] - Ub[rm1*NN + tid]
              + Vb[row*NN + tid] - Vb[row*NN + jm1]) * RDX;
    Ab[(k<<8) + rj] = make_float2(dv, 0.0f);
  }
  __syncthreads();
  int g = tid >> 5, lane = tid & 31;
  fft_fwd_sc(Ab + (g<<8), lane);
  float2* Sb = S + b*FIELD;
  #pragma unroll
  for (int k = 0; k < 8; ++k)
    Sb[(row0 + k)*NN + tid] = Ab[(k<<8) + tid];
}

__global__ __launch_bounds__(256) void fft_cols_fb(float2* __restrict__ S)
{
  __shared__ float2 Ab[8*NN];
  int tid = threadIdx.x, b = blockIdx.x >> 5, col0 = (blockIdx.x & 31) << 3;
  float2* Sb = S + b*FIELD;
  #pragma unroll
  for (int k = 0; k < 8; ++k) {
    int idx = tid + (k << 8);
    int i = idx >> 3, c = idx & 7;
    Ab[(c<<8) + rev8(i)] = Sb[i*NN + col0 + c];
  }
  __syncthreads();
  int g = tid >> 5, lane = tid & 31;
  fft_fwd_sc(Ab + (g<<8), lane);
  int k2 = col0 + g;
  float s2 = __sinf(0.01227184630308512983f * (float)k2);
  float l2 = -4.0f * s2 * s2 * (RDX*RDX);
  #pragma unroll
  for (int r = 0; r < 8; ++r) {
    int k1 = lane + (r << 5);
    float s1 = __sinf(0.01227184630308512983f * (float)k1);
    float l1 = -4.0f * s1 * s1 * (RDX*RDX);
    float den = l1 + l2;
    float sc = ((k1 | k2) == 0) ? 0.0f : (1.0f/den);
    sc *= (1.0f/65536.0f);
    float2 v = Ab[(g<<8) + k1];
    Ab[(g<<8) + k1] = make_float2(v.x*sc, v.y*sc);
  }
  __syncthreads();
  fft_inv_sc(Ab + (g<<8), lane);
  #pragma unroll
  for (int k = 0; k < 8; ++k) {
    int idx = tid + (k << 8);
    int i = idx >> 3, c = idx & 7;
    Sb[i*NN + col0 + c] = Ab[(c<<8) + rev8(i)];
  }
}

__global__ __launch_bounds__(256) void fft_rows_inv_fb(
    const float2* __restrict__ S, float* __restrict__ Q)
{
  __shared__ float2 Ab[8*NN];
  int tid = threadIdx.x, b = blockIdx.x >> 5, row0 = (blockIdx.x & 31) << 3;
  const float2* Sb = S + b*FIELD;
  #pragma unroll
  for (int k = 0; k < 8; ++k)
    Ab[(k<<8) + tid] = Sb[(row0 + k)*NN + tid];
  __syncthreads();
  int g = tid >> 5, lane = tid & 31;
  fft_inv_sc(Ab + (g<<8), lane);
  float* Qb = Q + b*FIELD;
  int rj = rev8(tid);
  #pragma unroll
  for (int k = 0; k < 8; ++k)
    Qb[(row0 + k)*NN + tid] = Ab[(k<<8) + rj].x;
}

__global__ __launch_bounds__(256) void correct_uv_fb(
    float* __restrict__ U2, float* __restrict__ V2, const float* __restrict__ Q)
{
  int idx = blockIdx.x*256 + threadIdx.x;
  int j = idx & NM, i = (idx >> 8) & NM, base = (idx >> 16) * FIELD;
  const float* Qb = Q + base;
  float q0 = Qb[i*NN + j];
  float qi = Qb[((i+1)&NM)*NN + j];
  float qj = Qb[i*NN + ((j+1)&NM)];
  U2[idx] -= (qi - q0)*RDX;
  V2[idx] -= (qj - q0)*RDX;
}

// ---------------------------------------------------------------- launch
extern "C" void kernel_launch(void* const* d_in, const int* in_sizes, int n_in,
                              void* d_out, int out_size, void* d_ws, size_t ws_size,
                              hipStream_t stream) {
  (void)in_sizes; (void)n_in;
  const float*    y0  = (const float*)d_in[0];
  const unsigned* dtw = (const unsigned*)d_in[1];
  float* out = (float*)d_out;

  int T = out_size / (3*FIELD*BATCH);
  if (T < 1) T = 1;

  float* wsf = (float*)d_ws;

  // ---- preferred: fused 2-kernel/step path (needs 10*TOTAL floats) ----
  if (ws_size >= (size_t)10*TOTAL*sizeof(float)) {
    float* stA = wsf;                  // 3*TOTAL
    float* stB = wsf + 3*TOTAL;        // 3*TOTAL
    float2* Sa = (float2*)(wsf + 6*TOTAL);   // TOTAL float2
    float2* Sc = (float2*)(wsf + 8*TOTAL);   // TOTAL float2

    init_state<<<TOTAL/256, 256, 0, stream>>>(y0, stA, stA+TOTAL, stA+2*TOTAL);
    float* inb  = stA;
    float* outb = stB;
    float2* Sr = Sa;                   // spectral q from previous step
    float2* Sw = Sc;                   // new div spectral
    int step = 0;
    for (int t = 0; t < T; ++t) {
      for (int s = 0; s < 10; ++s) {
        int tm1 = (s == 0) ? (t - 1) : -1;
        proj_advect_fft8<<<256, 1024, 0, stream>>>(Sr, inb, outb, Sw, out,
                                                   dtw, T, tm1, step == 0);
        fft_cols_h<<<dim3(17, BATCH), 512, 0, stream>>>(Sw);
        float*  t1 = inb; inb = outb; outb = t1;
        float2* t2 = Sr;  Sr  = Sw;   Sw  = t2;
        ++step;
      }
    }
    // final state in inb is uncorrected; Sr holds its Poisson solution
    fft_inv_correct<<<256, 512, 0, stream>>>(Sr, inb);
    write_out_k<<<TOTAL/256, 256, 0, stream>>>(inb, inb+TOTAL, inb+2*TOTAL,
                                               out, T-1, T);
    return;
  }

  // ---- R9 3-kernel path (needs 8*TOTAL floats) ----
  if (ws_size >= (size_t)8*TOTAL*sizeof(float)) {
    float2* S = (float2*)(wsf + 6*TOTAL);
    init_state<<<TOTAL/256, 256, 0, stream>>>(y0, wsf, wsf+TOTAL, wsf+2*TOTAL);
    float* inb = wsf;
    float* outb = wsf + 3*TOTAL;
    for (int t = 0; t < T; ++t) {
      for (int s = 0; s < 10; ++s) {
        int tm1 = (s == 0) ? (t - 1) : -1;
        advect_div_fft <<<256, 512, 0, stream>>>(inb, outb, S, out, dtw, T, tm1);
        fft_cols_r9    <<<256, 512, 0, stream>>>(S);
        fft_inv_correct<<<256, 512, 0, stream>>>(S, outb);
        float* tmp = inb; inb = outb; outb = tmp;
      }
    }
    write_out_k<<<TOTAL/256, 256, 0, stream>>>(inb, inb+TOTAL, inb+2*TOTAL,
                                               out, T-1, T);
    return;
  }

  // ---- R5 5-kernel path with aliased S/Q (12.6 MB) ----
  float* bank0 = wsf;
  float* bank1 = wsf + 3*TOTAL;
  init_state<<<TOTAL/256, 256, 0, stream>>>(y0, bank0, bank0+TOTAL, bank0+2*TOTAL);
  float* inb = bank0;
  float* outb = bank1;
  for (int t = 0; t < T; ++t) {
    for (int s = 0; s < 10; ++s) {
      float *Ui = inb,  *Vi = inb + TOTAL,  *Di = inb + 2*TOTAL;
      float *Uo = outb, *Vo = outb + TOTAL, *Do_ = outb + 2*TOTAL;
      float2* S = (float2*)(inb + TOTAL);
      float*  Q = inb;
      advect_kernel_fb<<<TOTAL/256, 256, 0, stream>>>(Ui, Vi, Di, Uo, Vo, Do_, dtw);
      fft_rows_div_fb <<<BATCH*32, 256, 0, stream>>>(Uo, Vo, S);
      fft_cols_fb     <<<BATCH*32, 256, 0, stream>>>(S);
      fft_rows_inv_fb <<<BATCH*32, 256, 0, stream>>>(S, Q);
      correct_uv_fb   <<<TOTAL/256, 256, 0, stream>>>(Uo, Vo, Q);
      float* tmp = inb; inb = outb; outb = tmp;
    }
    write_out_k<<<TOTAL/256, 256, 0, stream>>>(inb, inb+TOTAL, inb+2*TOTAL, out, t, T);
  }
}